// Round 2
// baseline (1036.291 us; speedup 1.0000x reference)
//
#include <hip/hip_runtime.h>
#include <hip/hip_bf16.h>

#define NN 50000
#define EE 800000
#define ET (EE + NN)          // 850000 edges incl self-loops
#define NB_SCAN ((NN + 255) / 256)   // 196

typedef __attribute__((ext_vector_type(8))) short bf16x8;
typedef __attribute__((ext_vector_type(4))) float f32x4;

static __device__ __forceinline__ float bf2f(__hip_bfloat16 x) { return __bfloat162float(x); }
static __device__ __forceinline__ ushort f2bu(float f) {
    union { __hip_bfloat16 b; ushort u; } c;
    c.b = __float2bfloat16(f);
    return c.u;
}

// ---------------------------------------------------------------- CSR build
__global__ void gat_count_kernel(const int* __restrict__ ei, int* __restrict__ cnt) {
    int i = blockIdx.x * blockDim.x + threadIdx.x;
    if (i >= ET) return;
    int dst = (i < EE) ? ei[EE + i] : (i - EE);
    atomicAdd(&cnt[dst], 1);
}

__global__ void gat_scan1_kernel(const int* __restrict__ cnt, int* __restrict__ tmp,
                                 int* __restrict__ part) {
    __shared__ int sm[256];
    int tid = threadIdx.x;
    int i = blockIdx.x * 256 + tid;
    int v = (i < NN) ? cnt[i] : 0;
    sm[tid] = v;
    __syncthreads();
    for (int o = 1; o < 256; o <<= 1) {
        int t = (tid >= o) ? sm[tid - o] : 0;
        __syncthreads();
        sm[tid] += t;
        __syncthreads();
    }
    if (i < NN) tmp[i] = sm[tid];
    if (tid == 255) part[blockIdx.x] = sm[255];
}

__global__ void gat_scan2_kernel(int* __restrict__ part) {
    __shared__ int sm[256];
    int tid = threadIdx.x;
    int v = (tid < NB_SCAN) ? part[tid] : 0;
    sm[tid] = v;
    __syncthreads();
    for (int o = 1; o < 256; o <<= 1) {
        int t = (tid >= o) ? sm[tid - o] : 0;
        __syncthreads();
        sm[tid] += t;
        __syncthreads();
    }
    part[tid] = sm[tid];
}

__global__ void gat_scan3_kernel(const int* __restrict__ tmp, const int* __restrict__ part,
                                 int* __restrict__ row_ptr) {
    int i = blockIdx.x * 256 + threadIdx.x;
    int off = (blockIdx.x > 0) ? part[blockIdx.x - 1] : 0;
    if (i < NN) row_ptr[i + 1] = tmp[i] + off;
    if (i == 0) row_ptr[0] = 0;
}

__global__ void gat_fill_kernel(const int* __restrict__ ei, const int* __restrict__ row_ptr,
                                int* __restrict__ fillc, int* __restrict__ colA) {
    int i = blockIdx.x * blockDim.x + threadIdx.x;
    if (i >= ET) return;
    int s, d;
    if (i < EE) { s = ei[i]; d = ei[EE + i]; }
    else        { s = d = i - EE; }
    int pos = row_ptr[d] + atomicAdd(&fillc[d], 1);
    colA[pos] = s;
}

// ---------------------------------------------------------------- GEMM core (templated on A dtype)
// C[M,N] = A[M,K] * B[K,N]; B fp32 (weights). A either fp32 (layer 1) or bf16 (layers 2,3).
// bf16 MFMA, fp32 accumulate, bf16 out. BM=128 BN=64 BK=32.
#define GBM 128
#define GBN 64
#define GBK 32
#define LDP 40   // padded LDS k-stride in ushorts (80B: 16B-aligned, bank-spread)

template <typename AT>
__global__ __launch_bounds__(256) void gat_gemm_kernel(
    const AT* __restrict__ A, const float* __restrict__ B,
    __hip_bfloat16* __restrict__ C, int M, int K, int N) {
    __shared__ __align__(16) ushort As[GBM * LDP];
    __shared__ __align__(16) ushort Bs[GBN * LDP];
    int tid = threadIdx.x;
    int wave = tid >> 6, lane = tid & 63;
    int lrow = lane & 15, lq = lane >> 4;
    int m0 = blockIdx.x * GBM, n0 = blockIdx.y * GBN;
    f32x4 acc[2][4] = {};

    for (int k0 = 0; k0 < K; k0 += GBK) {
        __syncthreads();
        // stage A: thread t -> row=t>>1, kc=(t&1)*16 (16 elements)
        {
            int row = tid >> 1, kc = (tid & 1) * 16;
            int gm = m0 + row;
            ushort u[16];
            if constexpr (sizeof(AT) == 4) {  // fp32 A
                float4 f0 = make_float4(0, 0, 0, 0), f1 = f0, f2 = f0, f3 = f0;
                if (gm < M) {
                    const float4* p = (const float4*)((const float*)A + (size_t)gm * K + k0 + kc);
                    f0 = p[0]; f1 = p[1]; f2 = p[2]; f3 = p[3];
                }
                u[0] = f2bu(f0.x); u[1] = f2bu(f0.y); u[2] = f2bu(f0.z); u[3] = f2bu(f0.w);
                u[4] = f2bu(f1.x); u[5] = f2bu(f1.y); u[6] = f2bu(f1.z); u[7] = f2bu(f1.w);
                u[8] = f2bu(f2.x); u[9] = f2bu(f2.y); u[10] = f2bu(f2.z); u[11] = f2bu(f2.w);
                u[12] = f2bu(f3.x); u[13] = f2bu(f3.y); u[14] = f2bu(f3.z); u[15] = f2bu(f3.w);
            } else {  // bf16 A
                uint4 z0 = make_uint4(0, 0, 0, 0), z1 = z0;
                if (gm < M) {
                    const uint4* p = (const uint4*)((const ushort*)A + (size_t)gm * K + k0 + kc);
                    z0 = p[0]; z1 = p[1];
                }
                *(uint4*)&u[0] = z0;
                *(uint4*)&u[8] = z1;
            }
            *(uint4*)&As[row * LDP + kc] = *(const uint4*)&u[0];
            *(uint4*)&As[row * LDP + kc + 8] = *(const uint4*)&u[8];
        }
        // stage B transposed: thread t -> k=t>>3, nc=(t&7)*8 (8 fp32 -> 8 bf16)
        {
            int kk = tid >> 3, nc = (tid & 7) * 8;
            float4 g0 = make_float4(0, 0, 0, 0), g1 = g0;
            if (n0 + nc < N) {
                const float4* p = (const float4*)(B + (size_t)(k0 + kk) * N + n0 + nc);
                g0 = p[0]; g1 = p[1];
            }
            ushort t8[8];
            t8[0] = f2bu(g0.x); t8[1] = f2bu(g0.y); t8[2] = f2bu(g0.z); t8[3] = f2bu(g0.w);
            t8[4] = f2bu(g1.x); t8[5] = f2bu(g1.y); t8[6] = f2bu(g1.z); t8[7] = f2bu(g1.w);
#pragma unroll
            for (int j = 0; j < 8; j++) Bs[(nc + j) * LDP + kk] = t8[j];
        }
        __syncthreads();

        bf16x8 af0 = *(const bf16x8*)&As[(wave * 32 + lrow) * LDP + lq * 8];
        bf16x8 af1 = *(const bf16x8*)&As[(wave * 32 + 16 + lrow) * LDP + lq * 8];
#pragma unroll
        for (int ng = 0; ng < 4; ng++) {
            bf16x8 bf = *(const bf16x8*)&Bs[(ng * 16 + lrow) * LDP + lq * 8];
            acc[0][ng] = __builtin_amdgcn_mfma_f32_16x16x32_bf16(af0, bf, acc[0][ng], 0, 0, 0);
            acc[1][ng] = __builtin_amdgcn_mfma_f32_16x16x32_bf16(af1, bf, acc[1][ng], 0, 0, 0);
        }
    }
    // epilogue: C/D layout col=lane&15, row=lq*4+r
#pragma unroll
    for (int rs = 0; rs < 2; rs++)
#pragma unroll
        for (int ng = 0; ng < 4; ng++)
#pragma unroll
            for (int r = 0; r < 4; r++) {
                int row = m0 + wave * 32 + rs * 16 + lq * 4 + r;
                int colI = n0 + ng * 16 + lrow;
                if (row < M && colI < N)
                    C[(size_t)row * N + colI] = __float2bfloat16(acc[rs][ng][r]);
            }
}

// ---------------------------------------------------------------- alpha dots
// as[n,h] = sum_c h[n,h*C+c]*a_src[h,c]; one wave per node. h bf16, a fp32.
__global__ void gat_alpha_kernel(const __hip_bfloat16* __restrict__ h,
                                 const float* __restrict__ a_src,
                                 const float* __restrict__ a_dst,
                                 float* __restrict__ as8, float* __restrict__ ad8,
                                 int heads, int C, int HW) {
    int node = blockIdx.x * 4 + (threadIdx.x >> 6);
    if (node >= NN) return;
    int lane = threadIdx.x & 63;
    for (int hh = 0; hh < heads; hh++) {
        float v = 0.f, cs = 0.f, cd = 0.f;
        if (lane < C) {
            v = bf2f(h[(size_t)node * HW + hh * C + lane]);
            cs = a_src[hh * C + lane];
            cd = a_dst[hh * C + lane];
        }
        float ps = v * cs, pd = v * cd;
#pragma unroll
        for (int o = 32; o > 0; o >>= 1) {
            ps += __shfl_xor(ps, o);
            pd += __shfl_xor(pd, o);
        }
        if (lane == 0) {
            as8[(size_t)node * 8 + hh] = ps;
            ad8[(size_t)node * 8 + hh] = pd;
        }
    }
}

// ---------------------------------------------------------------- aggregation, 7 heads x 64ch
__global__ void gat_agg7_kernel(const int* __restrict__ rp, const int* __restrict__ colA,
                                const float* __restrict__ as8, const float* __restrict__ ad8,
                                const __hip_bfloat16* __restrict__ h,
                                const float* __restrict__ bias,
                                __hip_bfloat16* __restrict__ outp) {
    int d = blockIdx.x * 4 + (threadIdx.x >> 6);
    if (d >= NN) return;
    int lane = threadIdx.x & 63;
    int s0 = rp[d], s1 = rp[d + 1];
    const float4* ad4 = (const float4*)(ad8 + (size_t)d * 8);
    float4 q0 = ad4[0], q1 = ad4[1];
    float adh[7] = {q0.x, q0.y, q0.z, q0.w, q1.x, q1.y, q1.z};
    float m[7];
#pragma unroll
    for (int hh = 0; hh < 7; hh++) m[hh] = -1e30f;
    for (int j = s0; j < s1; j++) {
        int s = colA[j];
        const float4* as4 = (const float4*)(as8 + (size_t)s * 8);
        float4 p0 = as4[0], p1 = as4[1];
        float av[7] = {p0.x, p0.y, p0.z, p0.w, p1.x, p1.y, p1.z};
#pragma unroll
        for (int hh = 0; hh < 7; hh++) {
            float e = av[hh] + adh[hh];
            e = (e > 0.f) ? e : 0.2f * e;
            m[hh] = fmaxf(m[hh], e);
        }
    }
    float acc[7] = {0.f, 0.f, 0.f, 0.f, 0.f, 0.f, 0.f};
    float den[7] = {0.f, 0.f, 0.f, 0.f, 0.f, 0.f, 0.f};
    for (int j = s0; j < s1; j++) {
        int s = colA[j];
        const float4* as4 = (const float4*)(as8 + (size_t)s * 8);
        float4 p0 = as4[0], p1 = as4[1];
        float av[7] = {p0.x, p0.y, p0.z, p0.w, p1.x, p1.y, p1.z};
        const __hip_bfloat16* hs = h + (size_t)s * 448;
#pragma unroll
        for (int hh = 0; hh < 7; hh++) {
            float e = av[hh] + adh[hh];
            e = (e > 0.f) ? e : 0.2f * e;
            float w = __expf(e - m[hh]);
            den[hh] += w;
            acc[hh] += w * bf2f(hs[hh * 64 + lane]);
        }
    }
#pragma unroll
    for (int hh = 0; hh < 7; hh++) {
        float o = acc[hh] / (den[hh] + 1e-16f) + bias[hh * 64 + lane];
        o = fmaxf(o, 0.f);  // relu (layers 1,2 only use this kernel)
        outp[(size_t)d * 448 + hh * 64 + lane] = __float2bfloat16(o);
    }
}

// ---------------------------------------------------------------- final layer: 1 head x 32ch + log_softmax (fp32 out)
__global__ void gat_aggF_kernel(const int* __restrict__ rp, const int* __restrict__ colA,
                                const float* __restrict__ as8, const float* __restrict__ ad8,
                                const __hip_bfloat16* __restrict__ h,
                                const float* __restrict__ bias,
                                float* __restrict__ outp) {
    int d = blockIdx.x * 4 + (threadIdx.x >> 6);
    if (d >= NN) return;
    int lane = threadIdx.x & 63;
    int s0 = rp[d], s1 = rp[d + 1];
    float adv = ad8[(size_t)d * 8];
    float m = -1e30f;
    for (int j = s0; j < s1; j++) {
        int s = colA[j];
        float e = as8[(size_t)s * 8] + adv;
        e = (e > 0.f) ? e : 0.2f * e;
        m = fmaxf(m, e);
    }
    float acc = 0.f, den = 0.f;
    for (int j = s0; j < s1; j++) {
        int s = colA[j];
        float e = as8[(size_t)s * 8] + adv;
        e = (e > 0.f) ? e : 0.2f * e;
        float w = __expf(e - m);
        den += w;
        float v = (lane < 32) ? bf2f(h[(size_t)s * 32 + lane]) : 0.f;
        acc += w * v;
    }
    float o = acc / (den + 1e-16f) + ((lane < 32) ? bias[lane] : 0.f);
    // log_softmax over 32 channels
    float t = (lane < 32) ? o : -1e30f;
#pragma unroll
    for (int off = 32; off > 0; off >>= 1) t = fmaxf(t, __shfl_xor(t, off));
    float ex = (lane < 32) ? __expf(o - t) : 0.f;
#pragma unroll
    for (int off = 32; off > 0; off >>= 1) ex += __shfl_xor(ex, off);
    float res = o - t - __logf(ex);
    if (lane < 32) outp[(size_t)d * 32 + lane] = res;
}

// ---------------------------------------------------------------- launch
extern "C" void kernel_launch(void* const* d_in, const int* in_sizes, int n_in,
                              void* d_out, int out_size, void* d_ws, size_t ws_size,
                              hipStream_t stream) {
    const float* x   = (const float*)d_in[0];
    const int*   ei  = (const int*)d_in[1];
    const float* W1  = (const float*)d_in[2];
    const float* a1s = (const float*)d_in[3];
    const float* a1d = (const float*)d_in[4];
    const float* b1  = (const float*)d_in[5];
    const float* W2  = (const float*)d_in[6];
    const float* a2s = (const float*)d_in[7];
    const float* a2d = (const float*)d_in[8];
    const float* b2  = (const float*)d_in[9];
    const float* W3  = (const float*)d_in[10];
    const float* a3s = (const float*)d_in[11];
    const float* a3d = (const float*)d_in[12];
    const float* b3  = (const float*)d_in[13];
    float* out = (float*)d_out;

    // workspace layout (~97 MB)
    char* w = (char*)d_ws;
    __hip_bfloat16* hbuf = (__hip_bfloat16*)w;                 // N*448 bf16  (44.8 MB)
    __hip_bfloat16* act  = hbuf + (size_t)NN * 448;            // N*448 bf16  (44.8 MB)
    float* as8 = (float*)(act + (size_t)NN * 448);             // N*8 f32
    float* ad8 = as8 + (size_t)NN * 8;                         // N*8 f32
    int* cnt     = (int*)(ad8 + (size_t)NN * 8);               // N
    int* fillc   = cnt + NN;                                   // N
    int* row_ptr = fillc + NN;                                 // N+1
    int* tmp     = row_ptr + (NN + 1);                         // N
    int* part    = tmp + NN;                                   // 256
    int* colA    = part + 256;                                 // ET

    // --- CSR build (edge_index constant across layers)
    hipMemsetAsync(cnt, 0, 2 * (size_t)NN * sizeof(int), stream);  // cnt + fillc
    int ethreads = 256, eblocks = (ET + 255) / 256;
    gat_count_kernel<<<eblocks, ethreads, 0, stream>>>(ei, cnt);
    gat_scan1_kernel<<<NB_SCAN, 256, 0, stream>>>(cnt, tmp, part);
    gat_scan2_kernel<<<1, 256, 0, stream>>>(part);
    gat_scan3_kernel<<<NB_SCAN, 256, 0, stream>>>(tmp, part, row_ptr);
    gat_fill_kernel<<<eblocks, ethreads, 0, stream>>>(ei, row_ptr, fillc, colA);

    dim3 gemmBlk(256);
    int mtiles = (NN + GBM - 1) / GBM;  // 391
    int aggBlocks = (NN + 3) / 4;       // 12500

    // --- layer 1: x[N,256] @ W1[256,448]   (A fp32)
    gat_gemm_kernel<float><<<dim3(mtiles, 7), gemmBlk, 0, stream>>>(x, W1, hbuf, NN, 256, 448);
    gat_alpha_kernel<<<aggBlocks, 256, 0, stream>>>(hbuf, a1s, a1d, as8, ad8, 7, 64, 448);
    gat_agg7_kernel<<<aggBlocks, 256, 0, stream>>>(row_ptr, colA, as8, ad8, hbuf, b1, act);

    // --- layer 2: act[N,448] @ W2[448,448]   (A bf16)
    gat_gemm_kernel<__hip_bfloat16><<<dim3(mtiles, 7), gemmBlk, 0, stream>>>(act, W2, hbuf, NN, 448, 448);
    gat_alpha_kernel<<<aggBlocks, 256, 0, stream>>>(hbuf, a2s, a2d, as8, ad8, 7, 64, 448);
    gat_agg7_kernel<<<aggBlocks, 256, 0, stream>>>(row_ptr, colA, as8, ad8, hbuf, b2, act);

    // --- layer 3: act[N,448] @ W3[448,32], 1 head, log_softmax (fp32 out)
    gat_gemm_kernel<__hip_bfloat16><<<dim3(mtiles, 1), gemmBlk, 0, stream>>>(act, W3, hbuf, NN, 448, 32);
    gat_alpha_kernel<<<aggBlocks, 256, 0, stream>>>(hbuf, a3s, a3d, as8, ad8, 1, 32, 32);
    gat_aggF_kernel<<<aggBlocks, 256, 0, stream>>>(row_ptr, colA, as8, ad8, hbuf, b3, out);
}

// Round 3
// 807.510 us; speedup vs baseline: 1.2833x; 1.2833x over previous
//
#include <hip/hip_runtime.h>
#include <hip/hip_bf16.h>
#include <hip/hip_fp16.h>

#define NN 50000
#define EE 800000
#define ET (EE + NN)          // 850000 edges incl self-loops
#define NB_SCAN ((NN + 255) / 256)   // 196

typedef __attribute__((ext_vector_type(8))) short bf16x8;
typedef __attribute__((ext_vector_type(4))) float f32x4;

static __device__ __forceinline__ float bf2f(__hip_bfloat16 x) { return __bfloat162float(x); }
static __device__ __forceinline__ ushort f2bu(float f) {
    union { __hip_bfloat16 b; ushort u; } c;
    c.b = __float2bfloat16(f);
    return c.u;
}
// order-preserving float<->uint for atomicMax
static __device__ __forceinline__ unsigned fenc(float f) {
    unsigned b = __float_as_uint(f);
    return (b & 0x80000000u) ? ~b : (b | 0x80000000u);
}
static __device__ __forceinline__ float fdec(unsigned u) {
    unsigned b = (u & 0x80000000u) ? (u & 0x7fffffffu) : ~u;
    return __uint_as_float(b);
}

// ---------------------------------------------------------------- CSR build
__global__ void gat_count_kernel(const int* __restrict__ ei, int* __restrict__ cnt) {
    int i = blockIdx.x * blockDim.x + threadIdx.x;
    if (i >= ET) return;
    int dst = (i < EE) ? ei[EE + i] : (i - EE);
    atomicAdd(&cnt[dst], 1);
}

__global__ void gat_scan1_kernel(const int* __restrict__ cnt, int* __restrict__ tmp,
                                 int* __restrict__ part) {
    __shared__ int sm[256];
    int tid = threadIdx.x;
    int i = blockIdx.x * 256 + tid;
    int v = (i < NN) ? cnt[i] : 0;
    sm[tid] = v;
    __syncthreads();
    for (int o = 1; o < 256; o <<= 1) {
        int t = (tid >= o) ? sm[tid - o] : 0;
        __syncthreads();
        sm[tid] += t;
        __syncthreads();
    }
    if (i < NN) tmp[i] = sm[tid];
    if (tid == 255) part[blockIdx.x] = sm[255];
}

__global__ void gat_scan2_kernel(int* __restrict__ part) {
    __shared__ int sm[256];
    int tid = threadIdx.x;
    int v = (tid < NB_SCAN) ? part[tid] : 0;
    sm[tid] = v;
    __syncthreads();
    for (int o = 1; o < 256; o <<= 1) {
        int t = (tid >= o) ? sm[tid - o] : 0;
        __syncthreads();
        sm[tid] += t;
        __syncthreads();
    }
    part[tid] = sm[tid];
}

__global__ void gat_scan3_kernel(const int* __restrict__ tmp, const int* __restrict__ part,
                                 int* __restrict__ row_ptr) {
    int i = blockIdx.x * 256 + threadIdx.x;
    int off = (blockIdx.x > 0) ? part[blockIdx.x - 1] : 0;
    if (i < NN) row_ptr[i + 1] = tmp[i] + off;
    if (i == 0) row_ptr[0] = 0;
}

__global__ void gat_fill_kernel(const int* __restrict__ ei, const int* __restrict__ row_ptr,
                                int* __restrict__ fillc, int* __restrict__ colA,
                                int* __restrict__ dstA) {
    int i = blockIdx.x * blockDim.x + threadIdx.x;
    if (i >= ET) return;
    int s, d;
    if (i < EE) { s = ei[i]; d = ei[EE + i]; }
    else        { s = d = i - EE; }
    int pos = row_ptr[d] + atomicAdd(&fillc[d], 1);
    colA[pos] = s;
    dstA[pos] = d;
}

// ---------------------------------------------------------------- GEMM core (templated on A dtype)
#define GBM 128
#define GBN 64
#define GBK 32
#define LDP 40

template <typename AT>
__global__ __launch_bounds__(256) void gat_gemm_kernel(
    const AT* __restrict__ A, const float* __restrict__ B,
    __hip_bfloat16* __restrict__ C, int M, int K, int N) {
    __shared__ __align__(16) ushort As[GBM * LDP];
    __shared__ __align__(16) ushort Bs[GBN * LDP];
    int tid = threadIdx.x;
    int wave = tid >> 6, lane = tid & 63;
    int lrow = lane & 15, lq = lane >> 4;
    int m0 = blockIdx.x * GBM, n0 = blockIdx.y * GBN;
    f32x4 acc[2][4] = {};

    for (int k0 = 0; k0 < K; k0 += GBK) {
        __syncthreads();
        {
            int row = tid >> 1, kc = (tid & 1) * 16;
            int gm = m0 + row;
            ushort u[16];
            if constexpr (sizeof(AT) == 4) {  // fp32 A
                float4 f0 = make_float4(0, 0, 0, 0), f1 = f0, f2 = f0, f3 = f0;
                if (gm < M) {
                    const float4* p = (const float4*)((const float*)A + (size_t)gm * K + k0 + kc);
                    f0 = p[0]; f1 = p[1]; f2 = p[2]; f3 = p[3];
                }
                u[0] = f2bu(f0.x); u[1] = f2bu(f0.y); u[2] = f2bu(f0.z); u[3] = f2bu(f0.w);
                u[4] = f2bu(f1.x); u[5] = f2bu(f1.y); u[6] = f2bu(f1.z); u[7] = f2bu(f1.w);
                u[8] = f2bu(f2.x); u[9] = f2bu(f2.y); u[10] = f2bu(f2.z); u[11] = f2bu(f2.w);
                u[12] = f2bu(f3.x); u[13] = f2bu(f3.y); u[14] = f2bu(f3.z); u[15] = f2bu(f3.w);
            } else {  // bf16 A
                uint4 z0 = make_uint4(0, 0, 0, 0), z1 = z0;
                if (gm < M) {
                    const uint4* p = (const uint4*)((const ushort*)A + (size_t)gm * K + k0 + kc);
                    z0 = p[0]; z1 = p[1];
                }
                *(uint4*)&u[0] = z0;
                *(uint4*)&u[8] = z1;
            }
            *(uint4*)&As[row * LDP + kc] = *(const uint4*)&u[0];
            *(uint4*)&As[row * LDP + kc + 8] = *(const uint4*)&u[8];
        }
        {
            int kk = tid >> 3, nc = (tid & 7) * 8;
            float4 g0 = make_float4(0, 0, 0, 0), g1 = g0;
            if (n0 + nc < N) {
                const float4* p = (const float4*)(B + (size_t)(k0 + kk) * N + n0 + nc);
                g0 = p[0]; g1 = p[1];
            }
            ushort t8[8];
            t8[0] = f2bu(g0.x); t8[1] = f2bu(g0.y); t8[2] = f2bu(g0.z); t8[3] = f2bu(g0.w);
            t8[4] = f2bu(g1.x); t8[5] = f2bu(g1.y); t8[6] = f2bu(g1.z); t8[7] = f2bu(g1.w);
#pragma unroll
            for (int j = 0; j < 8; j++) Bs[(nc + j) * LDP + kk] = t8[j];
        }
        __syncthreads();

        bf16x8 af0 = *(const bf16x8*)&As[(wave * 32 + lrow) * LDP + lq * 8];
        bf16x8 af1 = *(const bf16x8*)&As[(wave * 32 + 16 + lrow) * LDP + lq * 8];
#pragma unroll
        for (int ng = 0; ng < 4; ng++) {
            bf16x8 bf = *(const bf16x8*)&Bs[(ng * 16 + lrow) * LDP + lq * 8];
            acc[0][ng] = __builtin_amdgcn_mfma_f32_16x16x32_bf16(af0, bf, acc[0][ng], 0, 0, 0);
            acc[1][ng] = __builtin_amdgcn_mfma_f32_16x16x32_bf16(af1, bf, acc[1][ng], 0, 0, 0);
        }
    }
#pragma unroll
    for (int rs = 0; rs < 2; rs++)
#pragma unroll
        for (int ng = 0; ng < 4; ng++)
#pragma unroll
            for (int r = 0; r < 4; r++) {
                int row = m0 + wave * 32 + rs * 16 + lq * 4 + r;
                int colI = n0 + ng * 16 + lrow;
                if (row < M && colI < N)
                    C[(size_t)row * N + colI] = __float2bfloat16(acc[rs][ng][r]);
            }
}

// ---------------------------------------------------------------- alpha dots
__global__ void gat_alpha_kernel(const __hip_bfloat16* __restrict__ h,
                                 const float* __restrict__ a_src,
                                 const float* __restrict__ a_dst,
                                 float* __restrict__ as8, float* __restrict__ ad8,
                                 int heads, int C, int HW) {
    int node = blockIdx.x * 4 + (threadIdx.x >> 6);
    if (node >= NN) return;
    int lane = threadIdx.x & 63;
    for (int hh = 0; hh < heads; hh++) {
        float v = 0.f, cs = 0.f, cd = 0.f;
        if (lane < C) {
            v = bf2f(h[(size_t)node * HW + hh * C + lane]);
            cs = a_src[hh * C + lane];
            cd = a_dst[hh * C + lane];
        }
        float ps = v * cs, pd = v * cd;
#pragma unroll
        for (int o = 32; o > 0; o >>= 1) {
            ps += __shfl_xor(ps, o);
            pd += __shfl_xor(pd, o);
        }
        if (lane == 0) {
            as8[(size_t)node * 8 + hh] = ps;
            ad8[(size_t)node * 8 + hh] = pd;
        }
    }
}

// ---------------------------------------------------------------- Phase A: edge-parallel per-dst max
template <int H>
__global__ void gat_emax_kernel(const int* __restrict__ colA, const int* __restrict__ dstA,
                                const float* __restrict__ as8, const float* __restrict__ ad8,
                                unsigned int* __restrict__ mbuf) {
    int j = blockIdx.x * 256 + threadIdx.x;
    int lane = threadIdx.x & 63;
    bool valid = (j < ET);
    int jc = valid ? j : (ET - 1);
    int s = colA[jc];
    int d = valid ? dstA[jc] : -1;
    int dl = (d < 0) ? 0 : d;
    float e[H];
    if constexpr (H == 7) {
        const float4* pa = (const float4*)(as8 + (size_t)s * 8);
        const float4* pd = (const float4*)(ad8 + (size_t)dl * 8);
        float4 a0 = pa[0], a1 = pa[1], b0 = pd[0], b1 = pd[1];
        float av[7] = {a0.x, a0.y, a0.z, a0.w, a1.x, a1.y, a1.z};
        float dv[7] = {b0.x, b0.y, b0.z, b0.w, b1.x, b1.y, b1.z};
#pragma unroll
        for (int h = 0; h < 7; h++) {
            float v = av[h] + dv[h];
            e[h] = (v > 0.f) ? v : 0.2f * v;
        }
    } else {
        float v = as8[(size_t)s * 8] + ad8[(size_t)dl * 8];
        e[0] = (v > 0.f) ? v : 0.2f * v;
    }
    // segmented max over dst-sorted edges within the wave
    for (int off = 1; off < 64; off <<= 1) {
        int dd = __shfl_up(d, off);
#pragma unroll
        for (int h = 0; h < H; h++) {
            float ee = __shfl_up(e[h], off);
            if (lane >= off && dd == d) e[h] = fmaxf(e[h], ee);
        }
    }
    int dnext = __shfl_down(d, 1);
    bool leader = (lane == 63) || (dnext != d);
    if (leader && d >= 0) {
#pragma unroll
        for (int h = 0; h < H; h++)
            atomicMax(&mbuf[(size_t)d * 8 + h], fenc(e[h]));
    }
}

// ---------------------------------------------------------------- Phase B: edge-parallel exp weights (fp16)
template <int H>
__global__ void gat_expw_kernel(const int* __restrict__ colA, const int* __restrict__ dstA,
                                const float* __restrict__ as8, const float* __restrict__ ad8,
                                const unsigned int* __restrict__ mbuf,
                                ushort* __restrict__ wbuf) {
    int j = blockIdx.x * 256 + threadIdx.x;
    if (j >= ET) return;
    int s = colA[j], d = dstA[j];
    ushort w8[8] = {0, 0, 0, 0, 0, 0, 0, 0};
    if constexpr (H == 7) {
        const float4* pa = (const float4*)(as8 + (size_t)s * 8);
        const float4* pd = (const float4*)(ad8 + (size_t)d * 8);
        float4 a0 = pa[0], a1 = pa[1], b0 = pd[0], b1 = pd[1];
        float av[7] = {a0.x, a0.y, a0.z, a0.w, a1.x, a1.y, a1.z};
        float dv[7] = {b0.x, b0.y, b0.z, b0.w, b1.x, b1.y, b1.z};
#pragma unroll
        for (int h = 0; h < 7; h++) {
            float v = av[h] + dv[h];
            v = (v > 0.f) ? v : 0.2f * v;
            float m = fdec(mbuf[(size_t)d * 8 + h]);
            float w = __expf(v - m);
            w8[h] = __half_as_ushort(__float2half(w));
        }
    } else {
        float v = as8[(size_t)s * 8] + ad8[(size_t)d * 8];
        v = (v > 0.f) ? v : 0.2f * v;
        float m = fdec(mbuf[(size_t)d * 8]);
        float w = __expf(v - m);
        w8[0] = __half_as_ushort(__float2half(w));
    }
    *(uint4*)&wbuf[(size_t)j * 8] = *(const uint4*)&w8[0];
}

// ---------------------------------------------------------------- Phase C: wave-per-dst accumulate (7 heads x 64 ch)
__global__ void gat_aggC7_kernel(const int* __restrict__ rp, const int* __restrict__ colA,
                                 const ushort* __restrict__ wbuf,
                                 const __hip_bfloat16* __restrict__ h,
                                 const float* __restrict__ bias,
                                 __hip_bfloat16* __restrict__ outp) {
    int d = blockIdx.x * 4 + (threadIdx.x >> 6);
    if (d >= NN) return;
    int lane = threadIdx.x & 63;
    int s0 = rp[d], s1 = rp[d + 1];
    float acc[7] = {0.f, 0.f, 0.f, 0.f, 0.f, 0.f, 0.f};
    float den[7] = {0.f, 0.f, 0.f, 0.f, 0.f, 0.f, 0.f};
    for (int j = s0; j < s1; j++) {
        int s = colA[j];
        uint4 wv = *(const uint4*)&wbuf[(size_t)j * 8];
        const __half2* hw = (const __half2*)&wv;
        float2 w01 = __half22float2(hw[0]);
        float2 w23 = __half22float2(hw[1]);
        float2 w45 = __half22float2(hw[2]);
        float2 w67 = __half22float2(hw[3]);
        float w[7] = {w01.x, w01.y, w23.x, w23.y, w45.x, w45.y, w67.x};
        const __hip_bfloat16* hs = h + (size_t)s * 448;
#pragma unroll
        for (int hh = 0; hh < 7; hh++) {
            den[hh] += w[hh];
            acc[hh] += w[hh] * bf2f(hs[hh * 64 + lane]);
        }
    }
#pragma unroll
    for (int hh = 0; hh < 7; hh++) {
        float o = acc[hh] / (den[hh] + 1e-16f) + bias[hh * 64 + lane];
        o = fmaxf(o, 0.f);
        outp[(size_t)d * 448 + hh * 64 + lane] = __float2bfloat16(o);
    }
}

// ---------------------------------------------------------------- Phase C final: 2 dsts/wave, 32 ch, log_softmax
__global__ void gat_aggCF_kernel(const int* __restrict__ rp, const int* __restrict__ colA,
                                 const ushort* __restrict__ wbuf,
                                 const __hip_bfloat16* __restrict__ h,
                                 const float* __restrict__ bias,
                                 float* __restrict__ outp) {
    int wid = blockIdx.x * 4 + (threadIdx.x >> 6);
    int lane = threadIdx.x & 63;
    int half = lane >> 5, c = lane & 31;
    int dreal = wid * 2 + half;
    bool valid = dreal < NN;
    int d = valid ? dreal : (NN - 1);
    int s0 = rp[d], s1 = rp[d + 1];
    float acc = 0.f, den = 0.f;
    for (int j = s0; j < s1; j++) {
        int s = colA[j];
        float w = __half2float(__ushort_as_half(wbuf[(size_t)j * 8]));
        den += w;
        acc += w * bf2f(h[(size_t)s * 32 + c]);
    }
    float o = acc / (den + 1e-16f) + bias[c];
    float t = o;
#pragma unroll
    for (int off = 16; off > 0; off >>= 1) t = fmaxf(t, __shfl_xor(t, off));
    float ex = __expf(o - t);
#pragma unroll
    for (int off = 16; off > 0; off >>= 1) ex += __shfl_xor(ex, off);
    float res = o - t - __logf(ex);
    if (valid) outp[(size_t)d * 32 + c] = res;
}

// ---------------------------------------------------------------- launch
extern "C" void kernel_launch(void* const* d_in, const int* in_sizes, int n_in,
                              void* d_out, int out_size, void* d_ws, size_t ws_size,
                              hipStream_t stream) {
    const float* x   = (const float*)d_in[0];
    const int*   ei  = (const int*)d_in[1];
    const float* W1  = (const float*)d_in[2];
    const float* a1s = (const float*)d_in[3];
    const float* a1d = (const float*)d_in[4];
    const float* b1  = (const float*)d_in[5];
    const float* W2  = (const float*)d_in[6];
    const float* a2s = (const float*)d_in[7];
    const float* a2d = (const float*)d_in[8];
    const float* b2  = (const float*)d_in[9];
    const float* W3  = (const float*)d_in[10];
    const float* a3s = (const float*)d_in[11];
    const float* a3d = (const float*)d_in[12];
    const float* b3  = (const float*)d_in[13];
    float* out = (float*)d_out;

    // workspace layout (~116 MB)
    char* w = (char*)d_ws;
    __hip_bfloat16* hbuf = (__hip_bfloat16*)w;                 // N*448 bf16
    __hip_bfloat16* act  = hbuf + (size_t)NN * 448;            // N*448 bf16
    float* as8 = (float*)(act + (size_t)NN * 448);             // N*8 f32
    float* ad8 = as8 + (size_t)NN * 8;                         // N*8 f32
    unsigned int* mbuf = (unsigned int*)(ad8 + (size_t)NN * 8);// N*8 u32
    int* cnt     = (int*)(mbuf + (size_t)NN * 8);              // N
    int* fillc   = cnt + NN;                                   // N
    int* row_ptr = fillc + NN;                                 // N+4 (padded)
    int* tmp     = row_ptr + (NN + 4);                         // N
    int* part    = tmp + NN;                                   // 256
    int* colA    = part + 256;                                 // ET
    int* dstA    = colA + ET;                                  // ET
    ushort* wbuf = (ushort*)(dstA + ET);                       // ET*8 fp16

    hipMemsetAsync(cnt, 0, 2 * (size_t)NN * sizeof(int), stream);  // cnt + fillc
    int eblocks = (ET + 255) / 256;
    gat_count_kernel<<<eblocks, 256, 0, stream>>>(ei, cnt);
    gat_scan1_kernel<<<NB_SCAN, 256, 0, stream>>>(cnt, tmp, part);
    gat_scan2_kernel<<<1, 256, 0, stream>>>(part);
    gat_scan3_kernel<<<NB_SCAN, 256, 0, stream>>>(tmp, part, row_ptr);
    gat_fill_kernel<<<eblocks, 256, 0, stream>>>(ei, row_ptr, fillc, colA, dstA);

    dim3 gemmBlk(256);
    int mtiles = (NN + GBM - 1) / GBM;  // 391
    int aggBlocks = (NN + 3) / 4;       // 12500
    size_t mbytes = (size_t)NN * 8 * sizeof(unsigned int);

    // --- layer 1
    gat_gemm_kernel<float><<<dim3(mtiles, 7), gemmBlk, 0, stream>>>(x, W1, hbuf, NN, 256, 448);
    gat_alpha_kernel<<<aggBlocks, 256, 0, stream>>>(hbuf, a1s, a1d, as8, ad8, 7, 64, 448);
    hipMemsetAsync(mbuf, 0, mbytes, stream);
    gat_emax_kernel<7><<<eblocks, 256, 0, stream>>>(colA, dstA, as8, ad8, mbuf);
    gat_expw_kernel<7><<<eblocks, 256, 0, stream>>>(colA, dstA, as8, ad8, mbuf, wbuf);
    gat_aggC7_kernel<<<aggBlocks, 256, 0, stream>>>(row_ptr, colA, wbuf, hbuf, b1, act);

    // --- layer 2
    gat_gemm_kernel<__hip_bfloat16><<<dim3(mtiles, 7), gemmBlk, 0, stream>>>(act, W2, hbuf, NN, 448, 448);
    gat_alpha_kernel<<<aggBlocks, 256, 0, stream>>>(hbuf, a2s, a2d, as8, ad8, 7, 64, 448);
    hipMemsetAsync(mbuf, 0, mbytes, stream);
    gat_emax_kernel<7><<<eblocks, 256, 0, stream>>>(colA, dstA, as8, ad8, mbuf);
    gat_expw_kernel<7><<<eblocks, 256, 0, stream>>>(colA, dstA, as8, ad8, mbuf, wbuf);
    gat_aggC7_kernel<<<aggBlocks, 256, 0, stream>>>(row_ptr, colA, wbuf, hbuf, b2, act);

    // --- layer 3 (1 head, 32 ch, log_softmax, fp32 out)
    gat_gemm_kernel<__hip_bfloat16><<<dim3(mtiles, 1), gemmBlk, 0, stream>>>(act, W3, hbuf, NN, 448, 32);
    gat_alpha_kernel<<<aggBlocks, 256, 0, stream>>>(hbuf, a3s, a3d, as8, ad8, 1, 32, 32);
    hipMemsetAsync(mbuf, 0, mbytes, stream);
    gat_emax_kernel<1><<<eblocks, 256, 0, stream>>>(colA, dstA, as8, ad8, mbuf);
    gat_expw_kernel<1><<<eblocks, 256, 0, stream>>>(colA, dstA, as8, ad8, mbuf, wbuf);
    int fBlocks = (NN + 7) / 8;  // 8 dsts per block (2 per wave)
    gat_aggCF_kernel<<<fBlocks, 256, 0, stream>>>(row_ptr, colA, wbuf, hbuf, b3, out);
}

// Round 4
// 782.610 us; speedup vs baseline: 1.3241x; 1.0318x over previous
//
#include <hip/hip_runtime.h>
#include <hip/hip_bf16.h>
#include <hip/hip_fp16.h>

#define NN 50000
#define EE 800000
#define ET (EE + NN)          // 850000 edges incl self-loops
#define NB_SCAN ((NN + 255) / 256)   // 196

typedef __attribute__((ext_vector_type(8))) short bf16x8;
typedef __attribute__((ext_vector_type(4))) float f32x4;

static __device__ __forceinline__ float bf2f(__hip_bfloat16 x) { return __bfloat162float(x); }
static __device__ __forceinline__ ushort f2bu(float f) {
    union { __hip_bfloat16 b; ushort u; } c;
    c.b = __float2bfloat16(f);
    return c.u;
}
static __device__ __forceinline__ float u2f(ushort u) {
    union { ushort u; __hip_bfloat16 b; } c;
    c.u = u;
    return __bfloat162float(c.b);
}
// order-preserving float<->uint for atomicMax
static __device__ __forceinline__ unsigned fenc(float f) {
    unsigned b = __float_as_uint(f);
    return (b & 0x80000000u) ? ~b : (b | 0x80000000u);
}
static __device__ __forceinline__ float fdec(unsigned u) {
    unsigned b = (u & 0x80000000u) ? (u & 0x7fffffffu) : ~u;
    return __uint_as_float(b);
}

// ---------------------------------------------------------------- CSR build
__global__ void gat_count_kernel(const int* __restrict__ ei, int* __restrict__ cnt) {
    int i = blockIdx.x * blockDim.x + threadIdx.x;
    if (i >= ET) return;
    int dst = (i < EE) ? ei[EE + i] : (i - EE);
    atomicAdd(&cnt[dst], 1);
}

__global__ void gat_scan1_kernel(const int* __restrict__ cnt, int* __restrict__ tmp,
                                 int* __restrict__ part) {
    __shared__ int sm[256];
    int tid = threadIdx.x;
    int i = blockIdx.x * 256 + tid;
    int v = (i < NN) ? cnt[i] : 0;
    sm[tid] = v;
    __syncthreads();
    for (int o = 1; o < 256; o <<= 1) {
        int t = (tid >= o) ? sm[tid - o] : 0;
        __syncthreads();
        sm[tid] += t;
        __syncthreads();
    }
    if (i < NN) tmp[i] = sm[tid];
    if (tid == 255) part[blockIdx.x] = sm[255];
}

__global__ void gat_scan2_kernel(int* __restrict__ part) {
    __shared__ int sm[256];
    int tid = threadIdx.x;
    int v = (tid < NB_SCAN) ? part[tid] : 0;
    sm[tid] = v;
    __syncthreads();
    for (int o = 1; o < 256; o <<= 1) {
        int t = (tid >= o) ? sm[tid - o] : 0;
        __syncthreads();
        sm[tid] += t;
        __syncthreads();
    }
    part[tid] = sm[tid];
}

__global__ void gat_scan3_kernel(const int* __restrict__ tmp, const int* __restrict__ part,
                                 int* __restrict__ row_ptr) {
    int i = blockIdx.x * 256 + threadIdx.x;
    int off = (blockIdx.x > 0) ? part[blockIdx.x - 1] : 0;
    if (i < NN) row_ptr[i + 1] = tmp[i] + off;
    if (i == 0) row_ptr[0] = 0;
}

__global__ void gat_fill_kernel(const int* __restrict__ ei, const int* __restrict__ row_ptr,
                                int* __restrict__ fillc, int* __restrict__ colA,
                                int* __restrict__ dstA) {
    int i = blockIdx.x * blockDim.x + threadIdx.x;
    if (i >= ET) return;
    int s, d;
    if (i < EE) { s = ei[i]; d = ei[EE + i]; }
    else        { s = d = i - EE; }
    int pos = row_ptr[d] + atomicAdd(&fillc[d], 1);
    colA[pos] = s;
    dstA[pos] = d;
}

// ---------------------------------------------------------------- GEMM core (templated on A dtype)
#define GBM 128
#define GBN 64
#define GBK 32
#define LDP 40

template <typename AT>
__global__ __launch_bounds__(256) void gat_gemm_kernel(
    const AT* __restrict__ A, const float* __restrict__ B,
    __hip_bfloat16* __restrict__ C, int M, int K, int N) {
    __shared__ __align__(16) ushort As[GBM * LDP];
    __shared__ __align__(16) ushort Bs[GBN * LDP];
    int tid = threadIdx.x;
    int wave = tid >> 6, lane = tid & 63;
    int lrow = lane & 15, lq = lane >> 4;
    int m0 = blockIdx.x * GBM, n0 = blockIdx.y * GBN;
    f32x4 acc[2][4] = {};

    for (int k0 = 0; k0 < K; k0 += GBK) {
        __syncthreads();
        {
            int row = tid >> 1, kc = (tid & 1) * 16;
            int gm = m0 + row;
            ushort u[16];
            if constexpr (sizeof(AT) == 4) {  // fp32 A
                float4 f0 = make_float4(0, 0, 0, 0), f1 = f0, f2 = f0, f3 = f0;
                if (gm < M) {
                    const float4* p = (const float4*)((const float*)A + (size_t)gm * K + k0 + kc);
                    f0 = p[0]; f1 = p[1]; f2 = p[2]; f3 = p[3];
                }
                u[0] = f2bu(f0.x); u[1] = f2bu(f0.y); u[2] = f2bu(f0.z); u[3] = f2bu(f0.w);
                u[4] = f2bu(f1.x); u[5] = f2bu(f1.y); u[6] = f2bu(f1.z); u[7] = f2bu(f1.w);
                u[8] = f2bu(f2.x); u[9] = f2bu(f2.y); u[10] = f2bu(f2.z); u[11] = f2bu(f2.w);
                u[12] = f2bu(f3.x); u[13] = f2bu(f3.y); u[14] = f2bu(f3.z); u[15] = f2bu(f3.w);
            } else {  // bf16 A
                uint4 z0 = make_uint4(0, 0, 0, 0), z1 = z0;
                if (gm < M) {
                    const uint4* p = (const uint4*)((const ushort*)A + (size_t)gm * K + k0 + kc);
                    z0 = p[0]; z1 = p[1];
                }
                *(uint4*)&u[0] = z0;
                *(uint4*)&u[8] = z1;
            }
            *(uint4*)&As[row * LDP + kc] = *(const uint4*)&u[0];
            *(uint4*)&As[row * LDP + kc + 8] = *(const uint4*)&u[8];
        }
        {
            int kk = tid >> 3, nc = (tid & 7) * 8;
            float4 g0 = make_float4(0, 0, 0, 0), g1 = g0;
            if (n0 + nc < N) {
                const float4* p = (const float4*)(B + (size_t)(k0 + kk) * N + n0 + nc);
                g0 = p[0]; g1 = p[1];
            }
            ushort t8[8];
            t8[0] = f2bu(g0.x); t8[1] = f2bu(g0.y); t8[2] = f2bu(g0.z); t8[3] = f2bu(g0.w);
            t8[4] = f2bu(g1.x); t8[5] = f2bu(g1.y); t8[6] = f2bu(g1.z); t8[7] = f2bu(g1.w);
#pragma unroll
            for (int j = 0; j < 8; j++) Bs[(nc + j) * LDP + kk] = t8[j];
        }
        __syncthreads();

        bf16x8 af0 = *(const bf16x8*)&As[(wave * 32 + lrow) * LDP + lq * 8];
        bf16x8 af1 = *(const bf16x8*)&As[(wave * 32 + 16 + lrow) * LDP + lq * 8];
#pragma unroll
        for (int ng = 0; ng < 4; ng++) {
            bf16x8 bf = *(const bf16x8*)&Bs[(ng * 16 + lrow) * LDP + lq * 8];
            acc[0][ng] = __builtin_amdgcn_mfma_f32_16x16x32_bf16(af0, bf, acc[0][ng], 0, 0, 0);
            acc[1][ng] = __builtin_amdgcn_mfma_f32_16x16x32_bf16(af1, bf, acc[1][ng], 0, 0, 0);
        }
    }
#pragma unroll
    for (int rs = 0; rs < 2; rs++)
#pragma unroll
        for (int ng = 0; ng < 4; ng++)
#pragma unroll
            for (int r = 0; r < 4; r++) {
                int row = m0 + wave * 32 + rs * 16 + lq * 4 + r;
                int colI = n0 + ng * 16 + lrow;
                if (row < M && colI < N)
                    C[(size_t)row * N + colI] = __float2bfloat16(acc[rs][ng][r]);
            }
}

// ---------------------------------------------------------------- alpha dots
__global__ void gat_alpha_kernel(const __hip_bfloat16* __restrict__ h,
                                 const float* __restrict__ a_src,
                                 const float* __restrict__ a_dst,
                                 float* __restrict__ as8, float* __restrict__ ad8,
                                 int heads, int C, int HW) {
    int node = blockIdx.x * 4 + (threadIdx.x >> 6);
    if (node >= NN) return;
    int lane = threadIdx.x & 63;
    for (int hh = 0; hh < heads; hh++) {
        float v = 0.f, cs = 0.f, cd = 0.f;
        if (lane < C) {
            v = bf2f(h[(size_t)node * HW + hh * C + lane]);
            cs = a_src[hh * C + lane];
            cd = a_dst[hh * C + lane];
        }
        float ps = v * cs, pd = v * cd;
#pragma unroll
        for (int o = 32; o > 0; o >>= 1) {
            ps += __shfl_xor(ps, o);
            pd += __shfl_xor(pd, o);
        }
        if (lane == 0) {
            as8[(size_t)node * 8 + hh] = ps;
            ad8[(size_t)node * 8 + hh] = pd;
        }
    }
}

// ---------------------------------------------------------------- Phase A: edge-parallel per-dst max
template <int H>
__global__ void gat_emax_kernel(const int* __restrict__ colA, const int* __restrict__ dstA,
                                const float* __restrict__ as8, const float* __restrict__ ad8,
                                unsigned int* __restrict__ mbuf) {
    int j = blockIdx.x * 256 + threadIdx.x;
    int lane = threadIdx.x & 63;
    bool valid = (j < ET);
    int jc = valid ? j : (ET - 1);
    int s = colA[jc];
    int d = valid ? dstA[jc] : -1;
    int dl = (d < 0) ? 0 : d;
    float e[H];
    if constexpr (H == 7) {
        const float4* pa = (const float4*)(as8 + (size_t)s * 8);
        const float4* pd = (const float4*)(ad8 + (size_t)dl * 8);
        float4 a0 = pa[0], a1 = pa[1], b0 = pd[0], b1 = pd[1];
        float av[7] = {a0.x, a0.y, a0.z, a0.w, a1.x, a1.y, a1.z};
        float dv[7] = {b0.x, b0.y, b0.z, b0.w, b1.x, b1.y, b1.z};
#pragma unroll
        for (int h = 0; h < 7; h++) {
            float v = av[h] + dv[h];
            e[h] = (v > 0.f) ? v : 0.2f * v;
        }
    } else {
        float v = as8[(size_t)s * 8] + ad8[(size_t)dl * 8];
        e[0] = (v > 0.f) ? v : 0.2f * v;
    }
    // segmented max over dst-sorted edges within the wave
    for (int off = 1; off < 64; off <<= 1) {
        int dd = __shfl_up(d, off);
#pragma unroll
        for (int h = 0; h < H; h++) {
            float ee = __shfl_up(e[h], off);
            if (lane >= off && dd == d) e[h] = fmaxf(e[h], ee);
        }
    }
    int dnext = __shfl_down(d, 1);
    bool leader = (lane == 63) || (dnext != d);
    if (leader && d >= 0) {
#pragma unroll
        for (int h = 0; h < H; h++)
            atomicMax(&mbuf[(size_t)d * 8 + h], fenc(e[h]));
    }
}

// ---------------------------------------------------------------- Phase B: edge-parallel exp weights (fp16)
template <int H>
__global__ void gat_expw_kernel(const int* __restrict__ colA, const int* __restrict__ dstA,
                                const float* __restrict__ as8, const float* __restrict__ ad8,
                                const unsigned int* __restrict__ mbuf,
                                ushort* __restrict__ wbuf) {
    int j = blockIdx.x * 256 + threadIdx.x;
    if (j >= ET) return;
    int s = colA[j], d = dstA[j];
    ushort w8[8] = {0, 0, 0, 0, 0, 0, 0, 0};
    if constexpr (H == 7) {
        const float4* pa = (const float4*)(as8 + (size_t)s * 8);
        const float4* pd = (const float4*)(ad8 + (size_t)d * 8);
        float4 a0 = pa[0], a1 = pa[1], b0 = pd[0], b1 = pd[1];
        float av[7] = {a0.x, a0.y, a0.z, a0.w, a1.x, a1.y, a1.z};
        float dv[7] = {b0.x, b0.y, b0.z, b0.w, b1.x, b1.y, b1.z};
#pragma unroll
        for (int h = 0; h < 7; h++) {
            float v = av[h] + dv[h];
            v = (v > 0.f) ? v : 0.2f * v;
            float m = fdec(mbuf[(size_t)d * 8 + h]);
            float w = __expf(v - m);
            w8[h] = __half_as_ushort(__float2half(w));
        }
    } else {
        float v = as8[(size_t)s * 8] + ad8[(size_t)d * 8];
        v = (v > 0.f) ? v : 0.2f * v;
        float m = fdec(mbuf[(size_t)d * 8]);
        float w = __expf(v - m);
        w8[0] = __half_as_ushort(__float2half(w));
    }
    *(uint4*)&wbuf[(size_t)j * 8] = *(const uint4*)&w8[0];
}

// ---------------------------------------------------------------- Phase C: wave-per-dst accumulate
// lane l<56 owns head l>>3, channels 8l..8l+7 (16B/lane gather+store)
__global__ void gat_aggC7_kernel(const int* __restrict__ rp, const int* __restrict__ colA,
                                 const ushort* __restrict__ wbuf,
                                 const __hip_bfloat16* __restrict__ h,
                                 const float* __restrict__ bias,
                                 __hip_bfloat16* __restrict__ outp) {
    int d = blockIdx.x * 4 + (threadIdx.x >> 6);
    if (d >= NN) return;
    int lane = threadIdx.x & 63;
    if (lane >= 56) return;
    int hh = lane >> 3;
    const ushort* hu = (const ushort*)h;
    int s0 = rp[d], s1 = rp[d + 1];
    float acc[8] = {0.f, 0.f, 0.f, 0.f, 0.f, 0.f, 0.f, 0.f};
    float den = 0.f;
#pragma unroll 2
    for (int j = s0; j < s1; j++) {
        int s = colA[j];
        float w = __half2float(__ushort_as_half(wbuf[(size_t)j * 8 + hh]));
        uint4 hv = *(const uint4*)(hu + (size_t)s * 448 + lane * 8);
        const ushort* hp = (const ushort*)&hv;
        den += w;
#pragma unroll
        for (int k = 0; k < 8; k++) acc[k] += w * u2f(hp[k]);
    }
    float inv = 1.f / (den + 1e-16f);
    const float4* bp = (const float4*)(bias + lane * 8);
    float4 bb0 = bp[0], bb1 = bp[1];
    float bv[8] = {bb0.x, bb0.y, bb0.z, bb0.w, bb1.x, bb1.y, bb1.z, bb1.w};
    ushort o8[8];
#pragma unroll
    for (int k = 0; k < 8; k++) {
        float o = acc[k] * inv + bv[k];
        o = fmaxf(o, 0.f);
        o8[k] = f2bu(o);
    }
    *(uint4*)((ushort*)outp + (size_t)d * 448 + lane * 8) = *(const uint4*)o8;
}

// ---------------------------------------------------------------- Phase C final: 2 dsts/wave, 32 ch, log_softmax
__global__ void gat_aggCF_kernel(const int* __restrict__ rp, const int* __restrict__ colA,
                                 const ushort* __restrict__ wbuf,
                                 const __hip_bfloat16* __restrict__ h,
                                 const float* __restrict__ bias,
                                 float* __restrict__ outp) {
    int wid = blockIdx.x * 4 + (threadIdx.x >> 6);
    int lane = threadIdx.x & 63;
    int half = lane >> 5, c = lane & 31;
    int dreal = wid * 2 + half;
    bool valid = dreal < NN;
    int d = valid ? dreal : (NN - 1);
    int s0 = rp[d], s1 = rp[d + 1];
    float acc = 0.f, den = 0.f;
    for (int j = s0; j < s1; j++) {
        int s = colA[j];
        float w = __half2float(__ushort_as_half(wbuf[(size_t)j * 8]));
        den += w;
        acc += w * bf2f(h[(size_t)s * 32 + c]);
    }
    float o = acc / (den + 1e-16f) + bias[c];
    float t = o;
#pragma unroll
    for (int off = 16; off > 0; off >>= 1) t = fmaxf(t, __shfl_xor(t, off));
    float ex = __expf(o - t);
#pragma unroll
    for (int off = 16; off > 0; off >>= 1) ex += __shfl_xor(ex, off);
    float res = o - t - __logf(ex);
    if (valid) outp[(size_t)d * 32 + c] = res;
}

// ---------------------------------------------------------------- launch
extern "C" void kernel_launch(void* const* d_in, const int* in_sizes, int n_in,
                              void* d_out, int out_size, void* d_ws, size_t ws_size,
                              hipStream_t stream) {
    const float* x   = (const float*)d_in[0];
    const int*   ei  = (const int*)d_in[1];
    const float* W1  = (const float*)d_in[2];
    const float* a1s = (const float*)d_in[3];
    const float* a1d = (const float*)d_in[4];
    const float* b1  = (const float*)d_in[5];
    const float* W2  = (const float*)d_in[6];
    const float* a2s = (const float*)d_in[7];
    const float* a2d = (const float*)d_in[8];
    const float* b2  = (const float*)d_in[9];
    const float* W3  = (const float*)d_in[10];
    const float* a3s = (const float*)d_in[11];
    const float* a3d = (const float*)d_in[12];
    const float* b3  = (const float*)d_in[13];
    float* out = (float*)d_out;

    // workspace layout (~116 MB)
    char* w = (char*)d_ws;
    __hip_bfloat16* hbuf = (__hip_bfloat16*)w;                 // N*448 bf16
    __hip_bfloat16* act  = hbuf + (size_t)NN * 448;            // N*448 bf16
    float* as8 = (float*)(act + (size_t)NN * 448);             // N*8 f32
    float* ad8 = as8 + (size_t)NN * 8;                         // N*8 f32
    unsigned int* mbuf = (unsigned int*)(ad8 + (size_t)NN * 8);// N*8 u32
    int* cnt     = (int*)(mbuf + (size_t)NN * 8);              // N
    int* fillc   = cnt + NN;                                   // N
    int* row_ptr = fillc + NN;                                 // N+4 (padded)
    int* tmp     = row_ptr + (NN + 4);                         // N
    int* part    = tmp + NN;                                   // 256
    int* colA    = part + 256;                                 // ET
    int* dstA    = colA + ET;                                  // ET
    ushort* wbuf = (ushort*)(dstA + ET);                       // ET*8 fp16

    hipMemsetAsync(cnt, 0, 2 * (size_t)NN * sizeof(int), stream);  // cnt + fillc
    int eblocks = (ET + 255) / 256;
    gat_count_kernel<<<eblocks, 256, 0, stream>>>(ei, cnt);
    gat_scan1_kernel<<<NB_SCAN, 256, 0, stream>>>(cnt, tmp, part);
    gat_scan2_kernel<<<1, 256, 0, stream>>>(part);
    gat_scan3_kernel<<<NB_SCAN, 256, 0, stream>>>(tmp, part, row_ptr);
    gat_fill_kernel<<<eblocks, 256, 0, stream>>>(ei, row_ptr, fillc, colA, dstA);

    dim3 gemmBlk(256);
    int mtiles = (NN + GBM - 1) / GBM;  // 391
    int aggBlocks = (NN + 3) / 4;       // 12500
    size_t mbytes = (size_t)NN * 8 * sizeof(unsigned int);

    // --- layer 1
    gat_gemm_kernel<float><<<dim3(mtiles, 7), gemmBlk, 0, stream>>>(x, W1, hbuf, NN, 256, 448);
    gat_alpha_kernel<<<aggBlocks, 256, 0, stream>>>(hbuf, a1s, a1d, as8, ad8, 7, 64, 448);
    hipMemsetAsync(mbuf, 0, mbytes, stream);
    gat_emax_kernel<7><<<eblocks, 256, 0, stream>>>(colA, dstA, as8, ad8, mbuf);
    gat_expw_kernel<7><<<eblocks, 256, 0, stream>>>(colA, dstA, as8, ad8, mbuf, wbuf);
    gat_aggC7_kernel<<<aggBlocks, 256, 0, stream>>>(row_ptr, colA, wbuf, hbuf, b1, act);

    // --- layer 2
    gat_gemm_kernel<__hip_bfloat16><<<dim3(mtiles, 7), gemmBlk, 0, stream>>>(act, W2, hbuf, NN, 448, 448);
    gat_alpha_kernel<<<aggBlocks, 256, 0, stream>>>(hbuf, a2s, a2d, as8, ad8, 7, 64, 448);
    hipMemsetAsync(mbuf, 0, mbytes, stream);
    gat_emax_kernel<7><<<eblocks, 256, 0, stream>>>(colA, dstA, as8, ad8, mbuf);
    gat_expw_kernel<7><<<eblocks, 256, 0, stream>>>(colA, dstA, as8, ad8, mbuf, wbuf);
    gat_aggC7_kernel<<<aggBlocks, 256, 0, stream>>>(row_ptr, colA, wbuf, hbuf, b2, act);

    // --- layer 3 (1 head, 32 ch, log_softmax, fp32 out)
    gat_gemm_kernel<__hip_bfloat16><<<dim3(mtiles, 1), gemmBlk, 0, stream>>>(act, W3, hbuf, NN, 448, 32);
    gat_alpha_kernel<<<aggBlocks, 256, 0, stream>>>(hbuf, a3s, a3d, as8, ad8, 1, 32, 32);
    hipMemsetAsync(mbuf, 0, mbytes, stream);
    gat_emax_kernel<1><<<eblocks, 256, 0, stream>>>(colA, dstA, as8, ad8, mbuf);
    gat_expw_kernel<1><<<eblocks, 256, 0, stream>>>(colA, dstA, as8, ad8, mbuf, wbuf);
    int fBlocks = (NN + 7) / 8;  // 8 dsts per block (2 per wave)
    gat_aggCF_kernel<<<fBlocks, 256, 0, stream>>>(row_ptr, colA, wbuf, hbuf, b3, out);
}

// Round 5
// 775.749 us; speedup vs baseline: 1.3359x; 1.0088x over previous
//
#include <hip/hip_runtime.h>
#include <hip/hip_bf16.h>
#include <hip/hip_fp16.h>

#define NN 50000
#define EE 800000
#define ET (EE + NN)          // 850000 edges incl self-loops
#define NB_SCAN ((NN + 255) / 256)   // 196

typedef __attribute__((ext_vector_type(8))) short bf16x8;
typedef __attribute__((ext_vector_type(4))) float f32x4;

static __device__ __forceinline__ float bf2f(__hip_bfloat16 x) { return __bfloat162float(x); }
static __device__ __forceinline__ ushort f2bu(float f) {
    union { __hip_bfloat16 b; ushort u; } c;
    c.b = __float2bfloat16(f);
    return c.u;
}
static __device__ __forceinline__ float u2f(ushort u) {
    union { ushort u; __hip_bfloat16 b; } c;
    c.u = u;
    return __bfloat162float(c.b);
}
// order-preserving float<->uint for atomicMax
static __device__ __forceinline__ unsigned fenc(float f) {
    unsigned b = __float_as_uint(f);
    return (b & 0x80000000u) ? ~b : (b | 0x80000000u);
}
static __device__ __forceinline__ float fdec(unsigned u) {
    unsigned b = (u & 0x80000000u) ? (u & 0x7fffffffu) : ~u;
    return __uint_as_float(b);
}

// ---------------------------------------------------------------- CSR build
__global__ void gat_count_kernel(const int* __restrict__ ei, int* __restrict__ cnt) {
    int i = blockIdx.x * blockDim.x + threadIdx.x;
    if (i >= ET) return;
    int dst = (i < EE) ? ei[EE + i] : (i - EE);
    atomicAdd(&cnt[dst], 1);
}

__global__ void gat_scan1_kernel(const int* __restrict__ cnt, int* __restrict__ tmp,
                                 int* __restrict__ part) {
    __shared__ int sm[256];
    int tid = threadIdx.x;
    int i = blockIdx.x * 256 + tid;
    int v = (i < NN) ? cnt[i] : 0;
    sm[tid] = v;
    __syncthreads();
    for (int o = 1; o < 256; o <<= 1) {
        int t = (tid >= o) ? sm[tid - o] : 0;
        __syncthreads();
        sm[tid] += t;
        __syncthreads();
    }
    if (i < NN) tmp[i] = sm[tid];
    if (tid == 255) part[blockIdx.x] = sm[255];
}

__global__ void gat_scan2_kernel(int* __restrict__ part) {
    __shared__ int sm[256];
    int tid = threadIdx.x;
    int v = (tid < NB_SCAN) ? part[tid] : 0;
    sm[tid] = v;
    __syncthreads();
    for (int o = 1; o < 256; o <<= 1) {
        int t = (tid >= o) ? sm[tid - o] : 0;
        __syncthreads();
        sm[tid] += t;
        __syncthreads();
    }
    part[tid] = sm[tid];
}

__global__ void gat_scan3_kernel(const int* __restrict__ tmp, const int* __restrict__ part,
                                 int* __restrict__ row_ptr) {
    int i = blockIdx.x * 256 + threadIdx.x;
    int off = (blockIdx.x > 0) ? part[blockIdx.x - 1] : 0;
    if (i < NN) row_ptr[i + 1] = tmp[i] + off;
    if (i == 0) row_ptr[0] = 0;
}

__global__ void gat_fill_kernel(const int* __restrict__ ei, const int* __restrict__ row_ptr,
                                int* __restrict__ fillc, int* __restrict__ colA,
                                int* __restrict__ dstA) {
    int i = blockIdx.x * blockDim.x + threadIdx.x;
    if (i >= ET) return;
    int s, d;
    if (i < EE) { s = ei[i]; d = ei[EE + i]; }
    else        { s = d = i - EE; }
    int pos = row_ptr[d] + atomicAdd(&fillc[d], 1);
    colA[pos] = s;
    dstA[pos] = d;
}

// ---------------------------------------------------------------- GEMM core (templated on A dtype)
#define GBM 128
#define GBN 64
#define GBK 32
#define LDP 40

template <typename AT>
__global__ __launch_bounds__(256) void gat_gemm_kernel(
    const AT* __restrict__ A, const float* __restrict__ B,
    __hip_bfloat16* __restrict__ C, int M, int K, int N) {
    __shared__ __align__(16) ushort As[GBM * LDP];
    __shared__ __align__(16) ushort Bs[GBN * LDP];
    int tid = threadIdx.x;
    int wave = tid >> 6, lane = tid & 63;
    int lrow = lane & 15, lq = lane >> 4;
    int m0 = blockIdx.x * GBM, n0 = blockIdx.y * GBN;
    f32x4 acc[2][4] = {};

    for (int k0 = 0; k0 < K; k0 += GBK) {
        __syncthreads();
        {
            int row = tid >> 1, kc = (tid & 1) * 16;
            int gm = m0 + row;
            ushort u[16];
            if constexpr (sizeof(AT) == 4) {  // fp32 A
                float4 f0 = make_float4(0, 0, 0, 0), f1 = f0, f2 = f0, f3 = f0;
                if (gm < M) {
                    const float4* p = (const float4*)((const float*)A + (size_t)gm * K + k0 + kc);
                    f0 = p[0]; f1 = p[1]; f2 = p[2]; f3 = p[3];
                }
                u[0] = f2bu(f0.x); u[1] = f2bu(f0.y); u[2] = f2bu(f0.z); u[3] = f2bu(f0.w);
                u[4] = f2bu(f1.x); u[5] = f2bu(f1.y); u[6] = f2bu(f1.z); u[7] = f2bu(f1.w);
                u[8] = f2bu(f2.x); u[9] = f2bu(f2.y); u[10] = f2bu(f2.z); u[11] = f2bu(f2.w);
                u[12] = f2bu(f3.x); u[13] = f2bu(f3.y); u[14] = f2bu(f3.z); u[15] = f2bu(f3.w);
            } else {  // bf16 A
                uint4 z0 = make_uint4(0, 0, 0, 0), z1 = z0;
                if (gm < M) {
                    const uint4* p = (const uint4*)((const ushort*)A + (size_t)gm * K + k0 + kc);
                    z0 = p[0]; z1 = p[1];
                }
                *(uint4*)&u[0] = z0;
                *(uint4*)&u[8] = z1;
            }
            *(uint4*)&As[row * LDP + kc] = *(const uint4*)&u[0];
            *(uint4*)&As[row * LDP + kc + 8] = *(const uint4*)&u[8];
        }
        {
            int kk = tid >> 3, nc = (tid & 7) * 8;
            float4 g0 = make_float4(0, 0, 0, 0), g1 = g0;
            if (n0 + nc < N) {
                const float4* p = (const float4*)(B + (size_t)(k0 + kk) * N + n0 + nc);
                g0 = p[0]; g1 = p[1];
            }
            ushort t8[8];
            t8[0] = f2bu(g0.x); t8[1] = f2bu(g0.y); t8[2] = f2bu(g0.z); t8[3] = f2bu(g0.w);
            t8[4] = f2bu(g1.x); t8[5] = f2bu(g1.y); t8[6] = f2bu(g1.z); t8[7] = f2bu(g1.w);
#pragma unroll
            for (int j = 0; j < 8; j++) Bs[(nc + j) * LDP + kk] = t8[j];
        }
        __syncthreads();

        bf16x8 af0 = *(const bf16x8*)&As[(wave * 32 + lrow) * LDP + lq * 8];
        bf16x8 af1 = *(const bf16x8*)&As[(wave * 32 + 16 + lrow) * LDP + lq * 8];
#pragma unroll
        for (int ng = 0; ng < 4; ng++) {
            bf16x8 bf = *(const bf16x8*)&Bs[(ng * 16 + lrow) * LDP + lq * 8];
            acc[0][ng] = __builtin_amdgcn_mfma_f32_16x16x32_bf16(af0, bf, acc[0][ng], 0, 0, 0);
            acc[1][ng] = __builtin_amdgcn_mfma_f32_16x16x32_bf16(af1, bf, acc[1][ng], 0, 0, 0);
        }
    }
#pragma unroll
    for (int rs = 0; rs < 2; rs++)
#pragma unroll
        for (int ng = 0; ng < 4; ng++)
#pragma unroll
            for (int r = 0; r < 4; r++) {
                int row = m0 + wave * 32 + rs * 16 + lq * 4 + r;
                int colI = n0 + ng * 16 + lrow;
                if (row < M && colI < N)
                    C[(size_t)row * N + colI] = __float2bfloat16(acc[rs][ng][r]);
            }
}

// ---------------------------------------------------------------- alpha dots
__global__ void gat_alpha_kernel(const __hip_bfloat16* __restrict__ h,
                                 const float* __restrict__ a_src,
                                 const float* __restrict__ a_dst,
                                 float* __restrict__ as8, float* __restrict__ ad8,
                                 int heads, int C, int HW) {
    int node = blockIdx.x * 4 + (threadIdx.x >> 6);
    if (node >= NN) return;
    int lane = threadIdx.x & 63;
    for (int hh = 0; hh < heads; hh++) {
        float v = 0.f, cs = 0.f, cd = 0.f;
        if (lane < C) {
            v = bf2f(h[(size_t)node * HW + hh * C + lane]);
            cs = a_src[hh * C + lane];
            cd = a_dst[hh * C + lane];
        }
        float ps = v * cs, pd = v * cd;
#pragma unroll
        for (int o = 32; o > 0; o >>= 1) {
            ps += __shfl_xor(ps, o);
            pd += __shfl_xor(pd, o);
        }
        if (lane == 0) {
            as8[(size_t)node * 8 + hh] = ps;
            ad8[(size_t)node * 8 + hh] = pd;
        }
    }
}

// ---------------------------------------------------------------- Phase A: edge-parallel per-dst max
template <int H>
__global__ void gat_emax_kernel(const int* __restrict__ colA, const int* __restrict__ dstA,
                                const float* __restrict__ as8, const float* __restrict__ ad8,
                                unsigned int* __restrict__ mbuf) {
    int j = blockIdx.x * 256 + threadIdx.x;
    int lane = threadIdx.x & 63;
    bool valid = (j < ET);
    int jc = valid ? j : (ET - 1);
    int s = colA[jc];
    int d = valid ? dstA[jc] : -1;
    int dl = (d < 0) ? 0 : d;
    float e[H];
    if constexpr (H == 7) {
        const float4* pa = (const float4*)(as8 + (size_t)s * 8);
        const float4* pd = (const float4*)(ad8 + (size_t)dl * 8);
        float4 a0 = pa[0], a1 = pa[1], b0 = pd[0], b1 = pd[1];
        float av[7] = {a0.x, a0.y, a0.z, a0.w, a1.x, a1.y, a1.z};
        float dv[7] = {b0.x, b0.y, b0.z, b0.w, b1.x, b1.y, b1.z};
#pragma unroll
        for (int h = 0; h < 7; h++) {
            float v = av[h] + dv[h];
            e[h] = (v > 0.f) ? v : 0.2f * v;
        }
    } else {
        float v = as8[(size_t)s * 8] + ad8[(size_t)dl * 8];
        e[0] = (v > 0.f) ? v : 0.2f * v;
    }
    // segmented max over dst-sorted edges within the wave
    for (int off = 1; off < 64; off <<= 1) {
        int dd = __shfl_up(d, off);
#pragma unroll
        for (int h = 0; h < H; h++) {
            float ee = __shfl_up(e[h], off);
            if (lane >= off && dd == d) e[h] = fmaxf(e[h], ee);
        }
    }
    int dnext = __shfl_down(d, 1);
    bool leader = (lane == 63) || (dnext != d);
    if (leader && d >= 0) {
#pragma unroll
        for (int h = 0; h < H; h++)
            atomicMax(&mbuf[(size_t)d * 8 + h], fenc(e[h]));
    }
}

// ---------------------------------------------------------------- Phase B: edge-parallel exp weights (fp16)
template <int H>
__global__ void gat_expw_kernel(const int* __restrict__ colA, const int* __restrict__ dstA,
                                const float* __restrict__ as8, const float* __restrict__ ad8,
                                const unsigned int* __restrict__ mbuf,
                                ushort* __restrict__ wbuf) {
    int j = blockIdx.x * 256 + threadIdx.x;
    if (j >= ET) return;
    int s = colA[j], d = dstA[j];
    ushort w8[8] = {0, 0, 0, 0, 0, 0, 0, 0};
    if constexpr (H == 7) {
        const float4* pa = (const float4*)(as8 + (size_t)s * 8);
        const float4* pd = (const float4*)(ad8 + (size_t)d * 8);
        float4 a0 = pa[0], a1 = pa[1], b0 = pd[0], b1 = pd[1];
        float av[7] = {a0.x, a0.y, a0.z, a0.w, a1.x, a1.y, a1.z};
        float dv[7] = {b0.x, b0.y, b0.z, b0.w, b1.x, b1.y, b1.z};
#pragma unroll
        for (int h = 0; h < 7; h++) {
            float v = av[h] + dv[h];
            v = (v > 0.f) ? v : 0.2f * v;
            float m = fdec(mbuf[(size_t)d * 8 + h]);
            float w = __expf(v - m);
            w8[h] = __half_as_ushort(__float2half(w));
        }
    } else {
        float v = as8[(size_t)s * 8] + ad8[(size_t)d * 8];
        v = (v > 0.f) ? v : 0.2f * v;
        float m = fdec(mbuf[(size_t)d * 8]);
        float w = __expf(v - m);
        w8[0] = __half_as_ushort(__float2half(w));
    }
    *(uint4*)&wbuf[(size_t)j * 8] = *(const uint4*)&w8[0];
}

// ---------------------------------------------------------------- Phase C: wave-per-dst accumulate
// lane l<56 owns head l>>3, channels 8l..8l+7 (16B/lane gather+store)
// unroll-4 with batched index/weight loads for MLP (latency-bound fix, R4)
__global__ void gat_aggC7_kernel(const int* __restrict__ rp, const int* __restrict__ colA,
                                 const ushort* __restrict__ wbuf,
                                 const __hip_bfloat16* __restrict__ h,
                                 const float* __restrict__ bias,
                                 __hip_bfloat16* __restrict__ outp) {
    int d = blockIdx.x * 4 + (threadIdx.x >> 6);
    if (d >= NN) return;
    int lane = threadIdx.x & 63;
    if (lane >= 56) return;
    int hh = lane >> 3;
    const ushort* hu = (const ushort*)h;
    int s0 = rp[d], s1 = rp[d + 1];
    float acc[8] = {0.f, 0.f, 0.f, 0.f, 0.f, 0.f, 0.f, 0.f};
    float den = 0.f;
    int j = s0;
    for (; j + 4 <= s1; j += 4) {
        // all 8 loads independent -> issue together, 4 big gathers in flight
        int sA = colA[j], sB = colA[j + 1], sC = colA[j + 2], sD = colA[j + 3];
        float wA = __half2float(__ushort_as_half(wbuf[(size_t)j * 8 + hh]));
        float wB = __half2float(__ushort_as_half(wbuf[(size_t)(j + 1) * 8 + hh]));
        float wC = __half2float(__ushort_as_half(wbuf[(size_t)(j + 2) * 8 + hh]));
        float wD = __half2float(__ushort_as_half(wbuf[(size_t)(j + 3) * 8 + hh]));
        uint4 hA = *(const uint4*)(hu + (size_t)sA * 448 + lane * 8);
        uint4 hB = *(const uint4*)(hu + (size_t)sB * 448 + lane * 8);
        uint4 hC = *(const uint4*)(hu + (size_t)sC * 448 + lane * 8);
        uint4 hD = *(const uint4*)(hu + (size_t)sD * 448 + lane * 8);
        den += (wA + wB) + (wC + wD);
        const ushort* pA = (const ushort*)&hA;
        const ushort* pB = (const ushort*)&hB;
        const ushort* pC = (const ushort*)&hC;
        const ushort* pD = (const ushort*)&hD;
#pragma unroll
        for (int k = 0; k < 8; k++) {
            acc[k] += wA * u2f(pA[k]) + wB * u2f(pB[k]);
            acc[k] += wC * u2f(pC[k]) + wD * u2f(pD[k]);
        }
    }
    for (; j < s1; j++) {
        int s = colA[j];
        float w = __half2float(__ushort_as_half(wbuf[(size_t)j * 8 + hh]));
        uint4 hv = *(const uint4*)(hu + (size_t)s * 448 + lane * 8);
        const ushort* hp = (const ushort*)&hv;
        den += w;
#pragma unroll
        for (int k = 0; k < 8; k++) acc[k] += w * u2f(hp[k]);
    }
    float inv = 1.f / (den + 1e-16f);
    const float4* bp = (const float4*)(bias + lane * 8);
    float4 bb0 = bp[0], bb1 = bp[1];
    float bv[8] = {bb0.x, bb0.y, bb0.z, bb0.w, bb1.x, bb1.y, bb1.z, bb1.w};
    ushort o8[8];
#pragma unroll
    for (int k = 0; k < 8; k++) {
        float o = acc[k] * inv + bv[k];
        o = fmaxf(o, 0.f);
        o8[k] = f2bu(o);
    }
    *(uint4*)((ushort*)outp + (size_t)d * 448 + lane * 8) = *(const uint4*)o8;
}

// ---------------------------------------------------------------- Phase C final: 2 dsts/wave, 32 ch, log_softmax
__global__ void gat_aggCF_kernel(const int* __restrict__ rp, const int* __restrict__ colA,
                                 const ushort* __restrict__ wbuf,
                                 const __hip_bfloat16* __restrict__ h,
                                 const float* __restrict__ bias,
                                 float* __restrict__ outp) {
    int wid = blockIdx.x * 4 + (threadIdx.x >> 6);
    int lane = threadIdx.x & 63;
    int half = lane >> 5, c = lane & 31;
    int dreal = wid * 2 + half;
    bool valid = dreal < NN;
    int d = valid ? dreal : (NN - 1);
    int s0 = rp[d], s1 = rp[d + 1];
    float acc = 0.f, den = 0.f;
    int j = s0;
    for (; j + 2 <= s1; j += 2) {
        int sA = colA[j], sB = colA[j + 1];
        float wA = __half2float(__ushort_as_half(wbuf[(size_t)j * 8]));
        float wB = __half2float(__ushort_as_half(wbuf[(size_t)(j + 1) * 8]));
        float vA = bf2f(h[(size_t)sA * 32 + c]);
        float vB = bf2f(h[(size_t)sB * 32 + c]);
        den += wA + wB;
        acc += wA * vA + wB * vB;
    }
    for (; j < s1; j++) {
        int s = colA[j];
        float w = __half2float(__ushort_as_half(wbuf[(size_t)j * 8]));
        den += w;
        acc += w * bf2f(h[(size_t)s * 32 + c]);
    }
    float o = acc / (den + 1e-16f) + bias[c];
    float t = o;
#pragma unroll
    for (int off = 16; off > 0; off >>= 1) t = fmaxf(t, __shfl_xor(t, off));
    float ex = __expf(o - t);
#pragma unroll
    for (int off = 16; off > 0; off >>= 1) ex += __shfl_xor(ex, off);
    float res = o - t - __logf(ex);
    if (valid) outp[(size_t)d * 32 + c] = res;
}

// ---------------------------------------------------------------- launch
extern "C" void kernel_launch(void* const* d_in, const int* in_sizes, int n_in,
                              void* d_out, int out_size, void* d_ws, size_t ws_size,
                              hipStream_t stream) {
    const float* x   = (const float*)d_in[0];
    const int*   ei  = (const int*)d_in[1];
    const float* W1  = (const float*)d_in[2];
    const float* a1s = (const float*)d_in[3];
    const float* a1d = (const float*)d_in[4];
    const float* b1  = (const float*)d_in[5];
    const float* W2  = (const float*)d_in[6];
    const float* a2s = (const float*)d_in[7];
    const float* a2d = (const float*)d_in[8];
    const float* b2  = (const float*)d_in[9];
    const float* W3  = (const float*)d_in[10];
    const float* a3s = (const float*)d_in[11];
    const float* a3d = (const float*)d_in[12];
    const float* b3  = (const float*)d_in[13];
    float* out = (float*)d_out;

    // workspace layout (~116 MB)
    char* w = (char*)d_ws;
    __hip_bfloat16* hbuf = (__hip_bfloat16*)w;                 // N*448 bf16
    __hip_bfloat16* act  = hbuf + (size_t)NN * 448;            // N*448 bf16
    float* as8 = (float*)(act + (size_t)NN * 448);             // N*8 f32
    float* ad8 = as8 + (size_t)NN * 8;                         // N*8 f32
    unsigned int* mbuf = (unsigned int*)(ad8 + (size_t)NN * 8);// N*8 u32
    int* cnt     = (int*)(mbuf + (size_t)NN * 8);              // N
    int* fillc   = cnt + NN;                                   // N
    int* row_ptr = fillc + NN;                                 // N+4 (padded)
    int* tmp     = row_ptr + (NN + 4);                         // N
    int* part    = tmp + NN;                                   // 256
    int* colA    = part + 256;                                 // ET
    int* dstA    = colA + ET;                                  // ET
    ushort* wbuf = (ushort*)(dstA + ET);                       // ET*8 fp16

    hipMemsetAsync(cnt, 0, 2 * (size_t)NN * sizeof(int), stream);  // cnt + fillc
    int eblocks = (ET + 255) / 256;
    gat_count_kernel<<<eblocks, 256, 0, stream>>>(ei, cnt);
    gat_scan1_kernel<<<NB_SCAN, 256, 0, stream>>>(cnt, tmp, part);
    gat_scan2_kernel<<<1, 256, 0, stream>>>(part);
    gat_scan3_kernel<<<NB_SCAN, 256, 0, stream>>>(tmp, part, row_ptr);
    gat_fill_kernel<<<eblocks, 256, 0, stream>>>(ei, row_ptr, fillc, colA, dstA);

    dim3 gemmBlk(256);
    int mtiles = (NN + GBM - 1) / GBM;  // 391
    int aggBlocks = (NN + 3) / 4;       // 12500
    size_t mbytes = (size_t)NN * 8 * sizeof(unsigned int);

    // --- layer 1
    gat_gemm_kernel<float><<<dim3(mtiles, 7), gemmBlk, 0, stream>>>(x, W1, hbuf, NN, 256, 448);
    gat_alpha_kernel<<<aggBlocks, 256, 0, stream>>>(hbuf, a1s, a1d, as8, ad8, 7, 64, 448);
    hipMemsetAsync(mbuf, 0, mbytes, stream);
    gat_emax_kernel<7><<<eblocks, 256, 0, stream>>>(colA, dstA, as8, ad8, mbuf);
    gat_expw_kernel<7><<<eblocks, 256, 0, stream>>>(colA, dstA, as8, ad8, mbuf, wbuf);
    gat_aggC7_kernel<<<aggBlocks, 256, 0, stream>>>(row_ptr, colA, wbuf, hbuf, b1, act);

    // --- layer 2
    gat_gemm_kernel<__hip_bfloat16><<<dim3(mtiles, 7), gemmBlk, 0, stream>>>(act, W2, hbuf, NN, 448, 448);
    gat_alpha_kernel<<<aggBlocks, 256, 0, stream>>>(hbuf, a2s, a2d, as8, ad8, 7, 64, 448);
    hipMemsetAsync(mbuf, 0, mbytes, stream);
    gat_emax_kernel<7><<<eblocks, 256, 0, stream>>>(colA, dstA, as8, ad8, mbuf);
    gat_expw_kernel<7><<<eblocks, 256, 0, stream>>>(colA, dstA, as8, ad8, mbuf, wbuf);
    gat_aggC7_kernel<<<aggBlocks, 256, 0, stream>>>(row_ptr, colA, wbuf, hbuf, b2, act);

    // --- layer 3 (1 head, 32 ch, log_softmax, fp32 out)
    gat_gemm_kernel<__hip_bfloat16><<<dim3(mtiles, 1), gemmBlk, 0, stream>>>(act, W3, hbuf, NN, 448, 32);
    gat_alpha_kernel<<<aggBlocks, 256, 0, stream>>>(hbuf, a3s, a3d, as8, ad8, 1, 32, 32);
    hipMemsetAsync(mbuf, 0, mbytes, stream);
    gat_emax_kernel<1><<<eblocks, 256, 0, stream>>>(colA, dstA, as8, ad8, mbuf);
    gat_expw_kernel<1><<<eblocks, 256, 0, stream>>>(colA, dstA, as8, ad8, mbuf, wbuf);
    int fBlocks = (NN + 7) / 8;  // 8 dsts per block (2 per wave)
    gat_aggCF_kernel<<<fBlocks, 256, 0, stream>>>(row_ptr, colA, wbuf, hbuf, b3, out);
}

// Round 6
// 676.368 us; speedup vs baseline: 1.5321x; 1.1469x over previous
//
#include <hip/hip_runtime.h>
#include <hip/hip_bf16.h>
#include <hip/hip_fp16.h>

#define NN 50000
#define EE 800000
#define ET (EE + NN)          // 850000 edges incl self-loops
#define NB_SCAN ((NN + 255) / 256)   // 196

typedef __attribute__((ext_vector_type(8))) short bf16x8;
typedef __attribute__((ext_vector_type(4))) float f32x4;

static __device__ __forceinline__ float bf2f(__hip_bfloat16 x) { return __bfloat162float(x); }
static __device__ __forceinline__ ushort f2bu(float f) {
    union { __hip_bfloat16 b; ushort u; } c;
    c.b = __float2bfloat16(f);
    return c.u;
}
static __device__ __forceinline__ float u2f(ushort u) {
    union { ushort u; __hip_bfloat16 b; } c;
    c.u = u;
    return __bfloat162float(c.b);
}
// order-preserving float<->uint for atomicMax
static __device__ __forceinline__ unsigned fenc(float f) {
    unsigned b = __float_as_uint(f);
    return (b & 0x80000000u) ? ~b : (b | 0x80000000u);
}
static __device__ __forceinline__ float fdec(unsigned u) {
    unsigned b = (u & 0x80000000u) ? (u & 0x7fffffffu) : ~u;
    return __uint_as_float(b);
}

// ---------------------------------------------------------------- CSR build
__global__ void gat_count_kernel(const int* __restrict__ ei, int* __restrict__ cnt) {
    int i = blockIdx.x * blockDim.x + threadIdx.x;
    if (i >= ET) return;
    int dst = (i < EE) ? ei[EE + i] : (i - EE);
    atomicAdd(&cnt[dst], 1);
}

__global__ void gat_scan1_kernel(const int* __restrict__ cnt, int* __restrict__ tmp,
                                 int* __restrict__ part) {
    __shared__ int sm[256];
    int tid = threadIdx.x;
    int i = blockIdx.x * 256 + tid;
    int v = (i < NN) ? cnt[i] : 0;
    sm[tid] = v;
    __syncthreads();
    for (int o = 1; o < 256; o <<= 1) {
        int t = (tid >= o) ? sm[tid - o] : 0;
        __syncthreads();
        sm[tid] += t;
        __syncthreads();
    }
    if (i < NN) tmp[i] = sm[tid];
    if (tid == 255) part[blockIdx.x] = sm[255];
}

__global__ void gat_scan2_kernel(int* __restrict__ part) {
    __shared__ int sm[256];
    int tid = threadIdx.x;
    int v = (tid < NB_SCAN) ? part[tid] : 0;
    sm[tid] = v;
    __syncthreads();
    for (int o = 1; o < 256; o <<= 1) {
        int t = (tid >= o) ? sm[tid - o] : 0;
        __syncthreads();
        sm[tid] += t;
        __syncthreads();
    }
    part[tid] = sm[tid];
}

__global__ void gat_scan3_kernel(const int* __restrict__ tmp, const int* __restrict__ part,
                                 int* __restrict__ row_ptr) {
    int i = blockIdx.x * 256 + threadIdx.x;
    int off = (blockIdx.x > 0) ? part[blockIdx.x - 1] : 0;
    if (i < NN) row_ptr[i + 1] = tmp[i] + off;
    if (i == 0) row_ptr[0] = 0;
}

__global__ void gat_fill_kernel(const int* __restrict__ ei, const int* __restrict__ row_ptr,
                                int* __restrict__ fillc, int* __restrict__ colA,
                                int* __restrict__ dstA) {
    int i = blockIdx.x * blockDim.x + threadIdx.x;
    if (i >= ET) return;
    int s, d;
    if (i < EE) { s = ei[i]; d = ei[EE + i]; }
    else        { s = d = i - EE; }
    int pos = row_ptr[d] + atomicAdd(&fillc[d], 1);
    colA[pos] = s;
    dstA[pos] = d;
}

// ---------------------------------------------------------------- weight transpose: Wt[n][k] = bf16(W[k][n])
__global__ void gat_wt_kernel(const float* __restrict__ W, ushort* __restrict__ Wt,
                              int K, int N) {
    int i = blockIdx.x * 256 + threadIdx.x;   // i = k*N + n
    if (i >= K * N) return;
    int k = i / N, n = i - k * N;
    Wt[(size_t)n * K + k] = f2bu(W[i]);
}

// ---------------------------------------------------------------- GEMM core
// C[M,N] = A[M,K] * W[K,N]; W given pre-transposed bf16 Wt[N][K].
// DOA: fuse alpha dots (head = blockIdx.y, 64 ch) into epilogue.
#define GBM 128
#define GBN 64
#define GBK 32
#define LDP 40

template <typename AT, bool DOA>
__global__ __launch_bounds__(256) void gat_gemm_kernel(
    const AT* __restrict__ A, const ushort* __restrict__ Wt,
    __hip_bfloat16* __restrict__ C,
    const float* __restrict__ Asrc, const float* __restrict__ Adst,
    float* __restrict__ as8, float* __restrict__ ad8,
    int M, int K, int N) {
    __shared__ __align__(16) ushort As[GBM * LDP];
    __shared__ __align__(16) ushort Bs[GBN * LDP];
    int tid = threadIdx.x;
    int wave = tid >> 6, lane = tid & 63;
    int lrow = lane & 15, lq = lane >> 4;
    int m0 = blockIdx.x * GBM, n0 = blockIdx.y * GBN;
    f32x4 acc[2][4] = {};

    for (int k0 = 0; k0 < K; k0 += GBK) {
        __syncthreads();
        // stage A: thread t -> row=t>>1, kc=(t&1)*16 (16 elements)
        {
            int row = tid >> 1, kc = (tid & 1) * 16;
            int gm = m0 + row;
            ushort u[16];
            if constexpr (sizeof(AT) == 4) {  // fp32 A
                float4 f0 = make_float4(0, 0, 0, 0), f1 = f0, f2 = f0, f3 = f0;
                if (gm < M) {
                    const float4* p = (const float4*)((const float*)A + (size_t)gm * K + k0 + kc);
                    f0 = p[0]; f1 = p[1]; f2 = p[2]; f3 = p[3];
                }
                u[0] = f2bu(f0.x); u[1] = f2bu(f0.y); u[2] = f2bu(f0.z); u[3] = f2bu(f0.w);
                u[4] = f2bu(f1.x); u[5] = f2bu(f1.y); u[6] = f2bu(f1.z); u[7] = f2bu(f1.w);
                u[8] = f2bu(f2.x); u[9] = f2bu(f2.y); u[10] = f2bu(f2.z); u[11] = f2bu(f2.w);
                u[12] = f2bu(f3.x); u[13] = f2bu(f3.y); u[14] = f2bu(f3.z); u[15] = f2bu(f3.w);
            } else {  // bf16 A
                uint4 z0 = make_uint4(0, 0, 0, 0), z1 = z0;
                if (gm < M) {
                    const uint4* p = (const uint4*)((const ushort*)A + (size_t)gm * K + k0 + kc);
                    z0 = p[0]; z1 = p[1];
                }
                *(uint4*)&u[0] = z0;
                *(uint4*)&u[8] = z1;
            }
            *(uint4*)&As[row * LDP + kc] = *(const uint4*)&u[0];
            *(uint4*)&As[row * LDP + kc + 8] = *(const uint4*)&u[8];
        }
        // stage B from Wt[n][k]: thread t -> n=t>>2, q=t&3 (one uint4 = 8 bf16)
        {
            int n = tid >> 2, q = tid & 3;
            uint4 v = make_uint4(0, 0, 0, 0);
            if (n0 + n < N)
                v = *(const uint4*)(Wt + (size_t)(n0 + n) * K + k0 + q * 8);
            *(uint4*)&Bs[n * LDP + q * 8] = v;
        }
        __syncthreads();

        bf16x8 af0 = *(const bf16x8*)&As[(wave * 32 + lrow) * LDP + lq * 8];
        bf16x8 af1 = *(const bf16x8*)&As[(wave * 32 + 16 + lrow) * LDP + lq * 8];
#pragma unroll
        for (int ng = 0; ng < 4; ng++) {
            bf16x8 bf = *(const bf16x8*)&Bs[(ng * 16 + lrow) * LDP + lq * 8];
            acc[0][ng] = __builtin_amdgcn_mfma_f32_16x16x32_bf16(af0, bf, acc[0][ng], 0, 0, 0);
            acc[1][ng] = __builtin_amdgcn_mfma_f32_16x16x32_bf16(af1, bf, acc[1][ng], 0, 0, 0);
        }
    }
    // epilogue: C/D layout col=lane&15 within ng group, row=lq*4+r
#pragma unroll
    for (int rs = 0; rs < 2; rs++)
#pragma unroll
        for (int ng = 0; ng < 4; ng++)
#pragma unroll
            for (int r = 0; r < 4; r++) {
                int row = m0 + wave * 32 + rs * 16 + lq * 4 + r;
                int colI = n0 + ng * 16 + lrow;
                if (row < M && colI < N)
                    C[(size_t)row * N + colI] = __float2bfloat16(acc[rs][ng][r]);
            }
    if constexpr (DOA) {
        // fused alpha dots for head = blockIdx.y (64 channels)
        int head = blockIdx.y;
        float as_l[4], ad_l[4];
#pragma unroll
        for (int ng = 0; ng < 4; ng++) {
            as_l[ng] = Asrc[head * 64 + ng * 16 + lrow];
            ad_l[ng] = Adst[head * 64 + ng * 16 + lrow];
        }
#pragma unroll
        for (int rs = 0; rs < 2; rs++)
#pragma unroll
            for (int r = 0; r < 4; r++) {
                float ps = 0.f, pd = 0.f;
#pragma unroll
                for (int ng = 0; ng < 4; ng++) {
                    ps += acc[rs][ng][r] * as_l[ng];
                    pd += acc[rs][ng][r] * ad_l[ng];
                }
#pragma unroll
                for (int o = 1; o < 16; o <<= 1) {
                    ps += __shfl_xor(ps, o);
                    pd += __shfl_xor(pd, o);
                }
                int row = m0 + wave * 32 + rs * 16 + lq * 4 + r;
                if (lrow == 0 && row < M) {
                    as8[(size_t)row * 8 + head] = ps;
                    ad8[(size_t)row * 8 + head] = pd;
                }
            }
    }
}

// ---------------------------------------------------------------- alpha dots (layer 3 only)
__global__ void gat_alpha_kernel(const __hip_bfloat16* __restrict__ h,
                                 const float* __restrict__ a_src,
                                 const float* __restrict__ a_dst,
                                 float* __restrict__ as8, float* __restrict__ ad8,
                                 int heads, int C, int HW) {
    int node = blockIdx.x * 4 + (threadIdx.x >> 6);
    if (node >= NN) return;
    int lane = threadIdx.x & 63;
    for (int hh = 0; hh < heads; hh++) {
        float v = 0.f, cs = 0.f, cd = 0.f;
        if (lane < C) {
            v = bf2f(h[(size_t)node * HW + hh * C + lane]);
            cs = a_src[hh * C + lane];
            cd = a_dst[hh * C + lane];
        }
        float ps = v * cs, pd = v * cd;
#pragma unroll
        for (int o = 32; o > 0; o >>= 1) {
            ps += __shfl_xor(ps, o);
            pd += __shfl_xor(pd, o);
        }
        if (lane == 0) {
            as8[(size_t)node * 8 + hh] = ps;
            ad8[(size_t)node * 8 + hh] = pd;
        }
    }
}

// ---------------------------------------------------------------- Phase A: edge-parallel per-dst max
template <int H>
__global__ void gat_emax_kernel(const int* __restrict__ colA, const int* __restrict__ dstA,
                                const float* __restrict__ as8, const float* __restrict__ ad8,
                                unsigned int* __restrict__ mbuf) {
    int j = blockIdx.x * 256 + threadIdx.x;
    int lane = threadIdx.x & 63;
    bool valid = (j < ET);
    int jc = valid ? j : (ET - 1);
    int s = colA[jc];
    int d = valid ? dstA[jc] : -1;
    int dl = (d < 0) ? 0 : d;
    float e[H];
    if constexpr (H == 7) {
        const float4* pa = (const float4*)(as8 + (size_t)s * 8);
        const float4* pd = (const float4*)(ad8 + (size_t)dl * 8);
        float4 a0 = pa[0], a1 = pa[1], b0 = pd[0], b1 = pd[1];
        float av[7] = {a0.x, a0.y, a0.z, a0.w, a1.x, a1.y, a1.z};
        float dv[7] = {b0.x, b0.y, b0.z, b0.w, b1.x, b1.y, b1.z};
#pragma unroll
        for (int h = 0; h < 7; h++) {
            float v = av[h] + dv[h];
            e[h] = (v > 0.f) ? v : 0.2f * v;
        }
    } else {
        float v = as8[(size_t)s * 8] + ad8[(size_t)dl * 8];
        e[0] = (v > 0.f) ? v : 0.2f * v;
    }
    // segmented max over dst-sorted edges within the wave
    for (int off = 1; off < 64; off <<= 1) {
        int dd = __shfl_up(d, off);
#pragma unroll
        for (int h = 0; h < H; h++) {
            float ee = __shfl_up(e[h], off);
            if (lane >= off && dd == d) e[h] = fmaxf(e[h], ee);
        }
    }
    int dnext = __shfl_down(d, 1);
    bool leader = (lane == 63) || (dnext != d);
    if (leader && d >= 0) {
#pragma unroll
        for (int h = 0; h < H; h++)
            atomicMax(&mbuf[(size_t)d * 8 + h], fenc(e[h]));
    }
}

// ---------------------------------------------------------------- Phase C: wave-per-dst accumulate, inline softmax-w
// lane l<56 owns head l>>3, channels 8l..8l+7 (16B/lane gather+store)
__global__ void gat_aggC7_kernel(const int* __restrict__ rp, const int* __restrict__ colA,
                                 const float* __restrict__ as8, const float* __restrict__ ad8,
                                 const unsigned int* __restrict__ mbuf,
                                 const __hip_bfloat16* __restrict__ h,
                                 const float* __restrict__ bias,
                                 __hip_bfloat16* __restrict__ outp) {
    int d = blockIdx.x * 4 + (threadIdx.x >> 6);
    if (d >= NN) return;
    int lane = threadIdx.x & 63;
    if (lane >= 56) return;
    int hh = lane >> 3;
    const ushort* hu = (const ushort*)h;
    float adh = ad8[(size_t)d * 8 + hh];
    float mh = fdec(mbuf[(size_t)d * 8 + hh]);
    int s0 = rp[d], s1 = rp[d + 1];
    float acc[8] = {0.f, 0.f, 0.f, 0.f, 0.f, 0.f, 0.f, 0.f};
    float den = 0.f;
    int j = s0;
    for (; j + 4 <= s1; j += 4) {
        int sA = colA[j], sB = colA[j + 1], sC = colA[j + 2], sD = colA[j + 3];
        float eA = as8[(size_t)sA * 8 + hh] + adh;
        float eB = as8[(size_t)sB * 8 + hh] + adh;
        float eC = as8[(size_t)sC * 8 + hh] + adh;
        float eD = as8[(size_t)sD * 8 + hh] + adh;
        uint4 hA = *(const uint4*)(hu + (size_t)sA * 448 + lane * 8);
        uint4 hB = *(const uint4*)(hu + (size_t)sB * 448 + lane * 8);
        uint4 hC = *(const uint4*)(hu + (size_t)sC * 448 + lane * 8);
        uint4 hD = *(const uint4*)(hu + (size_t)sD * 448 + lane * 8);
        eA = (eA > 0.f) ? eA : 0.2f * eA;
        eB = (eB > 0.f) ? eB : 0.2f * eB;
        eC = (eC > 0.f) ? eC : 0.2f * eC;
        eD = (eD > 0.f) ? eD : 0.2f * eD;
        float wA = __expf(eA - mh), wB = __expf(eB - mh);
        float wC = __expf(eC - mh), wD = __expf(eD - mh);
        den += (wA + wB) + (wC + wD);
        const ushort* pA = (const ushort*)&hA;
        const ushort* pB = (const ushort*)&hB;
        const ushort* pC = (const ushort*)&hC;
        const ushort* pD = (const ushort*)&hD;
#pragma unroll
        for (int k = 0; k < 8; k++) {
            acc[k] += wA * u2f(pA[k]) + wB * u2f(pB[k]);
            acc[k] += wC * u2f(pC[k]) + wD * u2f(pD[k]);
        }
    }
    for (; j < s1; j++) {
        int s = colA[j];
        float e = as8[(size_t)s * 8 + hh] + adh;
        e = (e > 0.f) ? e : 0.2f * e;
        float w = __expf(e - mh);
        uint4 hv = *(const uint4*)(hu + (size_t)s * 448 + lane * 8);
        const ushort* hp = (const ushort*)&hv;
        den += w;
#pragma unroll
        for (int k = 0; k < 8; k++) acc[k] += w * u2f(hp[k]);
    }
    float inv = 1.f / (den + 1e-16f);
    const float4* bp = (const float4*)(bias + lane * 8);
    float4 bb0 = bp[0], bb1 = bp[1];
    float bv[8] = {bb0.x, bb0.y, bb0.z, bb0.w, bb1.x, bb1.y, bb1.z, bb1.w};
    ushort o8[8];
#pragma unroll
    for (int k = 0; k < 8; k++) {
        float o = acc[k] * inv + bv[k];
        o = fmaxf(o, 0.f);
        o8[k] = f2bu(o);
    }
    *(uint4*)((ushort*)outp + (size_t)d * 448 + lane * 8) = *(const uint4*)o8;
}

// ---------------------------------------------------------------- Phase C final: 2 dsts/wave, 32 ch, inline w, log_softmax
__global__ void gat_aggCF_kernel(const int* __restrict__ rp, const int* __restrict__ colA,
                                 const float* __restrict__ as8, const float* __restrict__ ad8,
                                 const unsigned int* __restrict__ mbuf,
                                 const __hip_bfloat16* __restrict__ h,
                                 const float* __restrict__ bias,
                                 float* __restrict__ outp) {
    int wid = blockIdx.x * 4 + (threadIdx.x >> 6);
    int lane = threadIdx.x & 63;
    int half = lane >> 5, c = lane & 31;
    int dreal = wid * 2 + half;
    bool valid = dreal < NN;
    int d = valid ? dreal : (NN - 1);
    float adh = ad8[(size_t)d * 8];
    float mh = fdec(mbuf[(size_t)d * 8]);
    int s0 = rp[d], s1 = rp[d + 1];
    float acc = 0.f, den = 0.f;
    int j = s0;
    for (; j + 2 <= s1; j += 2) {
        int sA = colA[j], sB = colA[j + 1];
        float eA = as8[(size_t)sA * 8] + adh;
        float eB = as8[(size_t)sB * 8] + adh;
        float vA = bf2f(h[(size_t)sA * 32 + c]);
        float vB = bf2f(h[(size_t)sB * 32 + c]);
        eA = (eA > 0.f) ? eA : 0.2f * eA;
        eB = (eB > 0.f) ? eB : 0.2f * eB;
        float wA = __expf(eA - mh), wB = __expf(eB - mh);
        den += wA + wB;
        acc += wA * vA + wB * vB;
    }
    for (; j < s1; j++) {
        int s = colA[j];
        float e = as8[(size_t)s * 8] + adh;
        e = (e > 0.f) ? e : 0.2f * e;
        float w = __expf(e - mh);
        den += w;
        acc += w * bf2f(h[(size_t)s * 32 + c]);
    }
    float o = acc / (den + 1e-16f) + bias[c];
    float t = o;
#pragma unroll
    for (int off = 16; off > 0; off >>= 1) t = fmaxf(t, __shfl_xor(t, off));
    float ex = __expf(o - t);
#pragma unroll
    for (int off = 16; off > 0; off >>= 1) ex += __shfl_xor(ex, off);
    float res = o - t - __logf(ex);
    if (valid) outp[(size_t)d * 32 + c] = res;
}

// ---------------------------------------------------------------- launch
extern "C" void kernel_launch(void* const* d_in, const int* in_sizes, int n_in,
                              void* d_out, int out_size, void* d_ws, size_t ws_size,
                              hipStream_t stream) {
    const float* x   = (const float*)d_in[0];
    const int*   ei  = (const int*)d_in[1];
    const float* W1  = (const float*)d_in[2];
    const float* a1s = (const float*)d_in[3];
    const float* a1d = (const float*)d_in[4];
    const float* b1  = (const float*)d_in[5];
    const float* W2  = (const float*)d_in[6];
    const float* a2s = (const float*)d_in[7];
    const float* a2d = (const float*)d_in[8];
    const float* b2  = (const float*)d_in[9];
    const float* W3  = (const float*)d_in[10];
    const float* a3s = (const float*)d_in[11];
    const float* a3d = (const float*)d_in[12];
    const float* b3  = (const float*)d_in[13];
    float* out = (float*)d_out;

    // workspace layout (~103 MB)
    char* w = (char*)d_ws;
    __hip_bfloat16* hbuf = (__hip_bfloat16*)w;                 // N*448 bf16
    __hip_bfloat16* act  = hbuf + (size_t)NN * 448;            // N*448 bf16
    float* as8 = (float*)(act + (size_t)NN * 448);             // N*8 f32
    float* ad8 = as8 + (size_t)NN * 8;                         // N*8 f32
    unsigned int* mbuf = (unsigned int*)(ad8 + (size_t)NN * 8);// N*8 u32
    int* cnt     = (int*)(mbuf + (size_t)NN * 8);              // N
    int* fillc   = cnt + NN;                                   // N
    int* row_ptr = fillc + NN;                                 // N+4 (padded)
    int* tmp     = row_ptr + (NN + 4);                         // N
    int* part    = tmp + NN;                                   // 256
    int* colA    = part + 256;                                 // ET
    int* dstA    = colA + ET;                                  // ET
    char* pw = (char*)(dstA + ET);
    pw = (char*)(((uintptr_t)pw + 15) & ~(uintptr_t)15);
    ushort* Wt1 = (ushort*)pw;                                 // 448*256
    ushort* Wt2 = Wt1 + 448 * 256;                             // 448*448
    ushort* Wt3 = Wt2 + 448 * 448;                             // 32*448

    hipMemsetAsync(cnt, 0, 2 * (size_t)NN * sizeof(int), stream);  // cnt + fillc
    int eblocks = (ET + 255) / 256;
    gat_count_kernel<<<eblocks, 256, 0, stream>>>(ei, cnt);
    gat_scan1_kernel<<<NB_SCAN, 256, 0, stream>>>(cnt, tmp, part);
    gat_scan2_kernel<<<1, 256, 0, stream>>>(part);
    gat_scan3_kernel<<<NB_SCAN, 256, 0, stream>>>(tmp, part, row_ptr);
    gat_fill_kernel<<<eblocks, 256, 0, stream>>>(ei, row_ptr, fillc, colA, dstA);

    // weight transposes (bf16, [N][K])
    gat_wt_kernel<<<(256 * 448 + 255) / 256, 256, 0, stream>>>(W1, Wt1, 256, 448);
    gat_wt_kernel<<<(448 * 448 + 255) / 256, 256, 0, stream>>>(W2, Wt2, 448, 448);
    gat_wt_kernel<<<(448 * 32 + 255) / 256, 256, 0, stream>>>(W3, Wt3, 448, 32);

    dim3 gemmBlk(256);
    int mtiles = (NN + GBM - 1) / GBM;  // 391
    int aggBlocks = (NN + 3) / 4;       // 12500
    size_t mbytes = (size_t)NN * 8 * sizeof(unsigned int);

    // --- layer 1 (alpha fused into GEMM epilogue)
    gat_gemm_kernel<float, true><<<dim3(mtiles, 7), gemmBlk, 0, stream>>>(
        x, Wt1, hbuf, a1s, a1d, as8, ad8, NN, 256, 448);
    hipMemsetAsync(mbuf, 0, mbytes, stream);
    gat_emax_kernel<7><<<eblocks, 256, 0, stream>>>(colA, dstA, as8, ad8, mbuf);
    gat_aggC7_kernel<<<aggBlocks, 256, 0, stream>>>(row_ptr, colA, as8, ad8, mbuf, hbuf, b1, act);

    // --- layer 2
    gat_gemm_kernel<__hip_bfloat16, true><<<dim3(mtiles, 7), gemmBlk, 0, stream>>>(
        act, Wt2, hbuf, a2s, a2d, as8, ad8, NN, 448, 448);
    hipMemsetAsync(mbuf, 0, mbytes, stream);
    gat_emax_kernel<7><<<eblocks, 256, 0, stream>>>(colA, dstA, as8, ad8, mbuf);
    gat_aggC7_kernel<<<aggBlocks, 256, 0, stream>>>(row_ptr, colA, as8, ad8, mbuf, hbuf, b2, act);

    // --- layer 3 (1 head, 32 ch, log_softmax, fp32 out)
    gat_gemm_kernel<__hip_bfloat16, false><<<dim3(mtiles, 1), gemmBlk, 0, stream>>>(
        act, Wt3, hbuf, nullptr, nullptr, nullptr, nullptr, NN, 448, 32);
    gat_alpha_kernel<<<aggBlocks, 256, 0, stream>>>(hbuf, a3s, a3d, as8, ad8, 1, 32, 32);
    hipMemsetAsync(mbuf, 0, mbytes, stream);
    gat_emax_kernel<1><<<eblocks, 256, 0, stream>>>(colA, dstA, as8, ad8, mbuf);
    int fBlocks = (NN + 7) / 8;  // 8 dsts per block (2 per wave)
    gat_aggCF_kernel<<<fBlocks, 256, 0, stream>>>(row_ptr, colA, as8, ad8, mbuf, hbuf, b3, out);
}

// Round 7
// 628.860 us; speedup vs baseline: 1.6479x; 1.0755x over previous
//
#include <hip/hip_runtime.h>
#include <hip/hip_bf16.h>
#include <hip/hip_fp16.h>

#define NN 50000
#define EE 800000
#define ET (EE + NN)          // 850000 edges incl self-loops
#define NB_SCAN ((NN + 255) / 256)   // 196

typedef __attribute__((ext_vector_type(8))) short bf16x8;
typedef __attribute__((ext_vector_type(4))) float f32x4;

static __device__ __forceinline__ float bf2f(__hip_bfloat16 x) { return __bfloat162float(x); }
static __device__ __forceinline__ ushort f2bu(float f) {
    union { __hip_bfloat16 b; ushort u; } c;
    c.b = __float2bfloat16(f);
    return c.u;
}
static __device__ __forceinline__ float u2f(ushort u) {
    union { ushort u; __hip_bfloat16 b; } c;
    c.u = u;
    return __bfloat162float(c.b);
}

// ---------------------------------------------------------------- CSR build
__global__ void gat_count_kernel(const int* __restrict__ ei, int* __restrict__ cnt) {
    int i = blockIdx.x * blockDim.x + threadIdx.x;
    if (i >= ET) return;
    int dst = (i < EE) ? ei[EE + i] : (i - EE);
    atomicAdd(&cnt[dst], 1);
}

__global__ void gat_scan1_kernel(const int* __restrict__ cnt, int* __restrict__ tmp,
                                 int* __restrict__ part) {
    __shared__ int sm[256];
    int tid = threadIdx.x;
    int i = blockIdx.x * 256 + tid;
    int v = (i < NN) ? cnt[i] : 0;
    sm[tid] = v;
    __syncthreads();
    for (int o = 1; o < 256; o <<= 1) {
        int t = (tid >= o) ? sm[tid - o] : 0;
        __syncthreads();
        sm[tid] += t;
        __syncthreads();
    }
    if (i < NN) tmp[i] = sm[tid];
    if (tid == 255) part[blockIdx.x] = sm[255];
}

__global__ void gat_scan2_kernel(int* __restrict__ part) {
    __shared__ int sm[256];
    int tid = threadIdx.x;
    int v = (tid < NB_SCAN) ? part[tid] : 0;
    sm[tid] = v;
    __syncthreads();
    for (int o = 1; o < 256; o <<= 1) {
        int t = (tid >= o) ? sm[tid - o] : 0;
        __syncthreads();
        sm[tid] += t;
        __syncthreads();
    }
    part[tid] = sm[tid];
}

__global__ void gat_scan3_kernel(const int* __restrict__ tmp, const int* __restrict__ part,
                                 int* __restrict__ row_ptr) {
    int i = blockIdx.x * 256 + threadIdx.x;
    int off = (blockIdx.x > 0) ? part[blockIdx.x - 1] : 0;
    if (i < NN) row_ptr[i + 1] = tmp[i] + off;
    if (i == 0) row_ptr[0] = 0;
}

__global__ void gat_fill_kernel(const int* __restrict__ ei, const int* __restrict__ row_ptr,
                                int* __restrict__ fillc, int* __restrict__ colA) {
    int i = blockIdx.x * blockDim.x + threadIdx.x;
    if (i >= ET) return;
    int s, d;
    if (i < EE) { s = ei[i]; d = ei[EE + i]; }
    else        { s = d = i - EE; }
    int pos = row_ptr[d] + atomicAdd(&fillc[d], 1);
    colA[pos] = s;
}

// ---------------------------------------------------------------- weight transpose: Wt[n][k] = bf16(W[k][n])
__global__ void gat_wt_kernel(const float* __restrict__ W, ushort* __restrict__ Wt,
                              int K, int N) {
    int i = blockIdx.x * 256 + threadIdx.x;   // i = k*N + n
    if (i >= K * N) return;
    int k = i / N, n = i - k * N;
    Wt[(size_t)n * K + k] = f2bu(W[i]);
}

// ---------------------------------------------------------------- GEMM core (BM=256, wave owns 64x64)
// C[M,N] = A[M,K] * W[K,N]; W pre-transposed bf16 Wt[N][K].
// DOA=1: fuse 64-ch alpha dots (head = blockIdx.y). DOA=2: fuse 32-ch alpha (head 0).
#define GBM 256
#define GBN 64
#define GBK 32
#define LDP 40

template <typename AT, int DOA>
__global__ __launch_bounds__(256) void gat_gemm_kernel(
    const AT* __restrict__ A, const ushort* __restrict__ Wt,
    __hip_bfloat16* __restrict__ C,
    const float* __restrict__ Asrc, const float* __restrict__ Adst,
    float* __restrict__ as8, float* __restrict__ ad8,
    int M, int K, int N) {
    __shared__ __align__(16) ushort As[GBM * LDP];   // 20.5 KB
    __shared__ __align__(16) ushort Bs[GBN * LDP];   // 5.1 KB
    int tid = threadIdx.x;
    int wave = tid >> 6, lane = tid & 63;
    int lrow = lane & 15, lq = lane >> 4;
    int m0 = blockIdx.x * GBM, n0 = blockIdx.y * GBN;
    f32x4 acc[4][4] = {};

    for (int k0 = 0; k0 < K; k0 += GBK) {
        __syncthreads();
        // stage A: thread t -> row t, 32 k-elems (64B)
        {
            int gm = m0 + tid;
            ushort u[32];
            if constexpr (sizeof(AT) == 4) {  // fp32 A
                float4 f[8];
                if (gm < M) {
                    const float4* p = (const float4*)((const float*)A + (size_t)gm * K + k0);
#pragma unroll
                    for (int q = 0; q < 8; q++) f[q] = p[q];
                } else {
#pragma unroll
                    for (int q = 0; q < 8; q++) f[q] = make_float4(0, 0, 0, 0);
                }
#pragma unroll
                for (int q = 0; q < 8; q++) {
                    u[q * 4 + 0] = f2bu(f[q].x); u[q * 4 + 1] = f2bu(f[q].y);
                    u[q * 4 + 2] = f2bu(f[q].z); u[q * 4 + 3] = f2bu(f[q].w);
                }
            } else {  // bf16 A
                uint4 z[4];
                if (gm < M) {
                    const uint4* p = (const uint4*)((const ushort*)A + (size_t)gm * K + k0);
#pragma unroll
                    for (int q = 0; q < 4; q++) z[q] = p[q];
                } else {
#pragma unroll
                    for (int q = 0; q < 4; q++) z[q] = make_uint4(0, 0, 0, 0);
                }
#pragma unroll
                for (int q = 0; q < 4; q++) *(uint4*)&u[q * 8] = z[q];
            }
#pragma unroll
            for (int q = 0; q < 4; q++)
                *(uint4*)&As[tid * LDP + q * 8] = *(const uint4*)&u[q * 8];
        }
        // stage B from Wt[n][k]: thread t -> n=t>>2, q=t&3 (one uint4 = 8 bf16)
        {
            int n = tid >> 2, q = tid & 3;
            uint4 v = make_uint4(0, 0, 0, 0);
            if (n0 + n < N)
                v = *(const uint4*)(Wt + (size_t)(n0 + n) * K + k0 + q * 8);
            *(uint4*)&Bs[n * LDP + q * 8] = v;
        }
        __syncthreads();

        bf16x8 af[4];
#pragma unroll
        for (int rf = 0; rf < 4; rf++)
            af[rf] = *(const bf16x8*)&As[(wave * 64 + rf * 16 + lrow) * LDP + lq * 8];
#pragma unroll
        for (int ng = 0; ng < 4; ng++) {
            bf16x8 bf = *(const bf16x8*)&Bs[(ng * 16 + lrow) * LDP + lq * 8];
#pragma unroll
            for (int rf = 0; rf < 4; rf++)
                acc[rf][ng] = __builtin_amdgcn_mfma_f32_16x16x32_bf16(af[rf], bf, acc[rf][ng], 0, 0, 0);
        }
    }
    // epilogue: C/D layout col=lane&15 (within ng group), row=lq*4+r
#pragma unroll
    for (int rf = 0; rf < 4; rf++)
#pragma unroll
        for (int ng = 0; ng < 4; ng++)
#pragma unroll
            for (int r = 0; r < 4; r++) {
                int row = m0 + wave * 64 + rf * 16 + lq * 4 + r;
                int colI = n0 + ng * 16 + lrow;
                if (row < M && colI < N)
                    C[(size_t)row * N + colI] = __float2bfloat16(acc[rf][ng][r]);
            }
    if constexpr (DOA == 1) {
        // fused alpha dots for head = blockIdx.y (64 channels)
        int head = blockIdx.y;
        float as_l[4], ad_l[4];
#pragma unroll
        for (int ng = 0; ng < 4; ng++) {
            as_l[ng] = Asrc[head * 64 + ng * 16 + lrow];
            ad_l[ng] = Adst[head * 64 + ng * 16 + lrow];
        }
#pragma unroll
        for (int rf = 0; rf < 4; rf++)
#pragma unroll
            for (int r = 0; r < 4; r++) {
                float ps = 0.f, pd = 0.f;
#pragma unroll
                for (int ng = 0; ng < 4; ng++) {
                    ps += acc[rf][ng][r] * as_l[ng];
                    pd += acc[rf][ng][r] * ad_l[ng];
                }
#pragma unroll
                for (int o = 1; o < 16; o <<= 1) {
                    ps += __shfl_xor(ps, o);
                    pd += __shfl_xor(pd, o);
                }
                int row = m0 + wave * 64 + rf * 16 + lq * 4 + r;
                if (lrow == 0 && row < M) {
                    as8[(size_t)row * 8 + head] = ps;
                    ad8[(size_t)row * 8 + head] = pd;
                }
            }
    } else if constexpr (DOA == 2) {
        // fused alpha dots, single head, 32 channels (ng 0..1)
        float as_l[2], ad_l[2];
#pragma unroll
        for (int ng = 0; ng < 2; ng++) {
            as_l[ng] = Asrc[ng * 16 + lrow];
            ad_l[ng] = Adst[ng * 16 + lrow];
        }
#pragma unroll
        for (int rf = 0; rf < 4; rf++)
#pragma unroll
            for (int r = 0; r < 4; r++) {
                float ps = acc[rf][0][r] * as_l[0] + acc[rf][1][r] * as_l[1];
                float pd = acc[rf][0][r] * ad_l[0] + acc[rf][1][r] * ad_l[1];
#pragma unroll
                for (int o = 1; o < 16; o <<= 1) {
                    ps += __shfl_xor(ps, o);
                    pd += __shfl_xor(pd, o);
                }
                int row = m0 + wave * 64 + rf * 16 + lq * 4 + r;
                if (lrow == 0 && row < M) {
                    as8[(size_t)row * 8] = ps;
                    ad8[(size_t)row * 8] = pd;
                }
            }
    }
}

// ---------------------------------------------------------------- Phase C: wave-per-dst accumulate, w = exp(e) (no max shift)
// lane l<56 owns head l>>3, channels 8l..8l+7 (16B/lane gather+store)
__global__ void gat_aggC7_kernel(const int* __restrict__ rp, const int* __restrict__ colA,
                                 const float* __restrict__ as8, const float* __restrict__ ad8,
                                 const __hip_bfloat16* __restrict__ h,
                                 const float* __restrict__ bias,
                                 __hip_bfloat16* __restrict__ outp) {
    int d = blockIdx.x * 4 + (threadIdx.x >> 6);
    if (d >= NN) return;
    int lane = threadIdx.x & 63;
    if (lane >= 56) return;
    int hh = lane >> 3;
    const ushort* hu = (const ushort*)h;
    float adh = ad8[(size_t)d * 8 + hh];
    int s0 = rp[d], s1 = rp[d + 1];
    float acc[8] = {0.f, 0.f, 0.f, 0.f, 0.f, 0.f, 0.f, 0.f};
    float den = 0.f;
    int j = s0;
    for (; j + 4 <= s1; j += 4) {
        int sA = colA[j], sB = colA[j + 1], sC = colA[j + 2], sD = colA[j + 3];
        float eA = as8[(size_t)sA * 8 + hh] + adh;
        float eB = as8[(size_t)sB * 8 + hh] + adh;
        float eC = as8[(size_t)sC * 8 + hh] + adh;
        float eD = as8[(size_t)sD * 8 + hh] + adh;
        uint4 hA = *(const uint4*)(hu + (size_t)sA * 448 + lane * 8);
        uint4 hB = *(const uint4*)(hu + (size_t)sB * 448 + lane * 8);
        uint4 hC = *(const uint4*)(hu + (size_t)sC * 448 + lane * 8);
        uint4 hD = *(const uint4*)(hu + (size_t)sD * 448 + lane * 8);
        eA = (eA > 0.f) ? eA : 0.2f * eA;
        eB = (eB > 0.f) ? eB : 0.2f * eB;
        eC = (eC > 0.f) ? eC : 0.2f * eC;
        eD = (eD > 0.f) ? eD : 0.2f * eD;
        float wA = __expf(eA), wB = __expf(eB);
        float wC = __expf(eC), wD = __expf(eD);
        den += (wA + wB) + (wC + wD);
        const ushort* pA = (const ushort*)&hA;
        const ushort* pB = (const ushort*)&hB;
        const ushort* pC = (const ushort*)&hC;
        const ushort* pD = (const ushort*)&hD;
#pragma unroll
        for (int k = 0; k < 8; k++) {
            acc[k] += wA * u2f(pA[k]) + wB * u2f(pB[k]);
            acc[k] += wC * u2f(pC[k]) + wD * u2f(pD[k]);
        }
    }
    for (; j < s1; j++) {
        int s = colA[j];
        float e = as8[(size_t)s * 8 + hh] + adh;
        e = (e > 0.f) ? e : 0.2f * e;
        float w = __expf(e);
        uint4 hv = *(const uint4*)(hu + (size_t)s * 448 + lane * 8);
        const ushort* hp = (const ushort*)&hv;
        den += w;
#pragma unroll
        for (int k = 0; k < 8; k++) acc[k] += w * u2f(hp[k]);
    }
    float inv = 1.f / (den + 1e-16f);
    const float4* bp = (const float4*)(bias + lane * 8);
    float4 bb0 = bp[0], bb1 = bp[1];
    float bv[8] = {bb0.x, bb0.y, bb0.z, bb0.w, bb1.x, bb1.y, bb1.z, bb1.w};
    ushort o8[8];
#pragma unroll
    for (int k = 0; k < 8; k++) {
        float o = acc[k] * inv + bv[k];
        o = fmaxf(o, 0.f);
        o8[k] = f2bu(o);
    }
    *(uint4*)((ushort*)outp + (size_t)d * 448 + lane * 8) = *(const uint4*)o8;
}

// ---------------------------------------------------------------- Phase C final: 2 dsts/wave, 32 ch, w=exp(e), log_softmax
__global__ void gat_aggCF_kernel(const int* __restrict__ rp, const int* __restrict__ colA,
                                 const float* __restrict__ as8, const float* __restrict__ ad8,
                                 const __hip_bfloat16* __restrict__ h,
                                 const float* __restrict__ bias,
                                 float* __restrict__ outp) {
    int wid = blockIdx.x * 4 + (threadIdx.x >> 6);
    int lane = threadIdx.x & 63;
    int half = lane >> 5, c = lane & 31;
    int dreal = wid * 2 + half;
    bool valid = dreal < NN;
    int d = valid ? dreal : (NN - 1);
    float adh = ad8[(size_t)d * 8];
    int s0 = rp[d], s1 = rp[d + 1];
    float acc = 0.f, den = 0.f;
    int j = s0;
    for (; j + 2 <= s1; j += 2) {
        int sA = colA[j], sB = colA[j + 1];
        float eA = as8[(size_t)sA * 8] + adh;
        float eB = as8[(size_t)sB * 8] + adh;
        float vA = bf2f(h[(size_t)sA * 32 + c]);
        float vB = bf2f(h[(size_t)sB * 32 + c]);
        eA = (eA > 0.f) ? eA : 0.2f * eA;
        eB = (eB > 0.f) ? eB : 0.2f * eB;
        float wA = __expf(eA), wB = __expf(eB);
        den += wA + wB;
        acc += wA * vA + wB * vB;
    }
    for (; j < s1; j++) {
        int s = colA[j];
        float e = as8[(size_t)s * 8] + adh;
        e = (e > 0.f) ? e : 0.2f * e;
        float w = __expf(e);
        den += w;
        acc += w * bf2f(h[(size_t)s * 32 + c]);
    }
    float o = acc / (den + 1e-16f) + bias[c];
    float t = o;
#pragma unroll
    for (int off = 16; off > 0; off >>= 1) t = fmaxf(t, __shfl_xor(t, off));
    float ex = __expf(o - t);
#pragma unroll
    for (int off = 16; off > 0; off >>= 1) ex += __shfl_xor(ex, off);
    float res = o - t - __logf(ex);
    if (valid) outp[(size_t)d * 32 + c] = res;
}

// ---------------------------------------------------------------- launch
extern "C" void kernel_launch(void* const* d_in, const int* in_sizes, int n_in,
                              void* d_out, int out_size, void* d_ws, size_t ws_size,
                              hipStream_t stream) {
    const float* x   = (const float*)d_in[0];
    const int*   ei  = (const int*)d_in[1];
    const float* W1  = (const float*)d_in[2];
    const float* a1s = (const float*)d_in[3];
    const float* a1d = (const float*)d_in[4];
    const float* b1  = (const float*)d_in[5];
    const float* W2  = (const float*)d_in[6];
    const float* a2s = (const float*)d_in[7];
    const float* a2d = (const float*)d_in[8];
    const float* b2  = (const float*)d_in[9];
    const float* W3  = (const float*)d_in[10];
    const float* a3s = (const float*)d_in[11];
    const float* a3d = (const float*)d_in[12];
    const float* b3  = (const float*)d_in[13];
    float* out = (float*)d_out;

    // workspace layout (~98 MB)
    char* w = (char*)d_ws;
    __hip_bfloat16* hbuf = (__hip_bfloat16*)w;                 // N*448 bf16
    __hip_bfloat16* act  = hbuf + (size_t)NN * 448;            // N*448 bf16
    float* as8 = (float*)(act + (size_t)NN * 448);             // N*8 f32
    float* ad8 = as8 + (size_t)NN * 8;                         // N*8 f32
    int* cnt     = (int*)(ad8 + (size_t)NN * 8);               // N
    int* fillc   = cnt + NN;                                   // N
    int* row_ptr = fillc + NN;                                 // N+4 (padded)
    int* tmp     = row_ptr + (NN + 4);                         // N
    int* part    = tmp + NN;                                   // 256
    int* colA    = part + 256;                                 // ET
    char* pw = (char*)(colA + ET);
    pw = (char*)(((uintptr_t)pw + 15) & ~(uintptr_t)15);
    ushort* Wt1 = (ushort*)pw;                                 // 448*256
    ushort* Wt2 = Wt1 + 448 * 256;                             // 448*448
    ushort* Wt3 = Wt2 + 448 * 448;                             // 32*448

    hipMemsetAsync(cnt, 0, 2 * (size_t)NN * sizeof(int), stream);  // cnt + fillc
    int eblocks = (ET + 255) / 256;
    gat_count_kernel<<<eblocks, 256, 0, stream>>>(ei, cnt);
    gat_scan1_kernel<<<NB_SCAN, 256, 0, stream>>>(cnt, tmp, part);
    gat_scan2_kernel<<<1, 256, 0, stream>>>(part);
    gat_scan3_kernel<<<NB_SCAN, 256, 0, stream>>>(tmp, part, row_ptr);
    gat_fill_kernel<<<eblocks, 256, 0, stream>>>(ei, row_ptr, fillc, colA);

    // weight transposes (bf16, [N][K])
    gat_wt_kernel<<<(256 * 448 + 255) / 256, 256, 0, stream>>>(W1, Wt1, 256, 448);
    gat_wt_kernel<<<(448 * 448 + 255) / 256, 256, 0, stream>>>(W2, Wt2, 448, 448);
    gat_wt_kernel<<<(448 * 32 + 255) / 256, 256, 0, stream>>>(W3, Wt3, 448, 32);

    dim3 gemmBlk(256);
    int mtiles = (NN + GBM - 1) / GBM;  // 196
    int aggBlocks = (NN + 3) / 4;       // 12500

    // --- layer 1 (alpha fused into GEMM epilogue)
    gat_gemm_kernel<float, 1><<<dim3(mtiles, 7), gemmBlk, 0, stream>>>(
        x, Wt1, hbuf, a1s, a1d, as8, ad8, NN, 256, 448);
    gat_aggC7_kernel<<<aggBlocks, 256, 0, stream>>>(row_ptr, colA, as8, ad8, hbuf, b1, act);

    // --- layer 2
    gat_gemm_kernel<__hip_bfloat16, 1><<<dim3(mtiles, 7), gemmBlk, 0, stream>>>(
        act, Wt2, hbuf, a2s, a2d, as8, ad8, NN, 448, 448);
    gat_aggC7_kernel<<<aggBlocks, 256, 0, stream>>>(row_ptr, colA, as8, ad8, hbuf, b2, act);

    // --- layer 3 (1 head, 32 ch, alpha fused, log_softmax, fp32 out)
    gat_gemm_kernel<__hip_bfloat16, 2><<<dim3(mtiles, 1), gemmBlk, 0, stream>>>(
        act, Wt3, hbuf, a3s, a3d, as8, ad8, NN, 448, 32);
    int fBlocks = (NN + 7) / 8;  // 8 dsts per block (2 per wave)
    gat_aggCF_kernel<<<fBlocks, 256, 0, stream>>>(row_ptr, colA, as8, ad8, hbuf, b3, out);
}

// Round 8
// 595.554 us; speedup vs baseline: 1.7400x; 1.0559x over previous
//
#include <hip/hip_runtime.h>
#include <hip/hip_bf16.h>
#include <hip/hip_fp16.h>

#define NN 50000
#define NP 50176              // NN padded to multiple of 256 (GEMM tiles, no bounds checks)
#define EE 800000
#define ET (EE + NN)          // 850000 edges incl self-loops
#define NB_SCAN ((NN + 255) / 256)   // 196

typedef __attribute__((ext_vector_type(8))) short bf16x8;
typedef __attribute__((ext_vector_type(4))) float f32x4;

static __device__ __forceinline__ float bf2f(__hip_bfloat16 x) { return __bfloat162float(x); }
static __device__ __forceinline__ ushort f2bu(float f) {
    union { __hip_bfloat16 b; ushort u; } c;
    c.b = __float2bfloat16(f);
    return c.u;
}
static __device__ __forceinline__ float u2f(ushort u) {
    union { ushort u; __hip_bfloat16 b; } c;
    c.u = u;
    return __bfloat162float(c.b);
}
// async global->LDS DMA, 16B per lane; lds dest must be wave-uniform base
static __device__ __forceinline__ void gl2lds(const ushort* g, ushort* l) {
    __builtin_amdgcn_global_load_lds(
        (const __attribute__((address_space(1))) void*)g,
        (__attribute__((address_space(3))) void*)l,
        16, 0, 0);
}

// ---------------------------------------------------------------- CSR build
__global__ void gat_count_kernel(const int* __restrict__ ei, int* __restrict__ cnt) {
    int i = blockIdx.x * blockDim.x + threadIdx.x;
    if (i >= ET) return;
    int dst = (i < EE) ? ei[EE + i] : (i - EE);
    atomicAdd(&cnt[dst], 1);
}

__global__ void gat_scan1_kernel(const int* __restrict__ cnt, int* __restrict__ tmp,
                                 int* __restrict__ part) {
    __shared__ int sm[256];
    int tid = threadIdx.x;
    int i = blockIdx.x * 256 + tid;
    int v = (i < NN) ? cnt[i] : 0;
    sm[tid] = v;
    __syncthreads();
    for (int o = 1; o < 256; o <<= 1) {
        int t = (tid >= o) ? sm[tid - o] : 0;
        __syncthreads();
        sm[tid] += t;
        __syncthreads();
    }
    if (i < NN) tmp[i] = sm[tid];
    if (tid == 255) part[blockIdx.x] = sm[255];
}

__global__ void gat_scan2_kernel(int* __restrict__ part) {
    __shared__ int sm[256];
    int tid = threadIdx.x;
    int v = (tid < NB_SCAN) ? part[tid] : 0;
    sm[tid] = v;
    __syncthreads();
    for (int o = 1; o < 256; o <<= 1) {
        int t = (tid >= o) ? sm[tid - o] : 0;
        __syncthreads();
        sm[tid] += t;
        __syncthreads();
    }
    part[tid] = sm[tid];
}

__global__ void gat_scan3_kernel(const int* __restrict__ tmp, const int* __restrict__ part,
                                 int* __restrict__ row_ptr) {
    int i = blockIdx.x * 256 + threadIdx.x;
    int off = (blockIdx.x > 0) ? part[blockIdx.x - 1] : 0;
    if (i < NN) row_ptr[i + 1] = tmp[i] + off;
    if (i == 0) row_ptr[0] = 0;
}

__global__ void gat_fill_kernel(const int* __restrict__ ei, const int* __restrict__ row_ptr,
                                int* __restrict__ fillc, int* __restrict__ colA) {
    int i = blockIdx.x * blockDim.x + threadIdx.x;
    if (i >= ET) return;
    int s, d;
    if (i < EE) { s = ei[i]; d = ei[EE + i]; }
    else        { s = d = i - EE; }
    int pos = row_ptr[d] + atomicAdd(&fillc[d], 1);
    colA[pos] = s;
}

// ---------------------------------------------------------------- weight transpose: Wt[n][k] = bf16(W[k][n])
__global__ void gat_wt_kernel(const float* __restrict__ W, ushort* __restrict__ Wt,
                              int K, int N) {
    int i = blockIdx.x * 256 + threadIdx.x;   // i = k*N + n
    if (i >= K * N) return;
    int k = i / N, n = i - k * N;
    Wt[(size_t)n * K + k] = f2bu(W[i]);
}

// ---------------------------------------------------------------- x -> bf16 (padded rows read as poison, never stored)
__global__ void gat_x2b_kernel(const float* __restrict__ x, ushort* __restrict__ xb) {
    int i = blockIdx.x * 256 + threadIdx.x;   // quad index
    if (i >= NN * 256 / 4) return;
    float4 f = ((const float4*)x)[i];
    ushort u[4] = {f2bu(f.x), f2bu(f.y), f2bu(f.z), f2bu(f.w)};
    ((uint2*)xb)[i] = *(const uint2*)u;
}

// ---------------------------------------------------------------- GEMM core (bf16 A, DMA staging, LDS dbuf)
// C[M,N] = A[M,K] * W[K,N]; W pre-transposed bf16 Wt[N][K] (rows padded to >= n0+64).
// A padded to NP rows. DOA=1: fuse 64-ch alpha dots (head = blockIdx.y). DOA=2: 32-ch alpha.
#define GBM 256
#define GBN 64
#define GBK 32

template <int DOA>
__global__ __launch_bounds__(256) void gat_gemm_kernel(
    const ushort* __restrict__ A, const ushort* __restrict__ Wt,
    __hip_bfloat16* __restrict__ C,
    const float* __restrict__ Asrc, const float* __restrict__ Adst,
    float* __restrict__ as8, float* __restrict__ ad8,
    int M, int K, int N) {
    __shared__ __align__(16) ushort As[2][GBM * GBK];   // 2 x 16 KB
    __shared__ __align__(16) ushort Bs[2][GBN * GBK];   // 2 x 4 KB
    int tid = threadIdx.x;
    int wave = tid >> 6, lane = tid & 63;
    int lrow = lane & 15, lq = lane >> 4;
    int m0 = blockIdx.x * GBM, n0 = blockIdx.y * GBN;
    int srow = lane >> 2, schunk = (lane & 3) * 8;      // 4 lanes per 64B row-chunk
    f32x4 acc[4][4] = {};

    int KT = K / GBK;
    // prologue: stage k-tile 0 into buffer 0
    {
#pragma unroll
        for (int q = 0; q < 4; q++) {
            const ushort* gp = A + (size_t)(m0 + wave * 64 + q * 16 + srow) * K + schunk;
            gl2lds(gp, &As[0][(wave * 64 + q * 16) * GBK]);
        }
        const ushort* gb = Wt + (size_t)(n0 + wave * 16 + srow) * K + schunk;
        gl2lds(gb, &Bs[0][wave * 16 * GBK]);
    }
    for (int kt = 0; kt < KT; kt++) {
        __syncthreads();   // drains DMA for buffer kt&1 (compiler emits vmcnt(0) before s_barrier)
        if (kt + 1 < KT) {
            int nb = (kt + 1) & 1, k0 = (kt + 1) * GBK;
#pragma unroll
            for (int q = 0; q < 4; q++) {
                const ushort* gp = A + (size_t)(m0 + wave * 64 + q * 16 + srow) * K + k0 + schunk;
                gl2lds(gp, &As[nb][(wave * 64 + q * 16) * GBK]);
            }
            const ushort* gb = Wt + (size_t)(n0 + wave * 16 + srow) * K + k0 + schunk;
            gl2lds(gb, &Bs[nb][wave * 16 * GBK]);
        }
        int b = kt & 1;
        bf16x8 af[4];
#pragma unroll
        for (int rf = 0; rf < 4; rf++)
            af[rf] = *(const bf16x8*)&As[b][(wave * 64 + rf * 16 + lrow) * GBK + lq * 8];
#pragma unroll
        for (int ng = 0; ng < 4; ng++) {
            bf16x8 bf = *(const bf16x8*)&Bs[b][(ng * 16 + lrow) * GBK + lq * 8];
#pragma unroll
            for (int rf = 0; rf < 4; rf++)
                acc[rf][ng] = __builtin_amdgcn_mfma_f32_16x16x32_bf16(af[rf], bf, acc[rf][ng], 0, 0, 0);
        }
    }
    // epilogue: C/D layout col=lane&15 (within ng group), row=lq*4+r
#pragma unroll
    for (int rf = 0; rf < 4; rf++)
#pragma unroll
        for (int ng = 0; ng < 4; ng++)
#pragma unroll
            for (int r = 0; r < 4; r++) {
                int row = m0 + wave * 64 + rf * 16 + lq * 4 + r;
                int colI = n0 + ng * 16 + lrow;
                if (row < M && colI < N)
                    C[(size_t)row * N + colI] = __float2bfloat16(acc[rf][ng][r]);
            }
    if constexpr (DOA == 1) {
        int head = blockIdx.y;
        float as_l[4], ad_l[4];
#pragma unroll
        for (int ng = 0; ng < 4; ng++) {
            as_l[ng] = Asrc[head * 64 + ng * 16 + lrow];
            ad_l[ng] = Adst[head * 64 + ng * 16 + lrow];
        }
#pragma unroll
        for (int rf = 0; rf < 4; rf++)
#pragma unroll
            for (int r = 0; r < 4; r++) {
                float ps = 0.f, pd = 0.f;
#pragma unroll
                for (int ng = 0; ng < 4; ng++) {
                    ps += acc[rf][ng][r] * as_l[ng];
                    pd += acc[rf][ng][r] * ad_l[ng];
                }
#pragma unroll
                for (int o = 1; o < 16; o <<= 1) {
                    ps += __shfl_xor(ps, o);
                    pd += __shfl_xor(pd, o);
                }
                int row = m0 + wave * 64 + rf * 16 + lq * 4 + r;
                if (lrow == 0 && row < M) {
                    as8[(size_t)row * 8 + head] = ps;
                    ad8[(size_t)row * 8 + head] = pd;
                }
            }
    } else if constexpr (DOA == 2) {
        float as_l[2], ad_l[2];
#pragma unroll
        for (int ng = 0; ng < 2; ng++) {
            as_l[ng] = Asrc[ng * 16 + lrow];
            ad_l[ng] = Adst[ng * 16 + lrow];
        }
#pragma unroll
        for (int rf = 0; rf < 4; rf++)
#pragma unroll
            for (int r = 0; r < 4; r++) {
                float ps = acc[rf][0][r] * as_l[0] + acc[rf][1][r] * as_l[1];
                float pd = acc[rf][0][r] * ad_l[0] + acc[rf][1][r] * ad_l[1];
#pragma unroll
                for (int o = 1; o < 16; o <<= 1) {
                    ps += __shfl_xor(ps, o);
                    pd += __shfl_xor(pd, o);
                }
                int row = m0 + wave * 64 + rf * 16 + lq * 4 + r;
                if (lrow == 0 && row < M) {
                    as8[(size_t)row * 8] = ps;
                    ad8[(size_t)row * 8] = pd;
                }
            }
    }
}

// ---------------------------------------------------------------- Phase C: wave-per-dst accumulate, w = exp(e)
// lane l<56 owns head l>>3, channels 8l..8l+7 (16B/lane gather+store)
__global__ void gat_aggC7_kernel(const int* __restrict__ rp, const int* __restrict__ colA,
                                 const float* __restrict__ as8, const float* __restrict__ ad8,
                                 const __hip_bfloat16* __restrict__ h,
                                 const float* __restrict__ bias,
                                 __hip_bfloat16* __restrict__ outp) {
    int d = blockIdx.x * 4 + (threadIdx.x >> 6);
    if (d >= NN) return;
    int lane = threadIdx.x & 63;
    if (lane >= 56) return;
    int hh = lane >> 3;
    const ushort* hu = (const ushort*)h;
    float adh = ad8[(size_t)d * 8 + hh];
    int s0 = rp[d], s1 = rp[d + 1];
    float acc[8] = {0.f, 0.f, 0.f, 0.f, 0.f, 0.f, 0.f, 0.f};
    float den = 0.f;
    int j = s0;
    for (; j + 4 <= s1; j += 4) {
        int sA = colA[j], sB = colA[j + 1], sC = colA[j + 2], sD = colA[j + 3];
        float eA = as8[(size_t)sA * 8 + hh] + adh;
        float eB = as8[(size_t)sB * 8 + hh] + adh;
        float eC = as8[(size_t)sC * 8 + hh] + adh;
        float eD = as8[(size_t)sD * 8 + hh] + adh;
        uint4 hA = *(const uint4*)(hu + (size_t)sA * 448 + lane * 8);
        uint4 hB = *(const uint4*)(hu + (size_t)sB * 448 + lane * 8);
        uint4 hC = *(const uint4*)(hu + (size_t)sC * 448 + lane * 8);
        uint4 hD = *(const uint4*)(hu + (size_t)sD * 448 + lane * 8);
        eA = (eA > 0.f) ? eA : 0.2f * eA;
        eB = (eB > 0.f) ? eB : 0.2f * eB;
        eC = (eC > 0.f) ? eC : 0.2f * eC;
        eD = (eD > 0.f) ? eD : 0.2f * eD;
        float wA = __expf(eA), wB = __expf(eB);
        float wC = __expf(eC), wD = __expf(eD);
        den += (wA + wB) + (wC + wD);
        const ushort* pA = (const ushort*)&hA;
        const ushort* pB = (const ushort*)&hB;
        const ushort* pC = (const ushort*)&hC;
        const ushort* pD = (const ushort*)&hD;
#pragma unroll
        for (int k = 0; k < 8; k++) {
            acc[k] += wA * u2f(pA[k]) + wB * u2f(pB[k]);
            acc[k] += wC * u2f(pC[k]) + wD * u2f(pD[k]);
        }
    }
    for (; j < s1; j++) {
        int s = colA[j];
        float e = as8[(size_t)s * 8 + hh] + adh;
        e = (e > 0.f) ? e : 0.2f * e;
        float w = __expf(e);
        uint4 hv = *(const uint4*)(hu + (size_t)s * 448 + lane * 8);
        const ushort* hp = (const ushort*)&hv;
        den += w;
#pragma unroll
        for (int k = 0; k < 8; k++) acc[k] += w * u2f(hp[k]);
    }
    float inv = 1.f / (den + 1e-16f);
    const float4* bp = (const float4*)(bias + lane * 8);
    float4 bb0 = bp[0], bb1 = bp[1];
    float bv[8] = {bb0.x, bb0.y, bb0.z, bb0.w, bb1.x, bb1.y, bb1.z, bb1.w};
    ushort o8[8];
#pragma unroll
    for (int k = 0; k < 8; k++) {
        float o = acc[k] * inv + bv[k];
        o = fmaxf(o, 0.f);
        o8[k] = f2bu(o);
    }
    *(uint4*)((ushort*)outp + (size_t)d * 448 + lane * 8) = *(const uint4*)o8;
}

// ---------------------------------------------------------------- Phase C final: 2 dsts/wave, 32 ch, w=exp(e), log_softmax
__global__ void gat_aggCF_kernel(const int* __restrict__ rp, const int* __restrict__ colA,
                                 const float* __restrict__ as8, const float* __restrict__ ad8,
                                 const __hip_bfloat16* __restrict__ h,
                                 const float* __restrict__ bias,
                                 float* __restrict__ outp) {
    int wid = blockIdx.x * 4 + (threadIdx.x >> 6);
    int lane = threadIdx.x & 63;
    int half = lane >> 5, c = lane & 31;
    int dreal = wid * 2 + half;
    bool valid = dreal < NN;
    int d = valid ? dreal : (NN - 1);
    float adh = ad8[(size_t)d * 8];
    int s0 = rp[d], s1 = rp[d + 1];
    float acc = 0.f, den = 0.f;
    int j = s0;
    for (; j + 2 <= s1; j += 2) {
        int sA = colA[j], sB = colA[j + 1];
        float eA = as8[(size_t)sA * 8] + adh;
        float eB = as8[(size_t)sB * 8] + adh;
        float vA = bf2f(h[(size_t)sA * 32 + c]);
        float vB = bf2f(h[(size_t)sB * 32 + c]);
        eA = (eA > 0.f) ? eA : 0.2f * eA;
        eB = (eB > 0.f) ? eB : 0.2f * eB;
        float wA = __expf(eA), wB = __expf(eB);
        den += wA + wB;
        acc += wA * vA + wB * vB;
    }
    for (; j < s1; j++) {
        int s = colA[j];
        float e = as8[(size_t)s * 8] + adh;
        e = (e > 0.f) ? e : 0.2f * e;
        float w = __expf(e);
        den += w;
        acc += w * bf2f(h[(size_t)s * 32 + c]);
    }
    float o = acc / (den + 1e-16f) + bias[c];
    float t = o;
#pragma unroll
    for (int off = 16; off > 0; off >>= 1) t = fmaxf(t, __shfl_xor(t, off));
    float ex = __expf(o - t);
#pragma unroll
    for (int off = 16; off > 0; off >>= 1) ex += __shfl_xor(ex, off);
    float res = o - t - __logf(ex);
    if (valid) outp[(size_t)d * 32 + c] = res;
}

// ---------------------------------------------------------------- launch
extern "C" void kernel_launch(void* const* d_in, const int* in_sizes, int n_in,
                              void* d_out, int out_size, void* d_ws, size_t ws_size,
                              hipStream_t stream) {
    const float* x   = (const float*)d_in[0];
    const int*   ei  = (const int*)d_in[1];
    const float* W1  = (const float*)d_in[2];
    const float* a1s = (const float*)d_in[3];
    const float* a1d = (const float*)d_in[4];
    const float* b1  = (const float*)d_in[5];
    const float* W2  = (const float*)d_in[6];
    const float* a2s = (const float*)d_in[7];
    const float* a2d = (const float*)d_in[8];
    const float* b2  = (const float*)d_in[9];
    const float* W3  = (const float*)d_in[10];
    const float* a3s = (const float*)d_in[11];
    const float* a3d = (const float*)d_in[12];
    const float* b3  = (const float*)d_in[13];
    float* out = (float*)d_out;

    // workspace layout (~124 MB); all GEMM A-sources padded to NP rows
    char* w = (char*)d_ws;
    ushort* xb = (ushort*)w;                                   // NP*256 bf16
    __hip_bfloat16* hbuf = (__hip_bfloat16*)(xb + (size_t)NP * 256);  // NP*448
    __hip_bfloat16* act  = hbuf + (size_t)NP * 448;            // NP*448
    float* as8 = (float*)(act + (size_t)NP * 448);             // N*8 f32
    float* ad8 = as8 + (size_t)NN * 8;                         // N*8 f32
    int* cnt     = (int*)(ad8 + (size_t)NN * 8);               // N
    int* fillc   = cnt + NN;                                   // N
    int* row_ptr = fillc + NN;                                 // N+4 (padded)
    int* tmp     = row_ptr + (NN + 4);                         // N
    int* part    = tmp + NN;                                   // 256
    int* colA    = part + 256;                                 // ET
    char* pw = (char*)(colA + ET);
    pw = (char*)(((uintptr_t)pw + 15) & ~(uintptr_t)15);
    ushort* Wt1 = (ushort*)pw;                                 // 448*256
    ushort* Wt2 = Wt1 + 448 * 256;                             // 448*448
    ushort* Wt3 = Wt2 + 448 * 448;                             // 64*448 (rows 32..63 poison, never stored)

    hipMemsetAsync(cnt, 0, 2 * (size_t)NN * sizeof(int), stream);  // cnt + fillc
    int eblocks = (ET + 255) / 256;
    gat_count_kernel<<<eblocks, 256, 0, stream>>>(ei, cnt);
    gat_scan1_kernel<<<NB_SCAN, 256, 0, stream>>>(cnt, tmp, part);
    gat_scan2_kernel<<<1, 256, 0, stream>>>(part);
    gat_scan3_kernel<<<NB_SCAN, 256, 0, stream>>>(tmp, part, row_ptr);
    gat_fill_kernel<<<eblocks, 256, 0, stream>>>(ei, row_ptr, fillc, colA);

    // weight transposes (bf16, [N][K]) + x conversion
    gat_wt_kernel<<<(256 * 448 + 255) / 256, 256, 0, stream>>>(W1, Wt1, 256, 448);
    gat_wt_kernel<<<(448 * 448 + 255) / 256, 256, 0, stream>>>(W2, Wt2, 448, 448);
    gat_wt_kernel<<<(448 * 32 + 255) / 256, 256, 0, stream>>>(W3, Wt3, 448, 32);
    gat_x2b_kernel<<<(NN * 64 + 255) / 256, 256, 0, stream>>>(x, xb);

    dim3 gemmBlk(256);
    int mtiles = NP / GBM;              // 196
    int aggBlocks = (NN + 3) / 4;       // 12500

    // --- layer 1 (alpha fused into GEMM epilogue)
    gat_gemm_kernel<1><<<dim3(mtiles, 7), gemmBlk, 0, stream>>>(
        xb, Wt1, hbuf, a1s, a1d, as8, ad8, NN, 256, 448);
    gat_aggC7_kernel<<<aggBlocks, 256, 0, stream>>>(row_ptr, colA, as8, ad8, hbuf, b1, act);

    // --- layer 2
    gat_gemm_kernel<1><<<dim3(mtiles, 7), gemmBlk, 0, stream>>>(
        (const ushort*)act, Wt2, hbuf, a2s, a2d, as8, ad8, NN, 448, 448);
    gat_aggC7_kernel<<<aggBlocks, 256, 0, stream>>>(row_ptr, colA, as8, ad8, hbuf, b2, act);

    // --- layer 3 (1 head, 32 ch, alpha fused, log_softmax, fp32 out)
    gat_gemm_kernel<2><<<dim3(mtiles, 1), gemmBlk, 0, stream>>>(
        (const ushort*)act, Wt3, hbuf, a3s, a3d, as8, ad8, NN, 448, 32);
    int fBlocks = (NN + 7) / 8;  // 8 dsts per block (2 per wave)
    gat_aggCF_kernel<<<fBlocks, 256, 0, stream>>>(row_ptr, colA, as8, ad8, hbuf, b3, out);
}

// Round 10
// 493.213 us; speedup vs baseline: 2.1011x; 1.2075x over previous
//
#include <hip/hip_runtime.h>
#include <hip/hip_bf16.h>
#include <hip/hip_fp16.h>

#define NN 50000
#define NP 50176              // NN padded to multiple of 256 (GEMM tiles, no bounds checks)
#define EE 800000
#define ET (EE + NN)          // 850000 edges incl self-loops
#define NB_SCAN ((NN + 255) / 256)   // 196

typedef __attribute__((ext_vector_type(8))) short bf16x8;
typedef __attribute__((ext_vector_type(4))) float f32x4;

static __device__ __forceinline__ float bf2f(__hip_bfloat16 x) { return __bfloat162float(x); }
static __device__ __forceinline__ ushort f2bu(float f) {
    union { __hip_bfloat16 b; ushort u; } c;
    c.b = __float2bfloat16(f);
    return c.u;
}
static __device__ __forceinline__ float u2f(ushort u) {
    union { ushort u; __hip_bfloat16 b; } c;
    c.u = u;
    return __bfloat162float(c.b);
}
// fp8 e4m3 HW conversion (gfx950). Encode+decode use the same HW format -> self-consistent.
static __device__ __forceinline__ unsigned char f2fp8(float v) {
    int p = __builtin_amdgcn_cvt_pk_fp8_f32(v, v, 0, false);
    return (unsigned char)(p & 0xff);
}
// decode 4 packed fp8 bytes and accumulate w * val into acc[0..3] (selectors must be ICE)
static __device__ __forceinline__ void fp8acc4(unsigned v, float w, float* acc) {
    acc[0] += w * __builtin_amdgcn_cvt_f32_fp8(v, 0);
    acc[1] += w * __builtin_amdgcn_cvt_f32_fp8(v, 1);
    acc[2] += w * __builtin_amdgcn_cvt_f32_fp8(v, 2);
    acc[3] += w * __builtin_amdgcn_cvt_f32_fp8(v, 3);
}
// async global->LDS DMA, 16B per lane; lds dest must be wave-uniform base
static __device__ __forceinline__ void gl2lds(const ushort* g, ushort* l) {
    __builtin_amdgcn_global_load_lds(
        (const __attribute__((address_space(1))) void*)g,
        (__attribute__((address_space(3))) void*)l,
        16, 0, 0);
}

// ---------------------------------------------------------------- CSR build
__global__ void gat_count_kernel(const int* __restrict__ ei, int* __restrict__ cnt) {
    int i = blockIdx.x * blockDim.x + threadIdx.x;
    if (i >= ET) return;
    int dst = (i < EE) ? ei[EE + i] : (i - EE);
    atomicAdd(&cnt[dst], 1);
}

__global__ void gat_scan1_kernel(const int* __restrict__ cnt, int* __restrict__ tmp,
                                 int* __restrict__ part) {
    __shared__ int sm[256];
    int tid = threadIdx.x;
    int i = blockIdx.x * 256 + tid;
    int v = (i < NN) ? cnt[i] : 0;
    sm[tid] = v;
    __syncthreads();
    for (int o = 1; o < 256; o <<= 1) {
        int t = (tid >= o) ? sm[tid - o] : 0;
        __syncthreads();
        sm[tid] += t;
        __syncthreads();
    }
    if (i < NN) tmp[i] = sm[tid];
    if (tid == 255) part[blockIdx.x] = sm[255];
}

__global__ void gat_scan2_kernel(int* __restrict__ part) {
    __shared__ int sm[256];
    int tid = threadIdx.x;
    int v = (tid < NB_SCAN) ? part[tid] : 0;
    sm[tid] = v;
    __syncthreads();
    for (int o = 1; o < 256; o <<= 1) {
        int t = (tid >= o) ? sm[tid - o] : 0;
        __syncthreads();
        sm[tid] += t;
        __syncthreads();
    }
    part[tid] = sm[tid];
}

__global__ void gat_scan3_kernel(const int* __restrict__ tmp, const int* __restrict__ part,
                                 int* __restrict__ row_ptr) {
    int i = blockIdx.x * 256 + threadIdx.x;
    int off = (blockIdx.x > 0) ? part[blockIdx.x - 1] : 0;
    if (i < NN) row_ptr[i + 1] = tmp[i] + off;
    if (i == 0) row_ptr[0] = 0;
}

__global__ void gat_fill_kernel(const int* __restrict__ ei, const int* __restrict__ row_ptr,
                                int* __restrict__ fillc, int* __restrict__ colA) {
    int i = blockIdx.x * blockDim.x + threadIdx.x;
    if (i >= ET) return;
    int s, d;
    if (i < EE) { s = ei[i]; d = ei[EE + i]; }
    else        { s = d = i - EE; }
    int pos = row_ptr[d] + atomicAdd(&fillc[d], 1);
    colA[pos] = s;
}

// ---------------------------------------------------------------- fused prep: Wt[n][k]=bf16(W[k][n]) x3 + x->bf16
#define PA1 (256 * 448)
#define PA2 (448 * 448)
#define PA3 (448 * 32)
#define PXQ (NN * 64)   // x quads (256 ch / 4)

__global__ void gat_prep_kernel(const float* __restrict__ W1, const float* __restrict__ W2,
                                const float* __restrict__ W3, const float* __restrict__ x,
                                ushort* __restrict__ Wt1, ushort* __restrict__ Wt2,
                                ushort* __restrict__ Wt3, ushort* __restrict__ xb) {
    int i = blockIdx.x * 256 + threadIdx.x;
    if (i < PA1) {
        int k = i / 448, n = i - k * 448;
        Wt1[(size_t)n * 256 + k] = f2bu(W1[i]);
        return;
    }
    i -= PA1;
    if (i < PA2) {
        int k = i / 448, n = i - k * 448;
        Wt2[(size_t)n * 448 + k] = f2bu(W2[i]);
        return;
    }
    i -= PA2;
    if (i < PA3) {
        int k = i / 32, n = i - k * 32;
        Wt3[(size_t)n * 448 + k] = f2bu(W3[i]);
        return;
    }
    i -= PA3;
    if (i < PXQ) {
        float4 f = ((const float4*)x)[i];
        ushort u[4] = {f2bu(f.x), f2bu(f.y), f2bu(f.z), f2bu(f.w)};
        ((uint2*)xb)[i] = *(const uint2*)u;
    }
}

// ---------------------------------------------------------------- GEMM core (bf16 A, DMA staging, LDS dbuf)
// C[M,N] = A[M,K] * W[K,N]; W pre-transposed bf16 Wt[N][K] (rows padded to >= n0+64).
// A padded to NP rows. DOA=1: fuse 64-ch alpha (head=blockIdx.y). DOA=2: 32-ch alpha.
// OM=0: C bf16. OM=1: C fp8 e4m3 (h-table for agg gather).
#define GBM 256
#define GBN 64
#define GBK 32

template <int DOA, int OM>
__global__ __launch_bounds__(256) void gat_gemm_kernel(
    const ushort* __restrict__ A, const ushort* __restrict__ Wt,
    void* __restrict__ Cv,
    const float* __restrict__ Asrc, const float* __restrict__ Adst,
    float* __restrict__ as8, float* __restrict__ ad8,
    int M, int K, int N) {
    __shared__ __align__(16) ushort As[2][GBM * GBK];   // 2 x 16 KB
    __shared__ __align__(16) ushort Bs[2][GBN * GBK];   // 2 x 4 KB
    int tid = threadIdx.x;
    int wave = tid >> 6, lane = tid & 63;
    int lrow = lane & 15, lq = lane >> 4;
    int m0 = blockIdx.x * GBM, n0 = blockIdx.y * GBN;
    int srow = lane >> 2, schunk = (lane & 3) * 8;      // 4 lanes per 64B row-chunk
    f32x4 acc[4][4] = {};

    int KT = K / GBK;
    {
#pragma unroll
        for (int q = 0; q < 4; q++) {
            const ushort* gp = A + (size_t)(m0 + wave * 64 + q * 16 + srow) * K + schunk;
            gl2lds(gp, &As[0][(wave * 64 + q * 16) * GBK]);
        }
        const ushort* gb = Wt + (size_t)(n0 + wave * 16 + srow) * K + schunk;
        gl2lds(gb, &Bs[0][wave * 16 * GBK]);
    }
    for (int kt = 0; kt < KT; kt++) {
        __syncthreads();
        if (kt + 1 < KT) {
            int nb = (kt + 1) & 1, k0 = (kt + 1) * GBK;
#pragma unroll
            for (int q = 0; q < 4; q++) {
                const ushort* gp = A + (size_t)(m0 + wave * 64 + q * 16 + srow) * K + k0 + schunk;
                gl2lds(gp, &As[nb][(wave * 64 + q * 16) * GBK]);
            }
            const ushort* gb = Wt + (size_t)(n0 + wave * 16 + srow) * K + k0 + schunk;
            gl2lds(gb, &Bs[nb][wave * 16 * GBK]);
        }
        int b = kt & 1;
        bf16x8 af[4];
#pragma unroll
        for (int rf = 0; rf < 4; rf++)
            af[rf] = *(const bf16x8*)&As[b][(wave * 64 + rf * 16 + lrow) * GBK + lq * 8];
#pragma unroll
        for (int ng = 0; ng < 4; ng++) {
            bf16x8 bf = *(const bf16x8*)&Bs[b][(ng * 16 + lrow) * GBK + lq * 8];
#pragma unroll
            for (int rf = 0; rf < 4; rf++)
                acc[rf][ng] = __builtin_amdgcn_mfma_f32_16x16x32_bf16(af[rf], bf, acc[rf][ng], 0, 0, 0);
        }
    }
    // epilogue: C/D layout col=lane&15 (within ng group), row=lq*4+r
#pragma unroll
    for (int rf = 0; rf < 4; rf++)
#pragma unroll
        for (int ng = 0; ng < 4; ng++)
#pragma unroll
            for (int r = 0; r < 4; r++) {
                int row = m0 + wave * 64 + rf * 16 + lq * 4 + r;
                int colI = n0 + ng * 16 + lrow;
                if (row < M && colI < N) {
                    if constexpr (OM == 0)
                        ((__hip_bfloat16*)Cv)[(size_t)row * N + colI] = __float2bfloat16(acc[rf][ng][r]);
                    else
                        ((unsigned char*)Cv)[(size_t)row * N + colI] = f2fp8(acc[rf][ng][r]);
                }
            }
    if constexpr (DOA == 1) {
        int head = blockIdx.y;
        float as_l[4], ad_l[4];
#pragma unroll
        for (int ng = 0; ng < 4; ng++) {
            as_l[ng] = Asrc[head * 64 + ng * 16 + lrow];
            ad_l[ng] = Adst[head * 64 + ng * 16 + lrow];
        }
#pragma unroll
        for (int rf = 0; rf < 4; rf++)
#pragma unroll
            for (int r = 0; r < 4; r++) {
                float ps = 0.f, pd = 0.f;
#pragma unroll
                for (int ng = 0; ng < 4; ng++) {
                    ps += acc[rf][ng][r] * as_l[ng];
                    pd += acc[rf][ng][r] * ad_l[ng];
                }
#pragma unroll
                for (int o = 1; o < 16; o <<= 1) {
                    ps += __shfl_xor(ps, o);
                    pd += __shfl_xor(pd, o);
                }
                int row = m0 + wave * 64 + rf * 16 + lq * 4 + r;
                if (lrow == 0 && row < M) {
                    as8[(size_t)row * 8 + head] = ps;
                    ad8[(size_t)row * 8 + head] = pd;
                }
            }
    } else if constexpr (DOA == 2) {
        float as_l[2], ad_l[2];
#pragma unroll
        for (int ng = 0; ng < 2; ng++) {
            as_l[ng] = Asrc[ng * 16 + lrow];
            ad_l[ng] = Adst[ng * 16 + lrow];
        }
#pragma unroll
        for (int rf = 0; rf < 4; rf++)
#pragma unroll
            for (int r = 0; r < 4; r++) {
                float ps = acc[rf][0][r] * as_l[0] + acc[rf][1][r] * as_l[1];
                float pd = acc[rf][0][r] * ad_l[0] + acc[rf][1][r] * ad_l[1];
#pragma unroll
                for (int o = 1; o < 16; o <<= 1) {
                    ps += __shfl_xor(ps, o);
                    pd += __shfl_xor(pd, o);
                }
                int row = m0 + wave * 64 + rf * 16 + lq * 4 + r;
                if (lrow == 0 && row < M) {
                    as8[(size_t)row * 8] = ps;
                    ad8[(size_t)row * 8] = pd;
                }
            }
    }
}

// ---------------------------------------------------------------- Phase C: wave-per-dst, fp8 h-table gather
// lane l<56 owns head l>>3, channels 8l..8l+7 (8B/lane fp8 gather, 16B/lane bf16 store)
__global__ void gat_aggC7_kernel(const int* __restrict__ rp, const int* __restrict__ colA,
                                 const float* __restrict__ as8, const float* __restrict__ ad8,
                                 const unsigned char* __restrict__ h8,
                                 const float* __restrict__ bias,
                                 __hip_bfloat16* __restrict__ outp) {
    int d = blockIdx.x * 4 + (threadIdx.x >> 6);
    if (d >= NN) return;
    int lane = threadIdx.x & 63;
    if (lane >= 56) return;
    int hh = lane >> 3;
    float adh = ad8[(size_t)d * 8 + hh];
    int s0 = rp[d], s1 = rp[d + 1];
    float acc[8] = {0.f, 0.f, 0.f, 0.f, 0.f, 0.f, 0.f, 0.f};
    float den = 0.f;
    int j = s0;
    for (; j + 4 <= s1; j += 4) {
        int sA = colA[j], sB = colA[j + 1], sC = colA[j + 2], sD = colA[j + 3];
        float eA = as8[(size_t)sA * 8 + hh] + adh;
        float eB = as8[(size_t)sB * 8 + hh] + adh;
        float eC = as8[(size_t)sC * 8 + hh] + adh;
        float eD = as8[(size_t)sD * 8 + hh] + adh;
        uint2 hA = *(const uint2*)(h8 + (size_t)sA * 448 + lane * 8);
        uint2 hB = *(const uint2*)(h8 + (size_t)sB * 448 + lane * 8);
        uint2 hC = *(const uint2*)(h8 + (size_t)sC * 448 + lane * 8);
        uint2 hD = *(const uint2*)(h8 + (size_t)sD * 448 + lane * 8);
        eA = (eA > 0.f) ? eA : 0.2f * eA;
        eB = (eB > 0.f) ? eB : 0.2f * eB;
        eC = (eC > 0.f) ? eC : 0.2f * eC;
        eD = (eD > 0.f) ? eD : 0.2f * eD;
        float wA = __expf(eA), wB = __expf(eB);
        float wC = __expf(eC), wD = __expf(eD);
        den += (wA + wB) + (wC + wD);
        fp8acc4(hA.x, wA, &acc[0]); fp8acc4(hA.y, wA, &acc[4]);
        fp8acc4(hB.x, wB, &acc[0]); fp8acc4(hB.y, wB, &acc[4]);
        fp8acc4(hC.x, wC, &acc[0]); fp8acc4(hC.y, wC, &acc[4]);
        fp8acc4(hD.x, wD, &acc[0]); fp8acc4(hD.y, wD, &acc[4]);
    }
    for (; j < s1; j++) {
        int s = colA[j];
        float e = as8[(size_t)s * 8 + hh] + adh;
        e = (e > 0.f) ? e : 0.2f * e;
        float w = __expf(e);
        uint2 hv = *(const uint2*)(h8 + (size_t)s * 448 + lane * 8);
        den += w;
        fp8acc4(hv.x, w, &acc[0]);
        fp8acc4(hv.y, w, &acc[4]);
    }
    float inv = 1.f / (den + 1e-16f);
    const float4* bp = (const float4*)(bias + lane * 8);
    float4 bb0 = bp[0], bb1 = bp[1];
    float bv[8] = {bb0.x, bb0.y, bb0.z, bb0.w, bb1.x, bb1.y, bb1.z, bb1.w};
    ushort o8[8];
#pragma unroll
    for (int k = 0; k < 8; k++) {
        float o = acc[k] * inv + bv[k];
        o = fmaxf(o, 0.f);
        o8[k] = f2bu(o);
    }
    *(uint4*)((ushort*)outp + (size_t)d * 448 + lane * 8) = *(const uint4*)o8;
}

// ---------------------------------------------------------------- Phase C final: 2 dsts/wave, 32 ch (bf16 h), log_softmax
__global__ void gat_aggCF_kernel(const int* __restrict__ rp, const int* __restrict__ colA,
                                 const float* __restrict__ as8, const float* __restrict__ ad8,
                                 const __hip_bfloat16* __restrict__ h,
                                 const float* __restrict__ bias,
                                 float* __restrict__ outp) {
    int wid = blockIdx.x * 4 + (threadIdx.x >> 6);
    int lane = threadIdx.x & 63;
    int half = lane >> 5, c = lane & 31;
    int dreal = wid * 2 + half;
    bool valid = dreal < NN;
    int d = valid ? dreal : (NN - 1);
    float adh = ad8[(size_t)d * 8];
    int s0 = rp[d], s1 = rp[d + 1];
    float acc = 0.f, den = 0.f;
    int j = s0;
    for (; j + 2 <= s1; j += 2) {
        int sA = colA[j], sB = colA[j + 1];
        float eA = as8[(size_t)sA * 8] + adh;
        float eB = as8[(size_t)sB * 8] + adh;
        float vA = bf2f(h[(size_t)sA * 32 + c]);
        float vB = bf2f(h[(size_t)sB * 32 + c]);
        eA = (eA > 0.f) ? eA : 0.2f * eA;
        eB = (eB > 0.f) ? eB : 0.2f * eB;
        float wA = __expf(eA), wB = __expf(eB);
        den += wA + wB;
        acc += wA * vA + wB * vB;
    }
    for (; j < s1; j++) {
        int s = colA[j];
        float e = as8[(size_t)s * 8] + adh;
        e = (e > 0.f) ? e : 0.2f * e;
        float w = __expf(e);
        den += w;
        acc += w * bf2f(h[(size_t)s * 32 + c]);
    }
    float o = acc / (den + 1e-16f) + bias[c];
    float t = o;
#pragma unroll
    for (int off = 16; off > 0; off >>= 1) t = fmaxf(t, __shfl_xor(t, off));
    float ex = __expf(o - t);
#pragma unroll
    for (int off = 16; off > 0; off >>= 1) ex += __shfl_xor(ex, off);
    float res = o - t - __logf(ex);
    if (valid) outp[(size_t)d * 32 + c] = res;
}

// ---------------------------------------------------------------- launch
extern "C" void kernel_launch(void* const* d_in, const int* in_sizes, int n_in,
                              void* d_out, int out_size, void* d_ws, size_t ws_size,
                              hipStream_t stream) {
    const float* x   = (const float*)d_in[0];
    const int*   ei  = (const int*)d_in[1];
    const float* W1  = (const float*)d_in[2];
    const float* a1s = (const float*)d_in[3];
    const float* a1d = (const float*)d_in[4];
    const float* b1  = (const float*)d_in[5];
    const float* W2  = (const float*)d_in[6];
    const float* a2s = (const float*)d_in[7];
    const float* a2d = (const float*)d_in[8];
    const float* b2  = (const float*)d_in[9];
    const float* W3  = (const float*)d_in[10];
    const float* a3s = (const float*)d_in[11];
    const float* a3d = (const float*)d_in[12];
    const float* b3  = (const float*)d_in[13];
    float* out = (float*)d_out;

    // workspace layout (~105 MB)
    char* w = (char*)d_ws;
    unsigned char* hbuf8 = (unsigned char*)w;                  // NP*448 fp8 (22.5 MB); layer-3 reuses as bf16 NP*32
    __hip_bfloat16* hbuf3 = (__hip_bfloat16*)w;
    ushort* xb = (ushort*)(w + (size_t)NP * 448);              // NP*256 bf16 (25.7 MB)
    __hip_bfloat16* act = (__hip_bfloat16*)(xb + (size_t)NP * 256);  // NP*448 bf16 (44.9 MB)
    float* as8 = (float*)(act + (size_t)NP * 448);             // N*8 f32
    float* ad8 = as8 + (size_t)NN * 8;                         // N*8 f32
    int* cnt     = (int*)(ad8 + (size_t)NN * 8);               // N
    int* fillc   = cnt + NN;                                   // N
    int* row_ptr = fillc + NN;                                 // N+4 (padded)
    int* tmp     = row_ptr + (NN + 4);                         // N
    int* part    = tmp + NN;                                   // 256
    int* colA    = part + 256;                                 // ET
    char* pw = (char*)(colA + ET);
    pw = (char*)(((uintptr_t)pw + 15) & ~(uintptr_t)15);
    ushort* Wt1 = (ushort*)pw;                                 // 448*256
    ushort* Wt2 = Wt1 + 448 * 256;                             // 448*448
    ushort* Wt3 = Wt2 + 448 * 448;                             // 64*448 (rows 32..63 poison, never stored)

    hipMemsetAsync(cnt, 0, 2 * (size_t)NN * sizeof(int), stream);  // cnt + fillc
    int eblocks = (ET + 255) / 256;
    gat_count_kernel<<<eblocks, 256, 0, stream>>>(ei, cnt);
    gat_scan1_kernel<<<NB_SCAN, 256, 0, stream>>>(cnt, tmp, part);
    gat_scan2_kernel<<<1, 256, 0, stream>>>(part);
    gat_scan3_kernel<<<NB_SCAN, 256, 0, stream>>>(tmp, part, row_ptr);
    gat_fill_kernel<<<eblocks, 256, 0, stream>>>(ei, row_ptr, fillc, colA);

    // fused prep: weight transposes + x->bf16
    int ptotal = PA1 + PA2 + PA3 + PXQ;
    gat_prep_kernel<<<(ptotal + 255) / 256, 256, 0, stream>>>(W1, W2, W3, x, Wt1, Wt2, Wt3, xb);

    dim3 gemmBlk(256);
    int mtiles = NP / GBM;              // 196
    int aggBlocks = (NN + 3) / 4;       // 12500

    // --- layer 1 (alpha fused; h written as fp8)
    gat_gemm_kernel<1, 1><<<dim3(mtiles, 7), gemmBlk, 0, stream>>>(
        xb, Wt1, hbuf8, a1s, a1d, as8, ad8, NN, 256, 448);
    gat_aggC7_kernel<<<aggBlocks, 256, 0, stream>>>(row_ptr, colA, as8, ad8, hbuf8, b1, act);

    // --- layer 2
    gat_gemm_kernel<1, 1><<<dim3(mtiles, 7), gemmBlk, 0, stream>>>(
        (const ushort*)act, Wt2, hbuf8, a2s, a2d, as8, ad8, NN, 448, 448);
    gat_aggC7_kernel<<<aggBlocks, 256, 0, stream>>>(row_ptr, colA, as8, ad8, hbuf8, b2, act);

    // --- layer 3 (1 head, 32 ch, alpha fused, bf16 h, log_softmax, fp32 out)
    gat_gemm_kernel<2, 0><<<dim3(mtiles, 1), gemmBlk, 0, stream>>>(
        (const ushort*)act, Wt3, hbuf3, a3s, a3d, as8, ad8, NN, 448, 32);
    int fBlocks = (NN + 7) / 8;  // 8 dsts per block (2 per wave)
    gat_aggCF_kernel<<<fBlocks, 256, 0, stream>>>(row_ptr, colA, as8, ad8, hbuf3, b3, out);
}

// Round 12
// 489.204 us; speedup vs baseline: 2.1183x; 1.0082x over previous
//
#include <hip/hip_runtime.h>
#include <hip/hip_bf16.h>
#include <hip/hip_fp16.h>

#define NN 50000
#define NP 50176              // NN padded to multiple of 256 (GEMM tiles, no bounds checks)
#define EE 800000
#define ET (EE + NN)          // 850000 edges incl self-loops
#define NB_SCAN ((NN + 255) / 256)   // 196

typedef __attribute__((ext_vector_type(8))) short bf16x8;
typedef __attribute__((ext_vector_type(4))) float f32x4;

static __device__ __forceinline__ float bf2f(__hip_bfloat16 x) { return __bfloat162float(x); }
static __device__ __forceinline__ ushort f2bu(float f) {
    union { __hip_bfloat16 b; ushort u; } c;
    c.b = __float2bfloat16(f);
    return c.u;
}
static __device__ __forceinline__ float u2f(ushort u) {
    union { ushort u; __hip_bfloat16 b; } c;
    c.u = u;
    return __bfloat162float(c.b);
}
// fp8 e4m3 HW conversion (gfx950). Encode+decode use the same HW format -> self-consistent.
static __device__ __forceinline__ unsigned char f2fp8(float v) {
    int p = __builtin_amdgcn_cvt_pk_fp8_f32(v, v, 0, false);
    return (unsigned char)(p & 0xff);
}
// decode 4 packed fp8 bytes, accumulate w*val into acc[0..3]; packed 2-at-a-time where available
static __device__ __forceinline__ void fp8acc4(unsigned v, float w, float* acc) {
#if __has_builtin(__builtin_amdgcn_cvt_pk_f32_fp8)
    auto f01 = __builtin_amdgcn_cvt_pk_f32_fp8((int)v, false);
    auto f23 = __builtin_amdgcn_cvt_pk_f32_fp8((int)v, true);
    acc[0] += w * f01[0];
    acc[1] += w * f01[1];
    acc[2] += w * f23[0];
    acc[3] += w * f23[1];
#else
    acc[0] += w * __builtin_amdgcn_cvt_f32_fp8(v, 0);
    acc[1] += w * __builtin_amdgcn_cvt_f32_fp8(v, 1);
    acc[2] += w * __builtin_amdgcn_cvt_f32_fp8(v, 2);
    acc[3] += w * __builtin_amdgcn_cvt_f32_fp8(v, 3);
#endif
}
// async global->LDS DMA, 16B per lane; lds dest must be wave-uniform base
static __device__ __forceinline__ void gl2lds(const ushort* g, ushort* l) {
    __builtin_amdgcn_global_load_lds(
        (const __attribute__((address_space(1))) void*)g,
        (__attribute__((address_space(3))) void*)l,
        16, 0, 0);
}

// ---------------------------------------------------------------- fused prep + CSR count
#define PA1 (256 * 448)
#define PA2 (448 * 448)
#define PA3 (448 * 32)
#define PXQ (NN * 64)   // x quads (256 ch / 4)
#define PTOT (PA1 + PA2 + PA3 + PXQ)
#define PBLK ((PTOT + 255) / 256)
#define CBLK ((ET + 255) / 256)

__global__ void gat_prepcnt_kernel(const float* __restrict__ W1, const float* __restrict__ W2,
                                   const float* __restrict__ W3, const float* __restrict__ x,
                                   ushort* __restrict__ Wt1, ushort* __restrict__ Wt2,
                                   ushort* __restrict__ Wt3, ushort* __restrict__ xb,
                                   const int* __restrict__ ei, int* __restrict__ cnt) {
    int b = blockIdx.x;
    if (b >= PBLK) {
        int i = (b - PBLK) * 256 + threadIdx.x;
        if (i < ET) {
            int dst = (i < EE) ? ei[EE + i] : (i - EE);
            atomicAdd(&cnt[dst], 1);
        }
        return;
    }
    int i = b * 256 + threadIdx.x;
    if (i < PA1) {
        int k = i / 448, n = i - k * 448;
        Wt1[(size_t)n * 256 + k] = f2bu(W1[i]);
        return;
    }
    i -= PA1;
    if (i < PA2) {
        int k = i / 448, n = i - k * 448;
        Wt2[(size_t)n * 448 + k] = f2bu(W2[i]);
        return;
    }
    i -= PA2;
    if (i < PA3) {
        int k = i / 32, n = i - k * 32;
        Wt3[(size_t)n * 448 + k] = f2bu(W3[i]);
        return;
    }
    i -= PA3;
    if (i < PXQ) {
        float4 f = ((const float4*)x)[i];
        ushort u[4] = {f2bu(f.x), f2bu(f.y), f2bu(f.z), f2bu(f.w)};
        ((uint2*)xb)[i] = *(const uint2*)u;
    }
}

// ---------------------------------------------------------------- CSR scans + fill
__global__ void gat_scan1_kernel(const int* __restrict__ cnt, int* __restrict__ tmp,
                                 int* __restrict__ part) {
    __shared__ int sm[256];
    int tid = threadIdx.x;
    int i = blockIdx.x * 256 + tid;
    int v = (i < NN) ? cnt[i] : 0;
    sm[tid] = v;
    __syncthreads();
    for (int o = 1; o < 256; o <<= 1) {
        int t = (tid >= o) ? sm[tid - o] : 0;
        __syncthreads();
        sm[tid] += t;
        __syncthreads();
    }
    if (i < NN) tmp[i] = sm[tid];
    if (tid == 255) part[blockIdx.x] = sm[255];
}

__global__ void gat_scan2_kernel(int* __restrict__ part) {
    __shared__ int sm[256];
    int tid = threadIdx.x;
    int v = (tid < NB_SCAN) ? part[tid] : 0;
    sm[tid] = v;
    __syncthreads();
    for (int o = 1; o < 256; o <<= 1) {
        int t = (tid >= o) ? sm[tid - o] : 0;
        __syncthreads();
        sm[tid] += t;
        __syncthreads();
    }
    part[tid] = sm[tid];
}

__global__ void gat_scan3_kernel(const int* __restrict__ tmp, const int* __restrict__ part,
                                 int* __restrict__ row_ptr) {
    int i = blockIdx.x * 256 + threadIdx.x;
    int off = (blockIdx.x > 0) ? part[blockIdx.x - 1] : 0;
    if (i < NN) row_ptr[i + 1] = tmp[i] + off;
    if (i == 0) row_ptr[0] = 0;
}

__global__ void gat_fill_kernel(const int* __restrict__ ei, const int* __restrict__ row_ptr,
                                int* __restrict__ fillc, int* __restrict__ colA) {
    int i = blockIdx.x * blockDim.x + threadIdx.x;
    if (i >= ET) return;
    int s, d;
    if (i < EE) { s = ei[i]; d = ei[EE + i]; }
    else        { s = d = i - EE; }
    int pos = row_ptr[d] + atomicAdd(&fillc[d], 1);
    colA[pos] = s;
}

// ---------------------------------------------------------------- GEMM core (bf16 A, DMA staging, LDS dbuf)
// C[M,N] = A[M,K] * W[K,N]; W pre-transposed bf16 Wt[N][K] (rows padded to >= n0+64).
// A padded to NP rows. RF = 16-row frags per wave (BM = RF*64).
// DOA=1: fuse 64-ch alpha (head=blockIdx.y). DOA=2: 32-ch alpha. OM=1: C fp8 e4m3.
#define GBN 64
#define GBK 32

template <int RF, int DOA, int OM>
__global__ __launch_bounds__(256) void gat_gemm_kernel(
    const ushort* __restrict__ A, const ushort* __restrict__ Wt,
    void* __restrict__ Cv,
    const float* __restrict__ Asrc, const float* __restrict__ Adst,
    float* __restrict__ as8, float* __restrict__ ad8,
    int M, int K, int N) {
    constexpr int GBM = RF * 64;
    __shared__ __align__(16) ushort As[2][GBM * GBK];
    __shared__ __align__(16) ushort Bs[2][GBN * GBK];
    int tid = threadIdx.x;
    int wave = tid >> 6, lane = tid & 63;
    int lrow = lane & 15, lq = lane >> 4;
    int m0 = blockIdx.x * GBM, n0 = blockIdx.y * GBN;
    int srow = lane >> 2, schunk = (lane & 3) * 8;      // 4 lanes per 64B row-chunk
    f32x4 acc[RF][4] = {};

    int KT = K / GBK;
    {
#pragma unroll
        for (int q = 0; q < RF; q++) {
            const ushort* gp = A + (size_t)(m0 + wave * RF * 16 + q * 16 + srow) * K + schunk;
            gl2lds(gp, &As[0][(wave * RF * 16 + q * 16) * GBK]);
        }
        const ushort* gb = Wt + (size_t)(n0 + wave * 16 + srow) * K + schunk;
        gl2lds(gb, &Bs[0][wave * 16 * GBK]);
    }
    for (int kt = 0; kt < KT; kt++) {
        __syncthreads();
        if (kt + 1 < KT) {
            int nb = (kt + 1) & 1, k0 = (kt + 1) * GBK;
#pragma unroll
            for (int q = 0; q < RF; q++) {
                const ushort* gp = A + (size_t)(m0 + wave * RF * 16 + q * 16 + srow) * K + k0 + schunk;
                gl2lds(gp, &As[nb][(wave * RF * 16 + q * 16) * GBK]);
            }
            const ushort* gb = Wt + (size_t)(n0 + wave * 16 + srow) * K + k0 + schunk;
            gl2lds(gb, &Bs[nb][wave * 16 * GBK]);
        }
        int b = kt & 1;
        bf16x8 af[RF];
#pragma unroll
        for (int rf = 0; rf < RF; rf++)
            af[rf] = *(const bf16x8*)&As[b][(wave * RF * 16 + rf * 16 + lrow) * GBK + lq * 8];
#pragma unroll
        for (int ng = 0; ng < 4; ng++) {
            bf16x8 bf = *(const bf16x8*)&Bs[b][(ng * 16 + lrow) * GBK + lq * 8];
#pragma unroll
            for (int rf = 0; rf < RF; rf++)
                acc[rf][ng] = __builtin_amdgcn_mfma_f32_16x16x32_bf16(af[rf], bf, acc[rf][ng], 0, 0, 0);
        }
    }
    // epilogue: C/D layout col=lane&15 (within ng group), row=lq*4+r
#pragma unroll
    for (int rf = 0; rf < RF; rf++)
#pragma unroll
        for (int ng = 0; ng < 4; ng++)
#pragma unroll
            for (int r = 0; r < 4; r++) {
                int row = m0 + wave * RF * 16 + rf * 16 + lq * 4 + r;
                int colI = n0 + ng * 16 + lrow;
                if (row < M && colI < N) {
                    if constexpr (OM == 0)
                        ((__hip_bfloat16*)Cv)[(size_t)row * N + colI] = __float2bfloat16(acc[rf][ng][r]);
                    else
                        ((unsigned char*)Cv)[(size_t)row * N + colI] = f2fp8(acc[rf][ng][r]);
                }
            }
    if constexpr (DOA == 1) {
        int head = blockIdx.y;
        float as_l[4], ad_l[4];
#pragma unroll
        for (int ng = 0; ng < 4; ng++) {
            as_l[ng] = Asrc[head * 64 + ng * 16 + lrow];
            ad_l[ng] = Adst[head * 64 + ng * 16 + lrow];
        }
#pragma unroll
        for (int rf = 0; rf < RF; rf++)
#pragma unroll
            for (int r = 0; r < 4; r++) {
                float ps = 0.f, pd = 0.f;
#pragma unroll
                for (int ng = 0; ng < 4; ng++) {
                    ps += acc[rf][ng][r] * as_l[ng];
                    pd += acc[rf][ng][r] * ad_l[ng];
                }
#pragma unroll
                for (int o = 1; o < 16; o <<= 1) {
                    ps += __shfl_xor(ps, o);
                    pd += __shfl_xor(pd, o);
                }
                int row = m0 + wave * RF * 16 + rf * 16 + lq * 4 + r;
                if (lrow == 0 && row < M) {
                    as8[(size_t)row * 8 + head] = ps;
                    ad8[(size_t)row * 8 + head] = pd;
                }
            }
    } else if constexpr (DOA == 2) {
        float as_l[2], ad_l[2];
#pragma unroll
        for (int ng = 0; ng < 2; ng++) {
            as_l[ng] = Asrc[ng * 16 + lrow];
            ad_l[ng] = Adst[ng * 16 + lrow];
        }
#pragma unroll
        for (int rf = 0; rf < RF; rf++)
#pragma unroll
            for (int r = 0; r < 4; r++) {
                float ps = acc[rf][0][r] * as_l[0] + acc[rf][1][r] * as_l[1];
                float pd = acc[rf][0][r] * ad_l[0] + acc[rf][1][r] * ad_l[1];
#pragma unroll
                for (int o = 1; o < 16; o <<= 1) {
                    ps += __shfl_xor(ps, o);
                    pd += __shfl_xor(pd, o);
                }
                int row = m0 + wave * RF * 16 + rf * 16 + lq * 4 + r;
                if (lrow == 0 && row < M) {
                    as8[(size_t)row * 8] = ps;
                    ad8[(size_t)row * 8] = pd;
                }
            }
    }
}

// ---------------------------------------------------------------- Phase C: wave-per-dst, fp8 h-table gather
// lane l<56 owns head l>>3, channels 8l..8l+7 (8B/lane fp8 gather, 16B/lane bf16 store)
__global__ void gat_aggC7_kernel(const int* __restrict__ rp, const int* __restrict__ colA,
                                 const float* __restrict__ as8, const float* __restrict__ ad8,
                                 const unsigned char* __restrict__ h8,
                                 const float* __restrict__ bias,
                                 __hip_bfloat16* __restrict__ outp) {
    int d = blockIdx.x * 4 + (threadIdx.x >> 6);
    if (d >= NN) return;
    int lane = threadIdx.x & 63;
    if (lane >= 56) return;
    int hh = lane >> 3;
    float adh = ad8[(size_t)d * 8 + hh];
    int s0 = rp[d], s1 = rp[d + 1];
    float acc[8] = {0.f, 0.f, 0.f, 0.f, 0.f, 0.f, 0.f, 0.f};
    float den = 0.f;
    int j = s0;
    for (; j + 4 <= s1; j += 4) {
        int sA = colA[j], sB = colA[j + 1], sC = colA[j + 2], sD = colA[j + 3];
        float eA = as8[(size_t)sA * 8 + hh] + adh;
        float eB = as8[(size_t)sB * 8 + hh] + adh;
        float eC = as8[(size_t)sC * 8 + hh] + adh;
        float eD = as8[(size_t)sD * 8 + hh] + adh;
        uint2 hA = *(const uint2*)(h8 + (size_t)sA * 448 + lane * 8);
        uint2 hB = *(const uint2*)(h8 + (size_t)sB * 448 + lane * 8);
        uint2 hC = *(const uint2*)(h8 + (size_t)sC * 448 + lane * 8);
        uint2 hD = *(const uint2*)(h8 + (size_t)sD * 448 + lane * 8);
        eA = (eA > 0.f) ? eA : 0.2f * eA;
        eB = (eB > 0.f) ? eB : 0.2f * eB;
        eC = (eC > 0.f) ? eC : 0.2f * eC;
        eD = (eD > 0.f) ? eD : 0.2f * eD;
        float wA = __expf(eA), wB = __expf(eB);
        float wC = __expf(eC), wD = __expf(eD);
        den += (wA + wB) + (wC + wD);
        fp8acc4(hA.x, wA, &acc[0]); fp8acc4(hA.y, wA, &acc[4]);
        fp8acc4(hB.x, wB, &acc[0]); fp8acc4(hB.y, wB, &acc[4]);
        fp8acc4(hC.x, wC, &acc[0]); fp8acc4(hC.y, wC, &acc[4]);
        fp8acc4(hD.x, wD, &acc[0]); fp8acc4(hD.y, wD, &acc[4]);
    }
    for (; j < s1; j++) {
        int s = colA[j];
        float e = as8[(size_t)s * 8 + hh] + adh;
        e = (e > 0.f) ? e : 0.2f * e;
        float w = __expf(e);
        uint2 hv = *(const uint2*)(h8 + (size_t)s * 448 + lane * 8);
        den += w;
        fp8acc4(hv.x, w, &acc[0]);
        fp8acc4(hv.y, w, &acc[4]);
    }
    float inv = 1.f / (den + 1e-16f);
    const float4* bp = (const float4*)(bias + lane * 8);
    float4 bb0 = bp[0], bb1 = bp[1];
    float bv[8] = {bb0.x, bb0.y, bb0.z, bb0.w, bb1.x, bb1.y, bb1.z, bb1.w};
    ushort o8[8];
#pragma unroll
    for (int k = 0; k < 8; k++) {
        float o = acc[k] * inv + bv[k];
        o = fmaxf(o, 0.f);
        o8[k] = f2bu(o);
    }
    *(uint4*)((ushort*)outp + (size_t)d * 448 + lane * 8) = *(const uint4*)o8;
}

// ---------------------------------------------------------------- Phase C final: 2 dsts/wave, 32 ch (bf16 h), log_softmax
__global__ void gat_aggCF_kernel(const int* __restrict__ rp, const int* __restrict__ colA,
                                 const float* __restrict__ as8, const float* __restrict__ ad8,
                                 const __hip_bfloat16* __restrict__ h,
                                 const float* __restrict__ bias,
                                 float* __restrict__ outp) {
    int wid = blockIdx.x * 4 + (threadIdx.x >> 6);
    int lane = threadIdx.x & 63;
    int half = lane >> 5, c = lane & 31;
    int dreal = wid * 2 + half;
    bool valid = dreal < NN;
    int d = valid ? dreal : (NN - 1);
    float adh = ad8[(size_t)d * 8];
    int s0 = rp[d], s1 = rp[d + 1];
    float acc = 0.f, den = 0.f;
    int j = s0;
    for (; j + 2 <= s1; j += 2) {
        int sA = colA[j], sB = colA[j + 1];
        float eA = as8[(size_t)sA * 8] + adh;
        float eB = as8[(size_t)sB * 8] + adh;
        float vA = bf2f(h[(size_t)sA * 32 + c]);
        float vB = bf2f(h[(size_t)sB * 32 + c]);
        eA = (eA > 0.f) ? eA : 0.2f * eA;
        eB = (eB > 0.f) ? eB : 0.2f * eB;
        float wA = __expf(eA), wB = __expf(eB);
        den += wA + wB;
        acc += wA * vA + wB * vB;
    }
    for (; j < s1; j++) {
        int s = colA[j];
        float e = as8[(size_t)s * 8] + adh;
        e = (e > 0.f) ? e : 0.2f * e;
        float w = __expf(e);
        den += w;
        acc += w * bf2f(h[(size_t)s * 32 + c]);
    }
    float o = acc / (den + 1e-16f) + bias[c];
    float t = o;
#pragma unroll
    for (int off = 16; off > 0; off >>= 1) t = fmaxf(t, __shfl_xor(t, off));
    float ex = __expf(o - t);
#pragma unroll
    for (int off = 16; off > 0; off >>= 1) ex += __shfl_xor(ex, off);
    float res = o - t - __logf(ex);
    if (valid) outp[(size_t)d * 32 + c] = res;
}

// ---------------------------------------------------------------- launch
extern "C" void kernel_launch(void* const* d_in, const int* in_sizes, int n_in,
                              void* d_out, int out_size, void* d_ws, size_t ws_size,
                              hipStream_t stream) {
    const float* x   = (const float*)d_in[0];
    const int*   ei  = (const int*)d_in[1];
    const float* W1  = (const float*)d_in[2];
    const float* a1s = (const float*)d_in[3];
    const float* a1d = (const float*)d_in[4];
    const float* b1  = (const float*)d_in[5];
    const float* W2  = (const float*)d_in[6];
    const float* a2s = (const float*)d_in[7];
    const float* a2d = (const float*)d_in[8];
    const float* b2  = (const float*)d_in[9];
    const float* W3  = (const float*)d_in[10];
    const float* a3s = (const float*)d_in[11];
    const float* a3d = (const float*)d_in[12];
    const float* b3  = (const float*)d_in[13];
    float* out = (float*)d_out;

    // workspace layout (~105 MB)
    char* w = (char*)d_ws;
    unsigned char* hbuf8 = (unsigned char*)w;                  // NP*448 fp8 (22.5 MB); layer-3 reuses as bf16 NP*32
    __hip_bfloat16* hbuf3 = (__hip_bfloat16*)w;
    ushort* xb = (ushort*)(w + (size_t)NP * 448);              // NP*256 bf16 (25.7 MB)
    __hip_bfloat16* act = (__hip_bfloat16*)(xb + (size_t)NP * 256);  // NP*448 bf16 (44.9 MB)
    float* as8 = (float*)(act + (size_t)NP * 448);             // N*8 f32
    float* ad8 = as8 + (size_t)NN * 8;                         // N*8 f32
    int* cnt     = (int*)(ad8 + (size_t)NN * 8);               // N
    int* fillc   = cnt + NN;                                   // N
    int* row_ptr = fillc + NN;                                 // N+4 (padded)
    int* tmp     = row_ptr + (NN + 4);                         // N
    int* part    = tmp + NN;                                   // 256
    int* colA    = part + 256;                                 // ET
    char* pw = (char*)(colA + ET);
    pw = (char*)(((uintptr_t)pw + 15) & ~(uintptr_t)15);
    ushort* Wt1 = (ushort*)pw;                                 // 448*256
    ushort* Wt2 = Wt1 + 448 * 256;                             // 448*448
    ushort* Wt3 = Wt2 + 448 * 448;                             // 64*448 (rows 32..63 poison, never stored)

    hipMemsetAsync(cnt, 0, 2 * (size_t)NN * sizeof(int), stream);  // cnt + fillc

    // fused prep (wt x3 + x->bf16) + CSR count
    gat_prepcnt_kernel<<<PBLK + CBLK, 256, 0, stream>>>(W1, W2, W3, x, Wt1, Wt2, Wt3, xb, ei, cnt);
    gat_scan1_kernel<<<NB_SCAN, 256, 0, stream>>>(cnt, tmp, part);
    gat_scan2_kernel<<<1, 256, 0, stream>>>(part);
    gat_scan3_kernel<<<NB_SCAN, 256, 0, stream>>>(tmp, part, row_ptr);
    gat_fill_kernel<<<CBLK, 256, 0, stream>>>(ei, row_ptr, fillc, colA);

    dim3 gemmBlk(256);
    int mtiles = NP / 256;              // 196 (RF=4)
    int mtiles1 = NP / 64;              // 784 (RF=1, layer 3)
    int aggBlocks = (NN + 3) / 4;       // 12500

    // --- layer 1 (alpha fused; h written as fp8)
    gat_gemm_kernel<4, 1, 1><<<dim3(mtiles, 7), gemmBlk, 0, stream>>>(
        xb, Wt1, hbuf8, a1s, a1d, as8, ad8, NN, 256, 448);
    gat_aggC7_kernel<<<aggBlocks, 256, 0, stream>>>(row_ptr, colA, as8, ad8, hbuf8, b1, act);

    // --- layer 2
    gat_gemm_kernel<4, 1, 1><<<dim3(mtiles, 7), gemmBlk, 0, stream>>>(
        (const ushort*)act, Wt2, hbuf8, a2s, a2d, as8, ad8, NN, 448, 448);
    gat_aggC7_kernel<<<aggBlocks, 256, 0, stream>>>(row_ptr, colA, as8, ad8, hbuf8, b2, act);

    // --- layer 3 (1 head, 32 ch, alpha fused, bf16 h, RF=1 for occupancy, log_softmax, fp32 out)
    gat_gemm_kernel<1, 2, 0><<<dim3(mtiles1, 1), gemmBlk, 0, stream>>>(
        (const ushort*)act, Wt3, hbuf3, a3s, a3d, as8, ad8, NN, 448, 32);
    int fBlocks = (NN + 7) / 8;  // 8 dsts per block (2 per wave)
    gat_aggCF_kernel<<<fBlocks, 256, 0, stream>>>(row_ptr, colA, as8, ad8, hbuf3, b3, out);
}